// Round 1
// baseline (2245.164 us; speedup 1.0000x reference)
//
#include <hip/hip_runtime.h>
#include <math.h>

#define N_PIX (512*512)
#define S_SEG 1024
#define CDIM  256
#define BATCH 8

#define BM 64
#define BN 64
#define BK 16

__device__ __forceinline__ float lrelu(float v) { return v > 0.f ? v : 0.2f * v; }

// ---------------------------------------------------------------------------
// Segment pooling: per-block LDS bins, then atomic flush to global sums/counts
// grid: BATCH*32 blocks, 256 threads
// ---------------------------------------------------------------------------
__global__ __launch_bounds__(256) void seg_pool_kernel(
    const float* __restrict__ images, const int* __restrict__ seg,
    float* __restrict__ sums, float* __restrict__ counts)
{
    __shared__ float bins[S_SEG * 4];
    const int b = blockIdx.x >> 5;
    const int chunk = blockIdx.x & 31;
    for (int i = threadIdx.x; i < S_SEG * 4; i += 256) bins[i] = 0.f;
    __syncthreads();

    const int pix_per_block = N_PIX / 32;  // 8192
    const int base = chunk * pix_per_block;
    const float* im = images + (size_t)b * 3 * N_PIX;
    const int* sg = seg + (size_t)b * N_PIX;

    for (int it = 0; it < pix_per_block / 256; ++it) {
        int p = base + it * 256 + threadIdx.x;
        int s = sg[p];
        float r = im[p];
        float g = im[N_PIX + p];
        float bl = im[2 * N_PIX + p];
        atomicAdd(&bins[s * 4 + 0], r);
        atomicAdd(&bins[s * 4 + 1], g);
        atomicAdd(&bins[s * 4 + 2], bl);
        atomicAdd(&bins[s * 4 + 3], 1.f);
    }
    __syncthreads();
    for (int s = threadIdx.x; s < S_SEG; s += 256) {
        float4 v = *(const float4*)&bins[s * 4];
        atomicAdd(&sums[((size_t)b * S_SEG + s) * 3 + 0], v.x);
        atomicAdd(&sums[((size_t)b * S_SEG + s) * 3 + 1], v.y);
        atomicAdd(&sums[((size_t)b * S_SEG + s) * 3 + 2], v.z);
        atomicAdd(&counts[(size_t)b * S_SEG + s], v.w);
    }
}

// ---------------------------------------------------------------------------
// abar[b,j] = mean_i A[b,i,j]   (column means of A) -- grid 32 x 256
// ---------------------------------------------------------------------------
__global__ __launch_bounds__(256) void abar_kernel(
    const float* __restrict__ A, float* __restrict__ abar)
{
    int idx = blockIdx.x * 256 + threadIdx.x;   // 0..8191
    int b = idx >> 10, j = idx & 1023;
    const float* Ab = A + (size_t)b * S_SEG * S_SEG + j;
    float s = 0.f;
    for (int i = 0; i < S_SEG; ++i) s += Ab[(size_t)i * S_SEG];
    abar[idx] = s * (1.f / (float)S_SEG);
}

// ---------------------------------------------------------------------------
// xin[r, c] (8192 x 144): c<3 -> feats, 3<=c<131 -> z, else 0
// ---------------------------------------------------------------------------
__global__ __launch_bounds__(256) void prep_xin_kernel(
    const float* __restrict__ sums, const float* __restrict__ counts,
    const float* __restrict__ z, float* __restrict__ xin)
{
    int idx = blockIdx.x * 256 + threadIdx.x;
    int r = idx / 144, c = idx % 144;
    int b = r >> 10;
    float v;
    if (c < 3)        v = sums[r * 3 + c] / (counts[r] + 1e-6f);
    else if (c < 131) v = z[b * 128 + (c - 3)];
    else              v = 0.f;
    xin[idx] = v;
}

__global__ __launch_bounds__(256) void prep_wpad_kernel(
    const float* __restrict__ proj_w, float* __restrict__ wpad)
{
    int idx = blockIdx.x * 256 + threadIdx.x;   // over 256*144
    int n = idx / 144, k = idx % 144;
    wpad[idx] = (k < 131) ? proj_w[n * 131 + k] : 0.f;
}

// ---------------------------------------------------------------------------
// gemm_nt: C[M x 256] = alpha * (A[M x K] @ B[256 x K]^T) + bias
// both A,B row-major, contraction along K (contiguous). grid (M/64, 4), 256 thr
// ---------------------------------------------------------------------------
__global__ __launch_bounds__(256) void gemm_nt_kernel(
    const float* __restrict__ A, const float* __restrict__ B,
    float* __restrict__ C, int K, float alpha, const float* __restrict__ bias)
{
    __shared__ float As[BK][BM + 4];
    __shared__ float Bs[BK][BN + 4];
    const int tid = threadIdx.x;
    const int bm = blockIdx.x, bn = blockIdx.y;
    const int tx = tid & 15, ty = tid >> 4;
    const int lrow = tid >> 2;          // 0..63
    const int lk = (tid & 3) << 2;      // 0,4,8,12
    const float* Ag = A + (size_t)(bm * BM + lrow) * K + lk;
    const float* Bg = B + (size_t)(bn * BN + lrow) * K + lk;
    float acc[4][4] = {};

    for (int k0 = 0; k0 < K; k0 += BK) {
        float4 av = *(const float4*)(Ag + k0);
        float4 bv = *(const float4*)(Bg + k0);
        __syncthreads();
        As[lk + 0][lrow] = av.x; As[lk + 1][lrow] = av.y;
        As[lk + 2][lrow] = av.z; As[lk + 3][lrow] = av.w;
        Bs[lk + 0][lrow] = bv.x; Bs[lk + 1][lrow] = bv.y;
        Bs[lk + 2][lrow] = bv.z; Bs[lk + 3][lrow] = bv.w;
        __syncthreads();
#pragma unroll
        for (int kk = 0; kk < BK; ++kk) {
            const float4 a = *(const float4*)&As[kk][ty << 2];
            const float4 b = *(const float4*)&Bs[kk][tx << 2];
            float ar[4] = {a.x, a.y, a.z, a.w};
            float br[4] = {b.x, b.y, b.z, b.w};
#pragma unroll
            for (int i = 0; i < 4; ++i)
#pragma unroll
                for (int j = 0; j < 4; ++j)
                    acc[i][j] += ar[i] * br[j];
        }
    }
    const int row = bm * BM + (ty << 2);
    const int col = bn * BN + (tx << 2);
    float bi[4] = {bias[col], bias[col + 1], bias[col + 2], bias[col + 3]};
#pragma unroll
    for (int i = 0; i < 4; ++i) {
        float4 o;
        o.x = alpha * acc[i][0] + bi[0];
        o.y = alpha * acc[i][1] + bi[1];
        o.z = alpha * acc[i][2] + bi[2];
        o.w = alpha * acc[i][3] + bi[3];
        *(float4*)(C + (size_t)(row + i) * CDIM + col) = o;
    }
}

// ---------------------------------------------------------------------------
// gemm_nn fused: x[b] = lrelu(gamma * (A[b] @ h1[b]) + beta)
// A[b]: 1024x1024, h1[b]: 1024x256. grid (16, 4, 8), 256 thr
// ---------------------------------------------------------------------------
__global__ __launch_bounds__(256) void gemm_nn_fused_kernel(
    const float* __restrict__ A, const float* __restrict__ Bm,
    const float* __restrict__ style, float* __restrict__ C)
{
    const int b = blockIdx.z;
    const float* Ag0 = A + (size_t)b * S_SEG * S_SEG;
    const float* Bg0 = Bm + (size_t)b * S_SEG * CDIM;
    __shared__ float As[BK][BM + 4];
    __shared__ float Bs[BK][BN + 4];
    const int tid = threadIdx.x;
    const int bm = blockIdx.x, bn = blockIdx.y;
    const int tx = tid & 15, ty = tid >> 4;
    const int lrow = tid >> 2;
    const int lk = (tid & 3) << 2;
    const float* Ag = Ag0 + (size_t)(bm * BM + lrow) * S_SEG + lk;
    const int bkk = tid >> 4;           // 0..15
    const int bn4 = (tid & 15) << 2;
    const float* Bg = Bg0 + (size_t)bkk * CDIM + bn * BN + bn4;
    float acc[4][4] = {};

    for (int k0 = 0; k0 < S_SEG; k0 += BK) {
        float4 av = *(const float4*)(Ag + k0);
        float4 bv = *(const float4*)(Bg + (size_t)k0 * CDIM);
        __syncthreads();
        As[lk + 0][lrow] = av.x; As[lk + 1][lrow] = av.y;
        As[lk + 2][lrow] = av.z; As[lk + 3][lrow] = av.w;
        *(float4*)&Bs[bkk][bn4] = bv;
        __syncthreads();
#pragma unroll
        for (int kk = 0; kk < BK; ++kk) {
            const float4 a = *(const float4*)&As[kk][ty << 2];
            const float4 bb = *(const float4*)&Bs[kk][tx << 2];
            float ar[4] = {a.x, a.y, a.z, a.w};
            float br[4] = {bb.x, bb.y, bb.z, bb.w};
#pragma unroll
            for (int i = 0; i < 4; ++i)
#pragma unroll
                for (int j = 0; j < 4; ++j)
                    acc[i][j] += ar[i] * br[j];
        }
    }
    const int row = bm * BM + (ty << 2);
    const int col = bn * BN + (tx << 2);
    const float* st = style + b * 2 * CDIM;
    float g[4], be[4];
#pragma unroll
    for (int j = 0; j < 4; ++j) {
        g[j] = st[col + j];
        be[j] = st[CDIM + col + j];
    }
    float* Cb = C + (size_t)b * S_SEG * CDIM;
#pragma unroll
    for (int i = 0; i < 4; ++i) {
        float4 o;
        o.x = lrelu(g[0] * acc[i][0] + be[0]);
        o.y = lrelu(g[1] * acc[i][1] + be[1]);
        o.z = lrelu(g[2] * acc[i][2] + be[2]);
        o.w = lrelu(g[3] * acc[i][3] + be[3]);
        *(float4*)(Cb + (size_t)(row + i) * CDIM + col) = o;
    }
}

// ---------------------------------------------------------------------------
// Tiny MLP per batch: m = abar@h1 ; s1 = lrelu(sc_c*m@W1^T+b1) ;
// style = sc_2c*s1@W2^T+b2.  grid 8 blocks x 512 threads
// ---------------------------------------------------------------------------
__global__ __launch_bounds__(512) void mlp_kernel(
    const float* __restrict__ h1, const float* __restrict__ abar,
    const float* __restrict__ W1, const float* __restrict__ b1,
    const float* __restrict__ W2, const float* __restrict__ b2,
    float* __restrict__ style, float sc_c, float sc_2c)
{
    const int b = blockIdx.x;
    const int t = threadIdx.x;
    __shared__ float pl[512];
    __shared__ float ml[256];
    __shared__ float s1[512];

    const float* h = h1 + (size_t)b * S_SEG * CDIM;
    const float* ab = abar + b * S_SEG;
    const int c = t & 255;
    const int half = t >> 8;
    float part = 0.f;
    for (int j = half * 512; j < half * 512 + 512; ++j)
        part += ab[j] * h[(size_t)j * CDIM + c];
    pl[t] = part;
    __syncthreads();
    if (t < 256) ml[t] = pl[t] + pl[t + 256];
    __syncthreads();

    float acc = 0.f;
    const float* w1r = W1 + (size_t)t * 256;
    for (int k = 0; k < 256; ++k) acc += ml[k] * w1r[k];
    acc = sc_c * acc + b1[t];
    s1[t] = lrelu(acc);
    __syncthreads();

    float acc2 = 0.f;
    const float* w2r = W2 + (size_t)t * 512;
    for (int k = 0; k < 512; ++k) acc2 += s1[k] * w2r[k];
    style[b * 512 + t] = sc_2c * acc2 + b2[t];
}

// ---------------------------------------------------------------------------
// color[r, c] = sc_c * (x[r,:] . rgb_w[c,:]) + rgb_b[c]; one wave per row
// grid 2048 x 256 (4 waves/block, 4 rows/block)
// ---------------------------------------------------------------------------
__global__ __launch_bounds__(256) void color_kernel(
    const float* __restrict__ x, const float* __restrict__ rgb_w,
    const float* __restrict__ rgb_b, float* __restrict__ color, float sc_c)
{
    const int wave = threadIdx.x >> 6;
    const int lane = threadIdx.x & 63;
    const int r = blockIdx.x * 4 + wave;  // 0..8191
    const float4 xv = *(const float4*)(x + (size_t)r * CDIM + lane * 4);
    float p[3];
#pragma unroll
    for (int cc = 0; cc < 3; ++cc) {
        const float4 wv = *(const float4*)(rgb_w + cc * CDIM + lane * 4);
        p[cc] = xv.x * wv.x + xv.y * wv.y + xv.z * wv.z + xv.w * wv.w;
    }
#pragma unroll
    for (int off = 32; off > 0; off >>= 1) {
#pragma unroll
        for (int cc = 0; cc < 3; ++cc) p[cc] += __shfl_down(p[cc], off);
    }
    if (lane == 0) {
#pragma unroll
        for (int cc = 0; cc < 3; ++cc)
            color[(size_t)r * 3 + cc] = sc_c * p[cc] + rgb_b[cc];
    }
}

// ---------------------------------------------------------------------------
// gather + tanh: out[b,c,p] = tanh(color[b, seg[b,p], c]); grid 8192 x 256
// ---------------------------------------------------------------------------
__global__ __launch_bounds__(256) void gather_kernel(
    const int* __restrict__ seg, const float* __restrict__ color,
    float* __restrict__ out)
{
    int idx = blockIdx.x * 256 + threadIdx.x;  // over B*N_PIX
    int b = idx >> 18;
    int p = idx & (N_PIX - 1);
    int s = seg[idx];
    const float* cp = color + ((size_t)b * S_SEG + s) * 3;
    out[((size_t)b * 3 + 0) * N_PIX + p] = tanhf(cp[0]);
    out[((size_t)b * 3 + 1) * N_PIX + p] = tanhf(cp[1]);
    out[((size_t)b * 3 + 2) * N_PIX + p] = tanhf(cp[2]);
}

// ---------------------------------------------------------------------------
extern "C" void kernel_launch(void* const* d_in, const int* in_sizes, int n_in,
                              void* d_out, int out_size, void* d_ws, size_t ws_size,
                              hipStream_t stream)
{
    (void)in_sizes; (void)n_in; (void)out_size; (void)ws_size;
    const float* z      = (const float*)d_in[0];
    const float* images = (const float*)d_in[1];
    const int*   seg    = (const int*)d_in[2];
    const float* A      = (const float*)d_in[3];
    const float* proj_w = (const float*)d_in[4];
    const float* proj_b = (const float*)d_in[5];
    const float* blk_w  = (const float*)d_in[6];
    const float* blk_b  = (const float*)d_in[7];
    const float* ada_w1 = (const float*)d_in[8];
    const float* ada_b1 = (const float*)d_in[9];
    const float* ada_w2 = (const float*)d_in[10];
    const float* ada_b2 = (const float*)d_in[11];
    const float* rgb_w  = (const float*)d_in[12];
    const float* rgb_b  = (const float*)d_in[13];
    float* out = (float*)d_out;

    float* ws = (float*)d_ws;
    float* sums   = ws;                 // 24576
    float* counts = ws + 24576;         // 8192
    float* abar   = ws + 32768;         // 8192
    float* style  = ws + 40960;         // 4096
    float* colr   = ws + 45056;         // 24576
    float* wpad   = ws + 69632;         // 36864
    float* xin    = ws + 106496;        // 1179648
    float* x      = ws + 1286144;       // 2097152
    float* h1     = ws + 3383296;       // 2097152

    const float sc_in = (float)sqrt(2.0 / 131.0);
    const float sc_c  = (float)sqrt(2.0 / 256.0);
    const float sc_2c = (float)sqrt(2.0 / 512.0);

    hipMemsetAsync(sums, 0, 32768 * sizeof(float), stream);
    seg_pool_kernel<<<dim3(BATCH * 32), 256, 0, stream>>>(images, seg, sums, counts);
    abar_kernel<<<dim3(32), 256, 0, stream>>>(A, abar);
    prep_xin_kernel<<<dim3((8192 * 144) / 256), 256, 0, stream>>>(sums, counts, z, xin);
    prep_wpad_kernel<<<dim3((256 * 144) / 256), 256, 0, stream>>>(proj_w, wpad);
    gemm_nt_kernel<<<dim3(128, 4), 256, 0, stream>>>(xin, wpad, x, 144, sc_in, proj_b);

    for (int i = 0; i < 8; ++i) {
        gemm_nt_kernel<<<dim3(128, 4), 256, 0, stream>>>(
            x, blk_w + (size_t)i * CDIM * CDIM, h1, CDIM, sc_c, blk_b + i * CDIM);
        mlp_kernel<<<dim3(8), 512, 0, stream>>>(
            h1, abar, ada_w1 + (size_t)i * 512 * 256, ada_b1 + i * 512,
            ada_w2 + (size_t)i * 512 * 512, ada_b2 + i * 512, style, sc_c, sc_2c);
        gemm_nn_fused_kernel<<<dim3(16, 4, 8), 256, 0, stream>>>(A, h1, style, x);
    }

    color_kernel<<<dim3(2048), 256, 0, stream>>>(x, rgb_w, rgb_b, colr, sc_c);
    gather_kernel<<<dim3(8192), 256, 0, stream>>>(seg, colr, out);
}

// Round 2
// 1243.969 us; speedup vs baseline: 1.8048x; 1.8048x over previous
//
#include <hip/hip_runtime.h>
#include <math.h>

#define N_PIX (512*512)
#define S_SEG 1024
#define CDIM  256
#define BATCH 8

#define BM 64
#define BN 64
#define BK 16

__device__ __forceinline__ float lrelu(float v) { return v > 0.f ? v : 0.2f * v; }

// ---------------------------------------------------------------------------
// Segment pooling: per-block LDS bins, then atomic flush to global sums/counts
// ---------------------------------------------------------------------------
__global__ __launch_bounds__(256) void seg_pool_kernel(
    const float* __restrict__ images, const int* __restrict__ seg,
    float* __restrict__ sums, float* __restrict__ counts)
{
    __shared__ float bins[S_SEG * 4];
    const int b = blockIdx.x >> 5;
    const int chunk = blockIdx.x & 31;
    for (int i = threadIdx.x; i < S_SEG * 4; i += 256) bins[i] = 0.f;
    __syncthreads();

    const int pix_per_block = N_PIX / 32;  // 8192
    const int base = chunk * pix_per_block;
    const float* im = images + (size_t)b * 3 * N_PIX;
    const int* sg = seg + (size_t)b * N_PIX;

    for (int it = 0; it < pix_per_block / 256; ++it) {
        int p = base + it * 256 + threadIdx.x;
        int s = sg[p];
        float r = im[p];
        float g = im[N_PIX + p];
        float bl = im[2 * N_PIX + p];
        atomicAdd(&bins[s * 4 + 0], r);
        atomicAdd(&bins[s * 4 + 1], g);
        atomicAdd(&bins[s * 4 + 2], bl);
        atomicAdd(&bins[s * 4 + 3], 1.f);
    }
    __syncthreads();
    for (int s = threadIdx.x; s < S_SEG; s += 256) {
        float4 v = *(const float4*)&bins[s * 4];
        atomicAdd(&sums[((size_t)b * S_SEG + s) * 3 + 0], v.x);
        atomicAdd(&sums[((size_t)b * S_SEG + s) * 3 + 1], v.y);
        atomicAdd(&sums[((size_t)b * S_SEG + s) * 3 + 2], v.z);
        atomicAdd(&counts[(size_t)b * S_SEG + s], v.w);
    }
}

// ---------------------------------------------------------------------------
// abar[b,j] = mean_i A[b,i,j]; also sumabar[b] += abar[b,j]
// ---------------------------------------------------------------------------
__global__ __launch_bounds__(256) void abar_kernel(
    const float* __restrict__ A, float* __restrict__ abar,
    float* __restrict__ sumabar)
{
    int idx = blockIdx.x * 256 + threadIdx.x;   // 0..8191
    int b = idx >> 10, j = idx & 1023;
    const float* Ab = A + (size_t)b * S_SEG * S_SEG + j;
    float s = 0.f;
    for (int i = 0; i < S_SEG; ++i) s += Ab[(size_t)i * S_SEG];
    float v = s * (1.f / (float)S_SEG);
    abar[idx] = v;
    // block-local reduce then one atomic per block per batch (block spans 1/4 batch)
    __shared__ float red[256];
    red[threadIdx.x] = v;
    __syncthreads();
    for (int off = 128; off > 0; off >>= 1) {
        if (threadIdx.x < off) red[threadIdx.x] += red[threadIdx.x + off];
        __syncthreads();
    }
    if (threadIdx.x == 0) atomicAdd(&sumabar[b], red[0]);
}

// ---------------------------------------------------------------------------
// xin[r, c] (8192 x 144): c<3 -> feats, 3<=c<131 -> z, else 0
// ---------------------------------------------------------------------------
__global__ __launch_bounds__(256) void prep_xin_kernel(
    const float* __restrict__ sums, const float* __restrict__ counts,
    const float* __restrict__ z, float* __restrict__ xin)
{
    int idx = blockIdx.x * 256 + threadIdx.x;
    int r = idx / 144, c = idx % 144;
    int b = r >> 10;
    float v;
    if (c < 3)        v = sums[r * 3 + c] / (counts[r] + 1e-6f);
    else if (c < 131) v = z[b * 128 + (c - 3)];
    else              v = 0.f;
    xin[idx] = v;
}

__global__ __launch_bounds__(256) void prep_wpad_kernel(
    const float* __restrict__ proj_w, float* __restrict__ wpad)
{
    int idx = blockIdx.x * 256 + threadIdx.x;   // over 256*144
    int n = idx / 144, k = idx % 144;
    wpad[idx] = (k < 131) ? proj_w[n * 131 + k] : 0.f;
}

// ---------------------------------------------------------------------------
// gemm_nt: C[M x 256] = alpha * (A[M x K] @ B[256 x K]^T) + bias
// optional epilogue: mv[b*256+col] += sum_rows abar[row] * out   (atomic)
// ---------------------------------------------------------------------------
__global__ __launch_bounds__(256) void gemm_nt_kernel(
    const float* __restrict__ A, const float* __restrict__ B,
    float* __restrict__ C, int K, float alpha, const float* __restrict__ bias,
    const float* __restrict__ abar, float* __restrict__ mv)
{
    __shared__ float As[BK][BM + 4];
    __shared__ float Bs[BK][BN + 4];
    __shared__ float red[16][BN];
    const int tid = threadIdx.x;
    const int bm = blockIdx.x, bn = blockIdx.y;
    const int tx = tid & 15, ty = tid >> 4;
    const int lrow = tid >> 2;          // 0..63
    const int lk = (tid & 3) << 2;      // 0,4,8,12
    const float* Ag = A + (size_t)(bm * BM + lrow) * K + lk;
    const float* Bg = B + (size_t)(bn * BN + lrow) * K + lk;
    float acc[4][4] = {};

    for (int k0 = 0; k0 < K; k0 += BK) {
        float4 av = *(const float4*)(Ag + k0);
        float4 bv = *(const float4*)(Bg + k0);
        __syncthreads();
        As[lk + 0][lrow] = av.x; As[lk + 1][lrow] = av.y;
        As[lk + 2][lrow] = av.z; As[lk + 3][lrow] = av.w;
        Bs[lk + 0][lrow] = bv.x; Bs[lk + 1][lrow] = bv.y;
        Bs[lk + 2][lrow] = bv.z; Bs[lk + 3][lrow] = bv.w;
        __syncthreads();
#pragma unroll
        for (int kk = 0; kk < BK; ++kk) {
            const float4 a = *(const float4*)&As[kk][ty << 2];
            const float4 b = *(const float4*)&Bs[kk][tx << 2];
            float ar[4] = {a.x, a.y, a.z, a.w};
            float br[4] = {b.x, b.y, b.z, b.w};
#pragma unroll
            for (int i = 0; i < 4; ++i)
#pragma unroll
                for (int j = 0; j < 4; ++j)
                    acc[i][j] += ar[i] * br[j];
        }
    }
    const int row = bm * BM + (ty << 2);
    const int col = bn * BN + (tx << 2);
    float bi[4] = {bias[col], bias[col + 1], bias[col + 2], bias[col + 3]};
    float o[4][4];
#pragma unroll
    for (int i = 0; i < 4; ++i) {
        float4 ov;
        ov.x = o[i][0] = alpha * acc[i][0] + bi[0];
        ov.y = o[i][1] = alpha * acc[i][1] + bi[1];
        ov.z = o[i][2] = alpha * acc[i][2] + bi[2];
        ov.w = o[i][3] = alpha * acc[i][3] + bi[3];
        *(float4*)(C + (size_t)(row + i) * CDIM + col) = ov;
    }
    if (mv) {
        const int b = row >> 10;
        float p[4];
#pragma unroll
        for (int j = 0; j < 4; ++j) {
            p[j] = 0.f;
#pragma unroll
            for (int i = 0; i < 4; ++i)
                p[j] += abar[((row + i) & 1023) + (b << 10)] * o[i][j];
            red[ty][(tx << 2) + j] = p[j];
        }
        __syncthreads();
        if (tid < BN) {
            float s = 0.f;
#pragma unroll
            for (int t = 0; t < 16; ++t) s += red[t][tid];
            atomicAdd(&mv[b * CDIM + bn * BN + tid], s);
        }
    }
}

// ---------------------------------------------------------------------------
// gemm_nn fused: x[b] = lrelu(gamma * (A[b] @ h1[b]) + beta)
// epilogue also accumulates mv_next[b,col] += sum_rows abar[b,row]*x_out
// ---------------------------------------------------------------------------
__global__ __launch_bounds__(256) void gemm_nn_fused_kernel(
    const float* __restrict__ A, const float* __restrict__ Bm,
    const float* __restrict__ style, float* __restrict__ C,
    const float* __restrict__ abar, float* __restrict__ mv)
{
    const int b = blockIdx.z;
    const float* Ag0 = A + (size_t)b * S_SEG * S_SEG;
    const float* Bg0 = Bm + (size_t)b * S_SEG * CDIM;
    __shared__ float As[BK][BM + 4];
    __shared__ float Bs[BK][BN + 4];
    __shared__ float red[16][BN];
    const int tid = threadIdx.x;
    const int bm = blockIdx.x, bn = blockIdx.y;
    const int tx = tid & 15, ty = tid >> 4;
    const int lrow = tid >> 2;
    const int lk = (tid & 3) << 2;
    const float* Ag = Ag0 + (size_t)(bm * BM + lrow) * S_SEG + lk;
    const int bkk = tid >> 4;           // 0..15
    const int bn4 = (tid & 15) << 2;
    const float* Bg = Bg0 + (size_t)bkk * CDIM + bn * BN + bn4;
    float acc[4][4] = {};

    for (int k0 = 0; k0 < S_SEG; k0 += BK) {
        float4 av = *(const float4*)(Ag + k0);
        float4 bv = *(const float4*)(Bg + (size_t)k0 * CDIM);
        __syncthreads();
        As[lk + 0][lrow] = av.x; As[lk + 1][lrow] = av.y;
        As[lk + 2][lrow] = av.z; As[lk + 3][lrow] = av.w;
        *(float4*)&Bs[bkk][bn4] = bv;
        __syncthreads();
#pragma unroll
        for (int kk = 0; kk < BK; ++kk) {
            const float4 a = *(const float4*)&As[kk][ty << 2];
            const float4 bb = *(const float4*)&Bs[kk][tx << 2];
            float ar[4] = {a.x, a.y, a.z, a.w};
            float br[4] = {bb.x, bb.y, bb.z, bb.w};
#pragma unroll
            for (int i = 0; i < 4; ++i)
#pragma unroll
                for (int j = 0; j < 4; ++j)
                    acc[i][j] += ar[i] * br[j];
        }
    }
    const int row = bm * BM + (ty << 2);
    const int col = bn * BN + (tx << 2);
    const float* st = style + b * 2 * CDIM;
    float g[4], be[4];
#pragma unroll
    for (int j = 0; j < 4; ++j) {
        g[j] = st[col + j];
        be[j] = st[CDIM + col + j];
    }
    float* Cb = C + (size_t)b * S_SEG * CDIM;
    float o[4][4];
#pragma unroll
    for (int i = 0; i < 4; ++i) {
        float4 ov;
        ov.x = o[i][0] = lrelu(g[0] * acc[i][0] + be[0]);
        ov.y = o[i][1] = lrelu(g[1] * acc[i][1] + be[1]);
        ov.z = o[i][2] = lrelu(g[2] * acc[i][2] + be[2]);
        ov.w = o[i][3] = lrelu(g[3] * acc[i][3] + be[3]);
        *(float4*)(Cb + (size_t)(row + i) * CDIM + col) = ov;
    }
    // mv_next accumulation
    {
        float p[4];
#pragma unroll
        for (int j = 0; j < 4; ++j) {
            p[j] = 0.f;
#pragma unroll
            for (int i = 0; i < 4; ++i)
                p[j] += abar[(b << 10) + row + i] * o[i][j];
            red[ty][(tx << 2) + j] = p[j];
        }
        __syncthreads();
        if (tid < BN) {
            float s = 0.f;
#pragma unroll
            for (int t = 0; t < 16; ++t) s += red[t][tid];
            atomicAdd(&mv[b * CDIM + bn * BN + tid], s);
        }
    }
}

// ---------------------------------------------------------------------------
// Tiny MLP per batch, from mv (8 x 256) instead of h1 (8 MB):
// m = sc_c * mv @ Wblk^T + sumabar*blk_b ; s1 = lrelu(sc_c*m@W1^T+b1) ;
// style = sc_2c*s1@W2^T+b2.  grid 8 blocks x 512 threads
// ---------------------------------------------------------------------------
__global__ __launch_bounds__(512) void mlp2_kernel(
    const float* __restrict__ mv, const float* __restrict__ sumabar,
    const float* __restrict__ Wblk, const float* __restrict__ bblk,
    const float* __restrict__ W1, const float* __restrict__ b1,
    const float* __restrict__ W2, const float* __restrict__ b2,
    float* __restrict__ style, float sc_c, float sc_2c)
{
    const int b = blockIdx.x;
    const int t = threadIdx.x;
    __shared__ float mvs[256];
    __shared__ float m[256];
    __shared__ float s1[512];

    if (t < 256) mvs[t] = mv[b * 256 + t];
    __syncthreads();
    if (t < 256) {
        const float* wr = Wblk + (size_t)t * 256;
        float acc = 0.f;
#pragma unroll 4
        for (int k = 0; k < 64; ++k) {
            float4 w = *(const float4*)(wr + k * 4);
            float4 v = *(const float4*)(mvs + k * 4);
            acc += w.x * v.x + w.y * v.y + w.z * v.z + w.w * v.w;
        }
        m[t] = sc_c * acc + sumabar[b] * bblk[t];
    }
    __syncthreads();

    {
        const float* w1r = W1 + (size_t)t * 256;
        float acc = 0.f;
#pragma unroll 4
        for (int k = 0; k < 64; ++k) {
            float4 w = *(const float4*)(w1r + k * 4);
            float4 v = *(const float4*)(m + k * 4);
            acc += w.x * v.x + w.y * v.y + w.z * v.z + w.w * v.w;
        }
        s1[t] = lrelu(sc_c * acc + b1[t]);
    }
    __syncthreads();

    {
        const float* w2r = W2 + (size_t)t * 512;
        float acc = 0.f;
#pragma unroll 4
        for (int k = 0; k < 128; ++k) {
            float4 w = *(const float4*)(w2r + k * 4);
            float4 v = *(const float4*)(s1 + k * 4);
            acc += w.x * v.x + w.y * v.y + w.z * v.z + w.w * v.w;
        }
        style[b * 512 + t] = sc_2c * acc + b2[t];
    }
}

// ---------------------------------------------------------------------------
// color[r, c] = sc_c * (x[r,:] . rgb_w[c,:]) + rgb_b[c]; one wave per row
// ---------------------------------------------------------------------------
__global__ __launch_bounds__(256) void color_kernel(
    const float* __restrict__ x, const float* __restrict__ rgb_w,
    const float* __restrict__ rgb_b, float* __restrict__ color, float sc_c)
{
    const int wave = threadIdx.x >> 6;
    const int lane = threadIdx.x & 63;
    const int r = blockIdx.x * 4 + wave;  // 0..8191
    const float4 xv = *(const float4*)(x + (size_t)r * CDIM + lane * 4);
    float p[3];
#pragma unroll
    for (int cc = 0; cc < 3; ++cc) {
        const float4 wv = *(const float4*)(rgb_w + cc * CDIM + lane * 4);
        p[cc] = xv.x * wv.x + xv.y * wv.y + xv.z * wv.z + xv.w * wv.w;
    }
#pragma unroll
    for (int off = 32; off > 0; off >>= 1) {
#pragma unroll
        for (int cc = 0; cc < 3; ++cc) p[cc] += __shfl_down(p[cc], off);
    }
    if (lane == 0) {
#pragma unroll
        for (int cc = 0; cc < 3; ++cc)
            color[(size_t)r * 3 + cc] = sc_c * p[cc] + rgb_b[cc];
    }
}

// ---------------------------------------------------------------------------
// gather + tanh: out[b,c,p] = tanh(color[b, seg[b,p], c])
// ---------------------------------------------------------------------------
__global__ __launch_bounds__(256) void gather_kernel(
    const int* __restrict__ seg, const float* __restrict__ color,
    float* __restrict__ out)
{
    int idx = blockIdx.x * 256 + threadIdx.x;  // over B*N_PIX
    int b = idx >> 18;
    int p = idx & (N_PIX - 1);
    int s = seg[idx];
    const float* cp = color + ((size_t)b * S_SEG + s) * 3;
    out[((size_t)b * 3 + 0) * N_PIX + p] = tanhf(cp[0]);
    out[((size_t)b * 3 + 1) * N_PIX + p] = tanhf(cp[1]);
    out[((size_t)b * 3 + 2) * N_PIX + p] = tanhf(cp[2]);
}

// ---------------------------------------------------------------------------
extern "C" void kernel_launch(void* const* d_in, const int* in_sizes, int n_in,
                              void* d_out, int out_size, void* d_ws, size_t ws_size,
                              hipStream_t stream)
{
    (void)in_sizes; (void)n_in; (void)out_size; (void)ws_size;
    const float* z      = (const float*)d_in[0];
    const float* images = (const float*)d_in[1];
    const int*   seg    = (const int*)d_in[2];
    const float* A      = (const float*)d_in[3];
    const float* proj_w = (const float*)d_in[4];
    const float* proj_b = (const float*)d_in[5];
    const float* blk_w  = (const float*)d_in[6];
    const float* blk_b  = (const float*)d_in[7];
    const float* ada_w1 = (const float*)d_in[8];
    const float* ada_b1 = (const float*)d_in[9];
    const float* ada_w2 = (const float*)d_in[10];
    const float* ada_b2 = (const float*)d_in[11];
    const float* rgb_w  = (const float*)d_in[12];
    const float* rgb_b  = (const float*)d_in[13];
    float* out = (float*)d_out;

    float* ws = (float*)d_ws;
    // zeroed region: [sums 24576][counts 8192][sumabar 16][mv 9*2048=18432]
    float* sums    = ws;                  // 24576
    float* counts  = ws + 24576;          // 8192
    float* sumabar = ws + 32768;          // 16
    float* mv      = ws + 32784;          // 18432 (9 iterations x 8 x 256)
    float* abar    = ws + 51216;          // 8192
    float* style   = ws + 59408;          // 4096
    float* colr    = ws + 63504;          // 24576
    float* wpad    = ws + 88080;          // 36864
    float* xin     = ws + 124944;         // 1179648
    float* x       = ws + 1304592;        // 2097152
    float* h1      = ws + 3401744;        // 2097152

    const float sc_in = (float)sqrt(2.0 / 131.0);
    const float sc_c  = (float)sqrt(2.0 / 256.0);
    const float sc_2c = (float)sqrt(2.0 / 512.0);

    hipMemsetAsync(sums, 0, 51216 * sizeof(float), stream);
    seg_pool_kernel<<<dim3(BATCH * 32), 256, 0, stream>>>(images, seg, sums, counts);
    abar_kernel<<<dim3(32), 256, 0, stream>>>(A, abar, sumabar);
    prep_xin_kernel<<<dim3((8192 * 144) / 256), 256, 0, stream>>>(sums, counts, z, xin);
    prep_wpad_kernel<<<dim3((256 * 144) / 256), 256, 0, stream>>>(proj_w, wpad);
    // initial projection, accumulate mv_0
    gemm_nt_kernel<<<dim3(128, 4), 256, 0, stream>>>(xin, wpad, x, 144, sc_in, proj_b,
                                                     abar, mv);

    for (int i = 0; i < 8; ++i) {
        gemm_nt_kernel<<<dim3(128, 4), 256, 0, stream>>>(
            x, blk_w + (size_t)i * CDIM * CDIM, h1, CDIM, sc_c, blk_b + i * CDIM,
            nullptr, nullptr);
        mlp2_kernel<<<dim3(8), 512, 0, stream>>>(
            mv + i * 2048, sumabar,
            blk_w + (size_t)i * CDIM * CDIM, blk_b + i * CDIM,
            ada_w1 + (size_t)i * 512 * 256, ada_b1 + i * 512,
            ada_w2 + (size_t)i * 512 * 512, ada_b2 + i * 512, style, sc_c, sc_2c);
        gemm_nn_fused_kernel<<<dim3(16, 4, 8), 256, 0, stream>>>(
            A, h1, style, x, abar, mv + (i + 1) * 2048);
    }

    color_kernel<<<dim3(2048), 256, 0, stream>>>(x, rgb_w, rgb_b, colr, sc_c);
    gather_kernel<<<dim3(8192), 256, 0, stream>>>(seg, colr, out);
}

// Round 3
// 945.008 us; speedup vs baseline: 2.3758x; 1.3164x over previous
//
#include <hip/hip_runtime.h>
#include <math.h>

#define N_PIX (512*512)
#define S_SEG 1024
#define CDIM  256
#define BATCH 8

typedef __attribute__((ext_vector_type(4))) float f32x4;
typedef __attribute__((ext_vector_type(8))) short bf16x8;

__device__ __forceinline__ float lrelu(float v) { return v > 0.f ? v : 0.2f * v; }

__device__ __forceinline__ unsigned short bf16_hi(float x) {
    union { float f; unsigned int u; } v; v.f = x;
    unsigned int r = v.u + 0x7FFFu + ((v.u >> 16) & 1u);
    return (unsigned short)(r >> 16);
}
__device__ __forceinline__ float bf16_tof(unsigned short h) {
    union { float f; unsigned int u; } v; v.u = ((unsigned int)h) << 16;
    return v.f;
}

// ---------------------------------------------------------------------------
// Segment pooling (unchanged)
// ---------------------------------------------------------------------------
__global__ __launch_bounds__(256) void seg_pool_kernel(
    const float* __restrict__ images, const int* __restrict__ seg,
    float* __restrict__ sums, float* __restrict__ counts)
{
    __shared__ float bins[S_SEG * 4];
    const int b = blockIdx.x >> 5;
    const int chunk = blockIdx.x & 31;
    for (int i = threadIdx.x; i < S_SEG * 4; i += 256) bins[i] = 0.f;
    __syncthreads();

    const int pix_per_block = N_PIX / 32;  // 8192
    const int base = chunk * pix_per_block;
    const float* im = images + (size_t)b * 3 * N_PIX;
    const int* sg = seg + (size_t)b * N_PIX;

    for (int it = 0; it < pix_per_block / 256; ++it) {
        int p = base + it * 256 + threadIdx.x;
        int s = sg[p];
        float r = im[p];
        float g = im[N_PIX + p];
        float bl = im[2 * N_PIX + p];
        atomicAdd(&bins[s * 4 + 0], r);
        atomicAdd(&bins[s * 4 + 1], g);
        atomicAdd(&bins[s * 4 + 2], bl);
        atomicAdd(&bins[s * 4 + 3], 1.f);
    }
    __syncthreads();
    for (int s = threadIdx.x; s < S_SEG; s += 256) {
        float4 v = *(const float4*)&bins[s * 4];
        atomicAdd(&sums[((size_t)b * S_SEG + s) * 3 + 0], v.x);
        atomicAdd(&sums[((size_t)b * S_SEG + s) * 3 + 1], v.y);
        atomicAdd(&sums[((size_t)b * S_SEG + s) * 3 + 2], v.z);
        atomicAdd(&counts[(size_t)b * S_SEG + s], v.w);
    }
}

// ---------------------------------------------------------------------------
// abar + sumabar (unchanged)
// ---------------------------------------------------------------------------
__global__ __launch_bounds__(256) void abar_kernel(
    const float* __restrict__ A, float* __restrict__ abar,
    float* __restrict__ sumabar)
{
    int idx = blockIdx.x * 256 + threadIdx.x;
    int b = idx >> 10;
    const float* Ab = A + (size_t)b * S_SEG * S_SEG + (idx & 1023);
    float s = 0.f;
    for (int i = 0; i < S_SEG; ++i) s += Ab[(size_t)i * S_SEG];
    float v = s * (1.f / (float)S_SEG);
    abar[idx] = v;
    __shared__ float red[256];
    red[threadIdx.x] = v;
    __syncthreads();
    for (int off = 128; off > 0; off >>= 1) {
        if (threadIdx.x < off) red[threadIdx.x] += red[threadIdx.x + off];
        __syncthreads();
    }
    if (threadIdx.x == 0) atomicAdd(&sumabar[b], red[0]);
}

__global__ __launch_bounds__(256) void prep_xin_kernel(
    const float* __restrict__ sums, const float* __restrict__ counts,
    const float* __restrict__ z, float* __restrict__ xin)
{
    int idx = blockIdx.x * 256 + threadIdx.x;
    int r = idx / 144, c = idx % 144;
    int b = r >> 10;
    float v;
    if (c < 3)        v = sums[r * 3 + c] / (counts[r] + 1e-6f);
    else if (c < 131) v = z[b * 128 + (c - 3)];
    else              v = 0.f;
    xin[idx] = v;
}

__global__ __launch_bounds__(256) void prep_wpad_kernel(
    const float* __restrict__ proj_w, float* __restrict__ wpad)
{
    int idx = blockIdx.x * 256 + threadIdx.x;
    int n = idx / 144, k = idx % 144;
    wpad[idx] = (k < 131) ? proj_w[n * 131 + k] : 0.f;
}

// ---------------------------------------------------------------------------
// fp32 -> (bf16 hi, bf16 lo) split, with scale. float4-vectorized.
// ---------------------------------------------------------------------------
__global__ __launch_bounds__(256) void conv_split_kernel(
    const float* __restrict__ in, unsigned short* __restrict__ hi,
    unsigned short* __restrict__ lo, float scale, unsigned int n4)
{
    unsigned int idx = blockIdx.x * 256 + threadIdx.x;
    if (idx >= n4) return;
    float4 v = ((const float4*)in)[idx];
    ushort4 h, l;
    float a;
    a = v.x * scale; h.x = bf16_hi(a); l.x = bf16_hi(a - bf16_tof(h.x));
    a = v.y * scale; h.y = bf16_hi(a); l.y = bf16_hi(a - bf16_tof(h.y));
    a = v.z * scale; h.z = bf16_hi(a); l.z = bf16_hi(a - bf16_tof(h.z));
    a = v.w * scale; h.w = bf16_hi(a); l.w = bf16_hi(a - bf16_tof(h.w));
    ((ushort4*)hi)[idx] = h;
    ((ushort4*)lo)[idx] = l;
}

// ---------------------------------------------------------------------------
// staging: global -> LDS via global_load_lds w=16, pre-swizzled global source
// (rule #21). Tile rows are 64 bf16 = 8 chunks of 16B. chunk' = chunk ^ (row&7)
// ---------------------------------------------------------------------------
__device__ __forceinline__ void stage_tile(
    const unsigned short* __restrict__ g, int grow,
    unsigned short* lds, int tid, int nissue)
{
    for (int i = 0; i < nissue; ++i) {
        int c = i * 256 + tid;
        int row = c >> 3, cin = c & 7;
        int cs = cin ^ (row & 7);
        const unsigned short* src = g + (size_t)row * grow + cs * 8;
        unsigned short* dst = lds + (size_t)(i * 256 + (tid & ~63)) * 8;
        __builtin_amdgcn_global_load_lds(
            (const __attribute__((address_space(1))) unsigned int*)src,
            (__attribute__((address_space(3))) unsigned int*)dst, 16, 0, 0);
    }
}

__device__ __forceinline__ int frag_idx(int row, int ks, int l)
{
    int chunk = (ks * 4 + (l >> 4)) ^ (row & 7);
    return row * 64 + chunk * 8;
}

// ---------------------------------------------------------------------------
// MFMA split-3 GEMM: x_out = lrelu(gamma*(A @ h1) + beta), + mv epilogue,
// also emits x as bf16 hi/lo. Block 128x64, BK=64, 4 waves (wave-tile 64x32).
// grid (8, 4, 8)
// ---------------------------------------------------------------------------
__global__ __launch_bounds__(256) void gemm_nn_mfma_kernel(
    const unsigned short* __restrict__ Ah_g, const unsigned short* __restrict__ Al_g,
    const unsigned short* __restrict__ Hh_g, const unsigned short* __restrict__ Hl_g,
    const float* __restrict__ style, const float* __restrict__ abar,
    float* __restrict__ x, unsigned short* __restrict__ xh,
    unsigned short* __restrict__ xl, float* __restrict__ mv)
{
    __shared__ __align__(16) unsigned short Ah_s[128 * 64];
    __shared__ __align__(16) unsigned short Al_s[128 * 64];
    __shared__ __align__(16) unsigned short Bh_s[64 * 64];
    __shared__ __align__(16) unsigned short Bl_s[64 * 64];
    __shared__ float mvred[64];
    const int tid = threadIdx.x;
    const int b = blockIdx.z, bm = blockIdx.x, bn = blockIdx.y;
    const int l = tid & 63, wave = tid >> 6;
    const int wr = wave >> 1, wc = wave & 1;
    if (tid < 64) mvred[tid] = 0.f;

    const unsigned short* Ag_h = Ah_g + ((size_t)(b * 1024 + bm * 128)) * 1024;
    const unsigned short* Ag_l = Al_g + ((size_t)(b * 1024 + bm * 128)) * 1024;
    const unsigned short* Hg_h = Hh_g + ((size_t)(b * 256 + bn * 64)) * 1024;
    const unsigned short* Hg_l = Hl_g + ((size_t)(b * 256 + bn * 64)) * 1024;

    f32x4 acc[4][2];
#pragma unroll
    for (int i = 0; i < 4; ++i)
#pragma unroll
        for (int j = 0; j < 2; ++j) acc[i][j] = (f32x4){0.f, 0.f, 0.f, 0.f};

    for (int kt = 0; kt < 16; ++kt) {
        stage_tile(Ag_h + kt * 64, 1024, Ah_s, tid, 4);
        stage_tile(Ag_l + kt * 64, 1024, Al_s, tid, 4);
        stage_tile(Hg_h + kt * 64, 1024, Bh_s, tid, 2);
        stage_tile(Hg_l + kt * 64, 1024, Bl_s, tid, 2);
        __syncthreads();
#pragma unroll
        for (int ks = 0; ks < 2; ++ks) {
            bf16x8 ah[4], al[4], bh[2], bl[2];
#pragma unroll
            for (int fm = 0; fm < 4; ++fm) {
                int row = wr * 64 + fm * 16 + (l & 15);
                int idx = frag_idx(row, ks, l);
                ah[fm] = *(const bf16x8*)&Ah_s[idx];
                al[fm] = *(const bf16x8*)&Al_s[idx];
            }
#pragma unroll
            for (int fn = 0; fn < 2; ++fn) {
                int row = wc * 32 + fn * 16 + (l & 15);
                int idx = frag_idx(row, ks, l);
                bh[fn] = *(const bf16x8*)&Bh_s[idx];
                bl[fn] = *(const bf16x8*)&Bl_s[idx];
            }
#pragma unroll
            for (int fm = 0; fm < 4; ++fm)
#pragma unroll
                for (int fn = 0; fn < 2; ++fn) {
                    acc[fm][fn] = __builtin_amdgcn_mfma_f32_16x16x32_bf16(ah[fm], bh[fn], acc[fm][fn], 0, 0, 0);
                    acc[fm][fn] = __builtin_amdgcn_mfma_f32_16x16x32_bf16(ah[fm], bl[fn], acc[fm][fn], 0, 0, 0);
                    acc[fm][fn] = __builtin_amdgcn_mfma_f32_16x16x32_bf16(al[fm], bh[fn], acc[fm][fn], 0, 0, 0);
                }
        }
        __syncthreads();
    }

    const float* st = style + b * 2 * CDIM;
#pragma unroll
    for (int fn = 0; fn < 2; ++fn) {
        int col = bn * 64 + wc * 32 + fn * 16 + (l & 15);
        float ga = st[col], be = st[CDIM + col];
        float pmv = 0.f;
#pragma unroll
        for (int fm = 0; fm < 4; ++fm) {
            int m0 = bm * 128 + wr * 64 + fm * 16 + (l >> 4) * 4;
#pragma unroll
            for (int r = 0; r < 4; ++r) {
                float v = lrelu(ga * acc[fm][fn][r] + be);
                size_t off = ((size_t)(b * 1024 + m0 + r)) * 256 + col;
                x[off] = v;
                unsigned short h = bf16_hi(v);
                xh[off] = h;
                xl[off] = bf16_hi(v - bf16_tof(h));
                pmv += abar[b * 1024 + m0 + r] * v;
            }
        }
        atomicAdd(&mvred[wc * 32 + fn * 16 + (l & 15)], pmv);
    }
    __syncthreads();
    if (tid < 64) atomicAdd(&mv[b * 256 + bn * 64 + tid], mvred[tid]);
}

// ---------------------------------------------------------------------------
// MFMA split-3 GEMM: h1 = x @ W'^T + b  (W' pre-scaled by sc_c), output
// written TRANSPOSED as bf16 hi/lo: h1t[b][c][s]. grid (64, 4); K=256.
// ---------------------------------------------------------------------------
__global__ __launch_bounds__(256) void gemm_nt_mfma_kernel(
    const unsigned short* __restrict__ xh_g, const unsigned short* __restrict__ xl_g,
    const unsigned short* __restrict__ Wh, const unsigned short* __restrict__ Wl,
    const float* __restrict__ bias,
    unsigned short* __restrict__ h1t_h, unsigned short* __restrict__ h1t_l)
{
    __shared__ __align__(16) unsigned short Ah_s[128 * 64];
    __shared__ __align__(16) unsigned short Al_s[128 * 64];
    __shared__ __align__(16) unsigned short Bh_s[64 * 64];
    __shared__ __align__(16) unsigned short Bl_s[64 * 64];
    const int tid = threadIdx.x;
    const int bm = blockIdx.x, bn = blockIdx.y;
    const int l = tid & 63, wave = tid >> 6;
    const int wr = wave >> 1, wc = wave & 1;
    const int row0 = bm * 128;
    const int b = row0 >> 10;

    const unsigned short* Ag_h = xh_g + (size_t)row0 * 256;
    const unsigned short* Ag_l = xl_g + (size_t)row0 * 256;
    const unsigned short* Bg_h = Wh + (size_t)(bn * 64) * 256;
    const unsigned short* Bg_l = Wl + (size_t)(bn * 64) * 256;

    f32x4 acc[4][2];
#pragma unroll
    for (int i = 0; i < 4; ++i)
#pragma unroll
        for (int j = 0; j < 2; ++j) acc[i][j] = (f32x4){0.f, 0.f, 0.f, 0.f};

    for (int kt = 0; kt < 4; ++kt) {
        stage_tile(Ag_h + kt * 64, 256, Ah_s, tid, 4);
        stage_tile(Ag_l + kt * 64, 256, Al_s, tid, 4);
        stage_tile(Bg_h + kt * 64, 256, Bh_s, tid, 2);
        stage_tile(Bg_l + kt * 64, 256, Bl_s, tid, 2);
        __syncthreads();
#pragma unroll
        for (int ks = 0; ks < 2; ++ks) {
            bf16x8 ah[4], al[4], bh[2], bl[2];
#pragma unroll
            for (int fm = 0; fm < 4; ++fm) {
                int row = wr * 64 + fm * 16 + (l & 15);
                int idx = frag_idx(row, ks, l);
                ah[fm] = *(const bf16x8*)&Ah_s[idx];
                al[fm] = *(const bf16x8*)&Al_s[idx];
            }
#pragma unroll
            for (int fn = 0; fn < 2; ++fn) {
                int row = wc * 32 + fn * 16 + (l & 15);
                int idx = frag_idx(row, ks, l);
                bh[fn] = *(const bf16x8*)&Bh_s[idx];
                bl[fn] = *(const bf16x8*)&Bl_s[idx];
            }
#pragma unroll
            for (int fm = 0; fm < 4; ++fm)
#pragma unroll
                for (int fn = 0; fn < 2; ++fn) {
                    acc[fm][fn] = __builtin_amdgcn_mfma_f32_16x16x32_bf16(ah[fm], bh[fn], acc[fm][fn], 0, 0, 0);
                    acc[fm][fn] = __builtin_amdgcn_mfma_f32_16x16x32_bf16(ah[fm], bl[fn], acc[fm][fn], 0, 0, 0);
                    acc[fm][fn] = __builtin_amdgcn_mfma_f32_16x16x32_bf16(al[fm], bh[fn], acc[fm][fn], 0, 0, 0);
                }
        }
        __syncthreads();
    }

#pragma unroll
    for (int fn = 0; fn < 2; ++fn) {
        int col = bn * 64 + wc * 32 + fn * 16 + (l & 15);
        float bi = bias[col];
#pragma unroll
        for (int fm = 0; fm < 4; ++fm) {
            int s0 = (row0 & 1023) + wr * 64 + fm * 16 + (l >> 4) * 4;
            float v0 = acc[fm][fn][0] + bi;
            float v1 = acc[fm][fn][1] + bi;
            float v2 = acc[fm][fn][2] + bi;
            float v3 = acc[fm][fn][3] + bi;
            ushort4 hv, lv;
            hv.x = bf16_hi(v0); lv.x = bf16_hi(v0 - bf16_tof(hv.x));
            hv.y = bf16_hi(v1); lv.y = bf16_hi(v1 - bf16_tof(hv.y));
            hv.z = bf16_hi(v2); lv.z = bf16_hi(v2 - bf16_tof(hv.z));
            hv.w = bf16_hi(v3); lv.w = bf16_hi(v3 - bf16_tof(hv.w));
            size_t off = ((size_t)(b * 256 + col)) * 1024 + s0;
            *(ushort4*)&h1t_h[off] = hv;
            *(ushort4*)&h1t_l[off] = lv;
        }
    }
}

// ---------------------------------------------------------------------------
// fp32 VALU gemm_nt (proj only): x = alpha*(xin @ wpad^T) + bias,
// + mv epilogue + bf16 hi/lo emit. grid (128, 4)
// ---------------------------------------------------------------------------
#define BM 64
#define BN 64
#define BK 16
__global__ __launch_bounds__(256) void gemm_nt_kernel(
    const float* __restrict__ A, const float* __restrict__ B,
    float* __restrict__ C, int K, float alpha, const float* __restrict__ bias,
    const float* __restrict__ abar, float* __restrict__ mv,
    unsigned short* __restrict__ xh, unsigned short* __restrict__ xl)
{
    __shared__ float As[BK][BM + 4];
    __shared__ float Bs[BK][BN + 4];
    __shared__ float red[16][BN];
    const int tid = threadIdx.x;
    const int bm = blockIdx.x, bn = blockIdx.y;
    const int tx = tid & 15, ty = tid >> 4;
    const int lrow = tid >> 2;
    const int lk = (tid & 3) << 2;
    const float* Ag = A + (size_t)(bm * BM + lrow) * K + lk;
    const float* Bg = B + (size_t)(bn * BN + lrow) * K + lk;
    float acc[4][4] = {};

    for (int k0 = 0; k0 < K; k0 += BK) {
        float4 av = *(const float4*)(Ag + k0);
        float4 bv = *(const float4*)(Bg + k0);
        __syncthreads();
        As[lk + 0][lrow] = av.x; As[lk + 1][lrow] = av.y;
        As[lk + 2][lrow] = av.z; As[lk + 3][lrow] = av.w;
        Bs[lk + 0][lrow] = bv.x; Bs[lk + 1][lrow] = bv.y;
        Bs[lk + 2][lrow] = bv.z; Bs[lk + 3][lrow] = bv.w;
        __syncthreads();
#pragma unroll
        for (int kk = 0; kk < BK; ++kk) {
            const float4 a = *(const float4*)&As[kk][ty << 2];
            const float4 b = *(const float4*)&Bs[kk][tx << 2];
            float ar[4] = {a.x, a.y, a.z, a.w};
            float br[4] = {b.x, b.y, b.z, b.w};
#pragma unroll
            for (int i = 0; i < 4; ++i)
#pragma unroll
                for (int j = 0; j < 4; ++j)
                    acc[i][j] += ar[i] * br[j];
        }
    }
    const int row = bm * BM + (ty << 2);
    const int col = bn * BN + (tx << 2);
    const int b = row >> 10;
    float bi[4] = {bias[col], bias[col + 1], bias[col + 2], bias[col + 3]};
    float o[4][4];
#pragma unroll
    for (int i = 0; i < 4; ++i) {
        float4 ov;
        ov.x = o[i][0] = alpha * acc[i][0] + bi[0];
        ov.y = o[i][1] = alpha * acc[i][1] + bi[1];
        ov.z = o[i][2] = alpha * acc[i][2] + bi[2];
        ov.w = o[i][3] = alpha * acc[i][3] + bi[3];
        *(float4*)(C + (size_t)(row + i) * CDIM + col) = ov;
#pragma unroll
        for (int j = 0; j < 4; ++j) {
            size_t off = (size_t)(row + i) * CDIM + col + j;
            unsigned short h = bf16_hi(o[i][j]);
            xh[off] = h;
            xl[off] = bf16_hi(o[i][j] - bf16_tof(h));
        }
    }
    {
        float p[4];
#pragma unroll
        for (int j = 0; j < 4; ++j) {
            p[j] = 0.f;
#pragma unroll
            for (int i = 0; i < 4; ++i)
                p[j] += abar[((row + i) & 1023) + (b << 10)] * o[i][j];
            red[ty][(tx << 2) + j] = p[j];
        }
        __syncthreads();
        if (tid < BN) {
            float s = 0.f;
#pragma unroll
            for (int t = 0; t < 16; ++t) s += red[t][tid];
            atomicAdd(&mv[b * CDIM + bn * BN + tid], s);
        }
    }
}

// ---------------------------------------------------------------------------
// Tiny per-batch MLP (unchanged from R2)
// ---------------------------------------------------------------------------
__global__ __launch_bounds__(512) void mlp2_kernel(
    const float* __restrict__ mv, const float* __restrict__ sumabar,
    const float* __restrict__ Wblk, const float* __restrict__ bblk,
    const float* __restrict__ W1, const float* __restrict__ b1,
    const float* __restrict__ W2, const float* __restrict__ b2,
    float* __restrict__ style, float sc_c, float sc_2c)
{
    const int b = blockIdx.x;
    const int t = threadIdx.x;
    __shared__ float mvs[256];
    __shared__ float m[256];
    __shared__ float s1[512];

    if (t < 256) mvs[t] = mv[b * 256 + t];
    __syncthreads();
    if (t < 256) {
        const float* wr = Wblk + (size_t)t * 256;
        float acc = 0.f;
#pragma unroll 4
        for (int k = 0; k < 64; ++k) {
            float4 w = *(const float4*)(wr + k * 4);
            float4 v = *(const float4*)(mvs + k * 4);
            acc += w.x * v.x + w.y * v.y + w.z * v.z + w.w * v.w;
        }
        m[t] = sc_c * acc + sumabar[b] * bblk[t];
    }
    __syncthreads();
    {
        const float* w1r = W1 + (size_t)t * 256;
        float acc = 0.f;
#pragma unroll 4
        for (int k = 0; k < 64; ++k) {
            float4 w = *(const float4*)(w1r + k * 4);
            float4 v = *(const float4*)(m + k * 4);
            acc += w.x * v.x + w.y * v.y + w.z * v.z + w.w * v.w;
        }
        s1[t] = lrelu(sc_c * acc + b1[t]);
    }
    __syncthreads();
    {
        const float* w2r = W2 + (size_t)t * 512;
        float acc = 0.f;
#pragma unroll 4
        for (int k = 0; k < 128; ++k) {
            float4 w = *(const float4*)(w2r + k * 4);
            float4 v = *(const float4*)(s1 + k * 4);
            acc += w.x * v.x + w.y * v.y + w.z * v.z + w.w * v.w;
        }
        style[b * 512 + t] = sc_2c * acc + b2[t];
    }
}

// ---------------------------------------------------------------------------
// color + gather (unchanged)
// ---------------------------------------------------------------------------
__global__ __launch_bounds__(256) void color_kernel(
    const float* __restrict__ x, const float* __restrict__ rgb_w,
    const float* __restrict__ rgb_b, float* __restrict__ color, float sc_c)
{
    const int wave = threadIdx.x >> 6;
    const int lane = threadIdx.x & 63;
    const int r = blockIdx.x * 4 + wave;
    const float4 xv = *(const float4*)(x + (size_t)r * CDIM + lane * 4);
    float p[3];
#pragma unroll
    for (int cc = 0; cc < 3; ++cc) {
        const float4 wv = *(const float4*)(rgb_w + cc * CDIM + lane * 4);
        p[cc] = xv.x * wv.x + xv.y * wv.y + xv.z * wv.z + xv.w * wv.w;
    }
#pragma unroll
    for (int off = 32; off > 0; off >>= 1) {
#pragma unroll
        for (int cc = 0; cc < 3; ++cc) p[cc] += __shfl_down(p[cc], off);
    }
    if (lane == 0) {
#pragma unroll
        for (int cc = 0; cc < 3; ++cc)
            color[(size_t)r * 3 + cc] = sc_c * p[cc] + rgb_b[cc];
    }
}

__global__ __launch_bounds__(256) void gather_kernel(
    const int* __restrict__ seg, const float* __restrict__ color,
    float* __restrict__ out)
{
    int idx = blockIdx.x * 256 + threadIdx.x;
    int b = idx >> 18;
    int p = idx & (N_PIX - 1);
    int s = seg[idx];
    const float* cp = color + ((size_t)b * S_SEG + s) * 3;
    out[((size_t)b * 3 + 0) * N_PIX + p] = tanhf(cp[0]);
    out[((size_t)b * 3 + 1) * N_PIX + p] = tanhf(cp[1]);
    out[((size_t)b * 3 + 2) * N_PIX + p] = tanhf(cp[2]);
}

// ---------------------------------------------------------------------------
extern "C" void kernel_launch(void* const* d_in, const int* in_sizes, int n_in,
                              void* d_out, int out_size, void* d_ws, size_t ws_size,
                              hipStream_t stream)
{
    (void)in_sizes; (void)n_in; (void)out_size; (void)ws_size;
    const float* z      = (const float*)d_in[0];
    const float* images = (const float*)d_in[1];
    const int*   seg    = (const int*)d_in[2];
    const float* A      = (const float*)d_in[3];
    const float* proj_w = (const float*)d_in[4];
    const float* proj_b = (const float*)d_in[5];
    const float* blk_w  = (const float*)d_in[6];
    const float* blk_b  = (const float*)d_in[7];
    const float* ada_w1 = (const float*)d_in[8];
    const float* ada_b1 = (const float*)d_in[9];
    const float* ada_w2 = (const float*)d_in[10];
    const float* ada_b2 = (const float*)d_in[11];
    const float* rgb_w  = (const float*)d_in[12];
    const float* rgb_b  = (const float*)d_in[13];
    float* out = (float*)d_out;

    float* ws = (float*)d_ws;
    float* sums    = ws;                  // 24576
    float* counts  = ws + 24576;          // 8192
    float* sumabar = ws + 32768;          // 16
    float* mv      = ws + 32784;          // 18432
    float* abar    = ws + 51216;          // 8192
    float* style   = ws + 59408;          // 4096
    float* colr    = ws + 63504;          // 24576
    float* wpad    = ws + 88080;          // 36864
    float* xin     = ws + 124944;         // 1179648 -> ends 1304592
    float* x       = ws + 1304592;        // 2097152 -> ends 3401744
    unsigned short* xh    = (unsigned short*)(ws + 3401744);   // 2M ushort
    unsigned short* xl    = (unsigned short*)(ws + 4450320);
    unsigned short* h1t_h = (unsigned short*)(ws + 5498896);
    unsigned short* h1t_l = (unsigned short*)(ws + 6547472);
    unsigned short* Ah    = (unsigned short*)(ws + 7596048);   // 8M ushort
    unsigned short* Al    = (unsigned short*)(ws + 11790352);
    unsigned short* Wh    = (unsigned short*)(ws + 15984656);  // 512K ushort
    unsigned short* Wl    = (unsigned short*)(ws + 16246800);  // ends 16508944

    const float sc_in = (float)sqrt(2.0 / 131.0);
    const float sc_c  = (float)sqrt(2.0 / 256.0);
    const float sc_2c = (float)sqrt(2.0 / 512.0);

    hipMemsetAsync(sums, 0, 51216 * sizeof(float), stream);
    seg_pool_kernel<<<dim3(BATCH * 32), 256, 0, stream>>>(images, seg, sums, counts);
    abar_kernel<<<dim3(32), 256, 0, stream>>>(A, abar, sumabar);
    prep_xin_kernel<<<dim3((8192 * 144) / 256), 256, 0, stream>>>(sums, counts, z, xin);
    prep_wpad_kernel<<<dim3((256 * 144) / 256), 256, 0, stream>>>(proj_w, wpad);
    conv_split_kernel<<<dim3(8192), 256, 0, stream>>>(A, Ah, Al, 1.0f, 2097152u);
    conv_split_kernel<<<dim3(512), 256, 0, stream>>>(blk_w, Wh, Wl, sc_c, 131072u);

    gemm_nt_kernel<<<dim3(128, 4), 256, 0, stream>>>(xin, wpad, x, 144, sc_in, proj_b,
                                                     abar, mv, xh, xl);

    for (int i = 0; i < 8; ++i) {
        mlp2_kernel<<<dim3(8), 512, 0, stream>>>(
            mv + i * 2048, sumabar,
            blk_w + (size_t)i * CDIM * CDIM, blk_b + i * CDIM,
            ada_w1 + (size_t)i * 512 * 256, ada_b1 + i * 512,
            ada_w2 + (size_t)i * 512 * 512, ada_b2 + i * 512, style, sc_c, sc_2c);
        gemm_nt_mfma_kernel<<<dim3(64, 4), 256, 0, stream>>>(
            xh, xl, Wh + (size_t)i * 65536, Wl + (size_t)i * 65536,
            blk_b + i * CDIM, h1t_h, h1t_l);
        gemm_nn_mfma_kernel<<<dim3(8, 4, 8), 256, 0, stream>>>(
            Ah, Al, h1t_h, h1t_l, style, abar, x, xh, xl, mv + (i + 1) * 2048);
    }

    color_kernel<<<dim3(2048), 256, 0, stream>>>(x, rgb_w, rgb_b, colr, sc_c);
    gather_kernel<<<dim3(8192), 256, 0, stream>>>(seg, colr, out);
}

// Round 4
// 904.979 us; speedup vs baseline: 2.4809x; 1.0442x over previous
//
#include <hip/hip_runtime.h>
#include <math.h>

#define N_PIX (512*512)
#define S_SEG 1024
#define CDIM  256
#define BATCH 8

typedef __attribute__((ext_vector_type(4))) float f32x4;
typedef __attribute__((ext_vector_type(8))) short bf16x8;

__device__ __forceinline__ float lrelu(float v) { return v > 0.f ? v : 0.2f * v; }

__device__ __forceinline__ unsigned short bf16_hi(float x) {
    union { float f; unsigned int u; } v; v.f = x;
    unsigned int r = v.u + 0x7FFFu + ((v.u >> 16) & 1u);
    return (unsigned short)(r >> 16);
}
__device__ __forceinline__ float bf16_tof(unsigned short h) {
    union { float f; unsigned int u; } v; v.u = ((unsigned int)h) << 16;
    return v.f;
}

// ---------------------------------------------------------------------------
// Segment pooling (unchanged)
// ---------------------------------------------------------------------------
__global__ __launch_bounds__(256) void seg_pool_kernel(
    const float* __restrict__ images, const int* __restrict__ seg,
    float* __restrict__ sums, float* __restrict__ counts)
{
    __shared__ float bins[S_SEG * 4];
    const int b = blockIdx.x >> 5;
    const int chunk = blockIdx.x & 31;
    for (int i = threadIdx.x; i < S_SEG * 4; i += 256) bins[i] = 0.f;
    __syncthreads();

    const int pix_per_block = N_PIX / 32;  // 8192
    const int base = chunk * pix_per_block;
    const float* im = images + (size_t)b * 3 * N_PIX;
    const int* sg = seg + (size_t)b * N_PIX;

    for (int it = 0; it < pix_per_block / 256; ++it) {
        int p = base + it * 256 + threadIdx.x;
        int s = sg[p];
        float r = im[p];
        float g = im[N_PIX + p];
        float bl = im[2 * N_PIX + p];
        atomicAdd(&bins[s * 4 + 0], r);
        atomicAdd(&bins[s * 4 + 1], g);
        atomicAdd(&bins[s * 4 + 2], bl);
        atomicAdd(&bins[s * 4 + 3], 1.f);
    }
    __syncthreads();
    for (int s = threadIdx.x; s < S_SEG; s += 256) {
        float4 v = *(const float4*)&bins[s * 4];
        atomicAdd(&sums[((size_t)b * S_SEG + s) * 3 + 0], v.x);
        atomicAdd(&sums[((size_t)b * S_SEG + s) * 3 + 1], v.y);
        atomicAdd(&sums[((size_t)b * S_SEG + s) * 3 + 2], v.z);
        atomicAdd(&counts[(size_t)b * S_SEG + s], v.w);
    }
}

// ---------------------------------------------------------------------------
// FUSED: A -> (Ah, Al) bf16 split + abar (column means) + sumabar.
// grid 256 blocks (8 batches x 32 row-chunks of 32 rows), 256 threads.
// Thread t owns columns 4t..4t+3 of its chunk; fully coalesced float4.
// ---------------------------------------------------------------------------
__global__ __launch_bounds__(256) void conv_split_abar_kernel(
    const float* __restrict__ A, unsigned short* __restrict__ Ah,
    unsigned short* __restrict__ Al, float* __restrict__ abar,
    float* __restrict__ sumabar)
{
    const int b = blockIdx.x >> 5;
    const int chunk = blockIdx.x & 31;
    const int t = threadIdx.x;
    const size_t base4 = ((size_t)b * 1024 * 1024 + (size_t)chunk * 32 * 1024) >> 2;
    const float4* Af = ((const float4*)A) + base4;
    ushort4* Ahf = ((ushort4*)Ah) + base4;
    ushort4* Alf = ((ushort4*)Al) + base4;
    float a0 = 0.f, a1 = 0.f, a2 = 0.f, a3 = 0.f;
#pragma unroll 4
    for (int r = 0; r < 32; ++r) {
        float4 v = Af[r * 256 + t];
        ushort4 h, l;
        h.x = bf16_hi(v.x); l.x = bf16_hi(v.x - bf16_tof(h.x));
        h.y = bf16_hi(v.y); l.y = bf16_hi(v.y - bf16_tof(h.y));
        h.z = bf16_hi(v.z); l.z = bf16_hi(v.z - bf16_tof(h.z));
        h.w = bf16_hi(v.w); l.w = bf16_hi(v.w - bf16_tof(h.w));
        Ahf[r * 256 + t] = h;
        Alf[r * 256 + t] = l;
        a0 += v.x; a1 += v.y; a2 += v.z; a3 += v.w;
    }
    const float inv = 1.f / 1024.f;
    atomicAdd(&abar[b * 1024 + t * 4 + 0], a0 * inv);
    atomicAdd(&abar[b * 1024 + t * 4 + 1], a1 * inv);
    atomicAdd(&abar[b * 1024 + t * 4 + 2], a2 * inv);
    atomicAdd(&abar[b * 1024 + t * 4 + 3], a3 * inv);
    __shared__ float red[256];
    red[t] = (a0 + a1 + a2 + a3) * inv;
    __syncthreads();
    for (int off = 128; off > 0; off >>= 1) {
        if (t < off) red[t] += red[t + off];
        __syncthreads();
    }
    if (t == 0) atomicAdd(&sumabar[b], red[0]);
}

__global__ __launch_bounds__(256) void prep_xin_kernel(
    const float* __restrict__ sums, const float* __restrict__ counts,
    const float* __restrict__ z, float* __restrict__ xin)
{
    int idx = blockIdx.x * 256 + threadIdx.x;
    int r = idx / 144, c = idx % 144;
    int b = r >> 10;
    float v;
    if (c < 3)        v = sums[r * 3 + c] / (counts[r] + 1e-6f);
    else if (c < 131) v = z[b * 128 + (c - 3)];
    else              v = 0.f;
    xin[idx] = v;
}

__global__ __launch_bounds__(256) void prep_wpad_kernel(
    const float* __restrict__ proj_w, float* __restrict__ wpad)
{
    int idx = blockIdx.x * 256 + threadIdx.x;
    int n = idx / 144, k = idx % 144;
    wpad[idx] = (k < 131) ? proj_w[n * 131 + k] : 0.f;
}

// ---------------------------------------------------------------------------
// fp32 -> (bf16 hi, bf16 lo) split with scale (weights only now)
// ---------------------------------------------------------------------------
__global__ __launch_bounds__(256) void conv_split_kernel(
    const float* __restrict__ in, unsigned short* __restrict__ hi,
    unsigned short* __restrict__ lo, float scale, unsigned int n4)
{
    unsigned int idx = blockIdx.x * 256 + threadIdx.x;
    if (idx >= n4) return;
    float4 v = ((const float4*)in)[idx];
    ushort4 h, l;
    float a;
    a = v.x * scale; h.x = bf16_hi(a); l.x = bf16_hi(a - bf16_tof(h.x));
    a = v.y * scale; h.y = bf16_hi(a); l.y = bf16_hi(a - bf16_tof(h.y));
    a = v.z * scale; h.z = bf16_hi(a); l.z = bf16_hi(a - bf16_tof(h.z));
    a = v.w * scale; h.w = bf16_hi(a); l.w = bf16_hi(a - bf16_tof(h.w));
    ((ushort4*)hi)[idx] = h;
    ((ushort4*)lo)[idx] = l;
}

// ---------------------------------------------------------------------------
// staging helpers (unchanged, rule #21 both-sides swizzle)
// ---------------------------------------------------------------------------
__device__ __forceinline__ void stage_tile(
    const unsigned short* __restrict__ g, int grow,
    unsigned short* lds, int tid, int nissue)
{
    for (int i = 0; i < nissue; ++i) {
        int c = i * 256 + tid;
        int row = c >> 3, cin = c & 7;
        int cs = cin ^ (row & 7);
        const unsigned short* src = g + (size_t)row * grow + cs * 8;
        unsigned short* dst = lds + (size_t)(i * 256 + (tid & ~63)) * 8;
        __builtin_amdgcn_global_load_lds(
            (const __attribute__((address_space(1))) unsigned int*)src,
            (__attribute__((address_space(3))) unsigned int*)dst, 16, 0, 0);
    }
}

__device__ __forceinline__ int frag_idx(int row, int ks, int l)
{
    int chunk = (ks * 4 + (l >> 4)) ^ (row & 7);
    return row * 64 + chunk * 8;
}

// ---------------------------------------------------------------------------
// MFMA split-3 GEMM: x_out = lrelu(gamma*(A @ h1) + beta)
// Optional outputs: x (fp32, last iter), xh/xl (bf16, iters 0..6),
// mv (iters 0..6). Null-gated.
// ---------------------------------------------------------------------------
__global__ __launch_bounds__(256) void gemm_nn_mfma_kernel(
    const unsigned short* __restrict__ Ah_g, const unsigned short* __restrict__ Al_g,
    const unsigned short* __restrict__ Hh_g, const unsigned short* __restrict__ Hl_g,
    const float* __restrict__ style, const float* __restrict__ abar,
    float* __restrict__ x, unsigned short* __restrict__ xh,
    unsigned short* __restrict__ xl, float* __restrict__ mv)
{
    __shared__ __align__(16) unsigned short Ah_s[128 * 64];
    __shared__ __align__(16) unsigned short Al_s[128 * 64];
    __shared__ __align__(16) unsigned short Bh_s[64 * 64];
    __shared__ __align__(16) unsigned short Bl_s[64 * 64];
    __shared__ float mvred[64];
    const int tid = threadIdx.x;
    const int b = blockIdx.z, bm = blockIdx.x, bn = blockIdx.y;
    const int l = tid & 63, wave = tid >> 6;
    const int wr = wave >> 1, wc = wave & 1;
    if (mv && tid < 64) mvred[tid] = 0.f;

    const unsigned short* Ag_h = Ah_g + ((size_t)(b * 1024 + bm * 128)) * 1024;
    const unsigned short* Ag_l = Al_g + ((size_t)(b * 1024 + bm * 128)) * 1024;
    const unsigned short* Hg_h = Hh_g + ((size_t)(b * 256 + bn * 64)) * 1024;
    const unsigned short* Hg_l = Hl_g + ((size_t)(b * 256 + bn * 64)) * 1024;

    f32x4 acc[4][2];
#pragma unroll
    for (int i = 0; i < 4; ++i)
#pragma unroll
        for (int j = 0; j < 2; ++j) acc[i][j] = (f32x4){0.f, 0.f, 0.f, 0.f};

    for (int kt = 0; kt < 16; ++kt) {
        stage_tile(Ag_h + kt * 64, 1024, Ah_s, tid, 4);
        stage_tile(Ag_l + kt * 64, 1024, Al_s, tid, 4);
        stage_tile(Hg_h + kt * 64, 1024, Bh_s, tid, 2);
        stage_tile(Hg_l + kt * 64, 1024, Bl_s, tid, 2);
        __syncthreads();
#pragma unroll
        for (int ks = 0; ks < 2; ++ks) {
            bf16x8 ah[4], al[4], bh[2], bl[2];
#pragma unroll
            for (int fm = 0; fm < 4; ++fm) {
                int row = wr * 64 + fm * 16 + (l & 15);
                int idx = frag_idx(row, ks, l);
                ah[fm] = *(const bf16x8*)&Ah_s[idx];
                al[fm] = *(const bf16x8*)&Al_s[idx];
            }
#pragma unroll
            for (int fn = 0; fn < 2; ++fn) {
                int row = wc * 32 + fn * 16 + (l & 15);
                int idx = frag_idx(row, ks, l);
                bh[fn] = *(const bf16x8*)&Bh_s[idx];
                bl[fn] = *(const bf16x8*)&Bl_s[idx];
            }
#pragma unroll
            for (int fm = 0; fm < 4; ++fm)
#pragma unroll
                for (int fn = 0; fn < 2; ++fn) {
                    acc[fm][fn] = __builtin_amdgcn_mfma_f32_16x16x32_bf16(ah[fm], bh[fn], acc[fm][fn], 0, 0, 0);
                    acc[fm][fn] = __builtin_amdgcn_mfma_f32_16x16x32_bf16(ah[fm], bl[fn], acc[fm][fn], 0, 0, 0);
                    acc[fm][fn] = __builtin_amdgcn_mfma_f32_16x16x32_bf16(al[fm], bh[fn], acc[fm][fn], 0, 0, 0);
                }
        }
        __syncthreads();
    }

    const float* st = style + b * 2 * CDIM;
#pragma unroll
    for (int fn = 0; fn < 2; ++fn) {
        int col = bn * 64 + wc * 32 + fn * 16 + (l & 15);
        float ga = st[col], be = st[CDIM + col];
        float pmv = 0.f;
#pragma unroll
        for (int fm = 0; fm < 4; ++fm) {
            int m0 = bm * 128 + wr * 64 + fm * 16 + (l >> 4) * 4;
#pragma unroll
            for (int r = 0; r < 4; ++r) {
                float v = lrelu(ga * acc[fm][fn][r] + be);
                size_t off = ((size_t)(b * 1024 + m0 + r)) * 256 + col;
                if (x) x[off] = v;
                if (xh) {
                    unsigned short h = bf16_hi(v);
                    xh[off] = h;
                    xl[off] = bf16_hi(v - bf16_tof(h));
                }
                pmv += abar[b * 1024 + m0 + r] * v;
            }
        }
        if (mv) atomicAdd(&mvred[wc * 32 + fn * 16 + (l & 15)], pmv);
    }
    if (mv) {
        __syncthreads();
        if (tid < 64) atomicAdd(&mv[b * 256 + bn * 64 + tid], mvred[tid]);
    }
}

// ---------------------------------------------------------------------------
// MFMA split-3 GEMM: h1 = x @ W'^T + b (W' pre-scaled), output transposed
// bf16 hi/lo: h1t[b][c][s]. grid (64, 4); K=256.
// ---------------------------------------------------------------------------
__global__ __launch_bounds__(256) void gemm_nt_mfma_kernel(
    const unsigned short* __restrict__ xh_g, const unsigned short* __restrict__ xl_g,
    const unsigned short* __restrict__ Wh, const unsigned short* __restrict__ Wl,
    const float* __restrict__ bias,
    unsigned short* __restrict__ h1t_h, unsigned short* __restrict__ h1t_l)
{
    __shared__ __align__(16) unsigned short Ah_s[128 * 64];
    __shared__ __align__(16) unsigned short Al_s[128 * 64];
    __shared__ __align__(16) unsigned short Bh_s[64 * 64];
    __shared__ __align__(16) unsigned short Bl_s[64 * 64];
    const int tid = threadIdx.x;
    const int bm = blockIdx.x, bn = blockIdx.y;
    const int l = tid & 63, wave = tid >> 6;
    const int wr = wave >> 1, wc = wave & 1;
    const int row0 = bm * 128;
    const int b = row0 >> 10;

    const unsigned short* Ag_h = xh_g + (size_t)row0 * 256;
    const unsigned short* Ag_l = xl_g + (size_t)row0 * 256;
    const unsigned short* Bg_h = Wh + (size_t)(bn * 64) * 256;
    const unsigned short* Bg_l = Wl + (size_t)(bn * 64) * 256;

    f32x4 acc[4][2];
#pragma unroll
    for (int i = 0; i < 4; ++i)
#pragma unroll
        for (int j = 0; j < 2; ++j) acc[i][j] = (f32x4){0.f, 0.f, 0.f, 0.f};

    for (int kt = 0; kt < 4; ++kt) {
        stage_tile(Ag_h + kt * 64, 256, Ah_s, tid, 4);
        stage_tile(Ag_l + kt * 64, 256, Al_s, tid, 4);
        stage_tile(Bg_h + kt * 64, 256, Bh_s, tid, 2);
        stage_tile(Bg_l + kt * 64, 256, Bl_s, tid, 2);
        __syncthreads();
#pragma unroll
        for (int ks = 0; ks < 2; ++ks) {
            bf16x8 ah[4], al[4], bh[2], bl[2];
#pragma unroll
            for (int fm = 0; fm < 4; ++fm) {
                int row = wr * 64 + fm * 16 + (l & 15);
                int idx = frag_idx(row, ks, l);
                ah[fm] = *(const bf16x8*)&Ah_s[idx];
                al[fm] = *(const bf16x8*)&Al_s[idx];
            }
#pragma unroll
            for (int fn = 0; fn < 2; ++fn) {
                int row = wc * 32 + fn * 16 + (l & 15);
                int idx = frag_idx(row, ks, l);
                bh[fn] = *(const bf16x8*)&Bh_s[idx];
                bl[fn] = *(const bf16x8*)&Bl_s[idx];
            }
#pragma unroll
            for (int fm = 0; fm < 4; ++fm)
#pragma unroll
                for (int fn = 0; fn < 2; ++fn) {
                    acc[fm][fn] = __builtin_amdgcn_mfma_f32_16x16x32_bf16(ah[fm], bh[fn], acc[fm][fn], 0, 0, 0);
                    acc[fm][fn] = __builtin_amdgcn_mfma_f32_16x16x32_bf16(ah[fm], bl[fn], acc[fm][fn], 0, 0, 0);
                    acc[fm][fn] = __builtin_amdgcn_mfma_f32_16x16x32_bf16(al[fm], bh[fn], acc[fm][fn], 0, 0, 0);
                }
        }
        __syncthreads();
    }

#pragma unroll
    for (int fn = 0; fn < 2; ++fn) {
        int col = bn * 64 + wc * 32 + fn * 16 + (l & 15);
        float bi = bias[col];
#pragma unroll
        for (int fm = 0; fm < 4; ++fm) {
            int s0 = (row0 & 1023) + wr * 64 + fm * 16 + (l >> 4) * 4;
            float v0 = acc[fm][fn][0] + bi;
            float v1 = acc[fm][fn][1] + bi;
            float v2 = acc[fm][fn][2] + bi;
            float v3 = acc[fm][fn][3] + bi;
            ushort4 hv, lv;
            hv.x = bf16_hi(v0); lv.x = bf16_hi(v0 - bf16_tof(hv.x));
            hv.y = bf16_hi(v1); lv.y = bf16_hi(v1 - bf16_tof(hv.y));
            hv.z = bf16_hi(v2); lv.z = bf16_hi(v2 - bf16_tof(hv.z));
            hv.w = bf16_hi(v3); lv.w = bf16_hi(v3 - bf16_tof(hv.w));
            size_t off = ((size_t)(b * 256 + col)) * 1024 + s0;
            *(ushort4*)&h1t_h[off] = hv;
            *(ushort4*)&h1t_l[off] = lv;
        }
    }
}

// ---------------------------------------------------------------------------
// fp32 VALU gemm_nt (proj only) + mv + bf16 emit (unchanged)
// ---------------------------------------------------------------------------
#define BM 64
#define BN 64
#define BK 16
__global__ __launch_bounds__(256) void gemm_nt_kernel(
    const float* __restrict__ A, const float* __restrict__ B,
    float* __restrict__ C, int K, float alpha, const float* __restrict__ bias,
    const float* __restrict__ abar, float* __restrict__ mv,
    unsigned short* __restrict__ xh, unsigned short* __restrict__ xl)
{
    __shared__ float As[BK][BM + 4];
    __shared__ float Bs[BK][BN + 4];
    __shared__ float red[16][BN];
    const int tid = threadIdx.x;
    const int bm = blockIdx.x, bn = blockIdx.y;
    const int tx = tid & 15, ty = tid >> 4;
    const int lrow = tid >> 2;
    const int lk = (tid & 3) << 2;
    const float* Ag = A + (size_t)(bm * BM + lrow) * K + lk;
    const float* Bg = B + (size_t)(bn * BN + lrow) * K + lk;
    float acc[4][4] = {};

    for (int k0 = 0; k0 < K; k0 += BK) {
        float4 av = *(const float4*)(Ag + k0);
        float4 bv = *(const float4*)(Bg + k0);
        __syncthreads();
        As[lk + 0][lrow] = av.x; As[lk + 1][lrow] = av.y;
        As[lk + 2][lrow] = av.z; As[lk + 3][lrow] = av.w;
        Bs[lk + 0][lrow] = bv.x; Bs[lk + 1][lrow] = bv.y;
        Bs[lk + 2][lrow] = bv.z; Bs[lk + 3][lrow] = bv.w;
        __syncthreads();
#pragma unroll
        for (int kk = 0; kk < BK; ++kk) {
            const float4 a = *(const float4*)&As[kk][ty << 2];
            const float4 b = *(const float4*)&Bs[kk][tx << 2];
            float ar[4] = {a.x, a.y, a.z, a.w};
            float br[4] = {b.x, b.y, b.z, b.w};
#pragma unroll
            for (int i = 0; i < 4; ++i)
#pragma unroll
                for (int j = 0; j < 4; ++j)
                    acc[i][j] += ar[i] * br[j];
        }
    }
    const int row = bm * BM + (ty << 2);
    const int col = bn * BN + (tx << 2);
    const int b = row >> 10;
    float bi[4] = {bias[col], bias[col + 1], bias[col + 2], bias[col + 3]};
    float o[4][4];
#pragma unroll
    for (int i = 0; i < 4; ++i) {
        float4 ov;
        ov.x = o[i][0] = alpha * acc[i][0] + bi[0];
        ov.y = o[i][1] = alpha * acc[i][1] + bi[1];
        ov.z = o[i][2] = alpha * acc[i][2] + bi[2];
        ov.w = o[i][3] = alpha * acc[i][3] + bi[3];
        *(float4*)(C + (size_t)(row + i) * CDIM + col) = ov;
#pragma unroll
        for (int j = 0; j < 4; ++j) {
            size_t off = (size_t)(row + i) * CDIM + col + j;
            unsigned short h = bf16_hi(o[i][j]);
            xh[off] = h;
            xl[off] = bf16_hi(o[i][j] - bf16_tof(h));
        }
    }
    {
        float p[4];
#pragma unroll
        for (int j = 0; j < 4; ++j) {
            p[j] = 0.f;
#pragma unroll
            for (int i = 0; i < 4; ++i)
                p[j] += abar[((row + i) & 1023) + (b << 10)] * o[i][j];
            red[ty][(tx << 2) + j] = p[j];
        }
        __syncthreads();
        if (tid < BN) {
            float s = 0.f;
#pragma unroll
            for (int t = 0; t < 16; ++t) s += red[t][tid];
            atomicAdd(&mv[b * CDIM + bn * BN + tid], s);
        }
    }
}

// ---------------------------------------------------------------------------
// Tiny per-batch MLP (unchanged)
// ---------------------------------------------------------------------------
__global__ __launch_bounds__(512) void mlp2_kernel(
    const float* __restrict__ mv, const float* __restrict__ sumabar,
    const float* __restrict__ Wblk, const float* __restrict__ bblk,
    const float* __restrict__ W1, const float* __restrict__ b1,
    const float* __restrict__ W2, const float* __restrict__ b2,
    float* __restrict__ style, float sc_c, float sc_2c)
{
    const int b = blockIdx.x;
    const int t = threadIdx.x;
    __shared__ float mvs[256];
    __shared__ float m[256];
    __shared__ float s1[512];

    if (t < 256) mvs[t] = mv[b * 256 + t];
    __syncthreads();
    if (t < 256) {
        const float* wr = Wblk + (size_t)t * 256;
        float acc = 0.f;
#pragma unroll 4
        for (int k = 0; k < 64; ++k) {
            float4 w = *(const float4*)(wr + k * 4);
            float4 v = *(const float4*)(mvs + k * 4);
            acc += w.x * v.x + w.y * v.y + w.z * v.z + w.w * v.w;
        }
        m[t] = sc_c * acc + sumabar[b] * bblk[t];
    }
    __syncthreads();
    {
        const float* w1r = W1 + (size_t)t * 256;
        float acc = 0.f;
#pragma unroll 4
        for (int k = 0; k < 64; ++k) {
            float4 w = *(const float4*)(w1r + k * 4);
            float4 v = *(const float4*)(m + k * 4);
            acc += w.x * v.x + w.y * v.y + w.z * v.z + w.w * v.w;
        }
        s1[t] = lrelu(sc_c * acc + b1[t]);
    }
    __syncthreads();
    {
        const float* w2r = W2 + (size_t)t * 512;
        float acc = 0.f;
#pragma unroll 4
        for (int k = 0; k < 128; ++k) {
            float4 w = *(const float4*)(w2r + k * 4);
            float4 v = *(const float4*)(s1 + k * 4);
            acc += w.x * v.x + w.y * v.y + w.z * v.z + w.w * v.w;
        }
        style[b * 512 + t] = sc_2c * acc + b2[t];
    }
}

// ---------------------------------------------------------------------------
// color + gather (unchanged)
// ---------------------------------------------------------------------------
__global__ __launch_bounds__(256) void color_kernel(
    const float* __restrict__ x, const float* __restrict__ rgb_w,
    const float* __restrict__ rgb_b, float* __restrict__ color, float sc_c)
{
    const int wave = threadIdx.x >> 6;
    const int lane = threadIdx.x & 63;
    const int r = blockIdx.x * 4 + wave;
    const float4 xv = *(const float4*)(x + (size_t)r * CDIM + lane * 4);
    float p[3];
#pragma unroll
    for (int cc = 0; cc < 3; ++cc) {
        const float4 wv = *(const float4*)(rgb_w + cc * CDIM + lane * 4);
        p[cc] = xv.x * wv.x + xv.y * wv.y + xv.z * wv.z + xv.w * wv.w;
    }
#pragma unroll
    for (int off = 32; off > 0; off >>= 1) {
#pragma unroll
        for (int cc = 0; cc < 3; ++cc) p[cc] += __shfl_down(p[cc], off);
    }
    if (lane == 0) {
#pragma unroll
        for (int cc = 0; cc < 3; ++cc)
            color[(size_t)r * 3 + cc] = sc_c * p[cc] + rgb_b[cc];
    }
}

__global__ __launch_bounds__(256) void gather_kernel(
    const int* __restrict__ seg, const float* __restrict__ color,
    float* __restrict__ out)
{
    int idx = blockIdx.x * 256 + threadIdx.x;
    int b = idx >> 18;
    int p = idx & (N_PIX - 1);
    int s = seg[idx];
    const float* cp = color + ((size_t)b * S_SEG + s) * 3;
    out[((size_t)b * 3 + 0) * N_PIX + p] = tanhf(cp[0]);
    out[((size_t)b * 3 + 1) * N_PIX + p] = tanhf(cp[1]);
    out[((size_t)b * 3 + 2) * N_PIX + p] = tanhf(cp[2]);
}

// ---------------------------------------------------------------------------
extern "C" void kernel_launch(void* const* d_in, const int* in_sizes, int n_in,
                              void* d_out, int out_size, void* d_ws, size_t ws_size,
                              hipStream_t stream)
{
    (void)in_sizes; (void)n_in; (void)out_size; (void)ws_size;
    const float* z      = (const float*)d_in[0];
    const float* images = (const float*)d_in[1];
    const int*   seg    = (const int*)d_in[2];
    const float* A      = (const float*)d_in[3];
    const float* proj_w = (const float*)d_in[4];
    const float* proj_b = (const float*)d_in[5];
    const float* blk_w  = (const float*)d_in[6];
    const float* blk_b  = (const float*)d_in[7];
    const float* ada_w1 = (const float*)d_in[8];
    const float* ada_b1 = (const float*)d_in[9];
    const float* ada_w2 = (const float*)d_in[10];
    const float* ada_b2 = (const float*)d_in[11];
    const float* rgb_w  = (const float*)d_in[12];
    const float* rgb_b  = (const float*)d_in[13];
    float* out = (float*)d_out;

    float* ws = (float*)d_ws;
    float* sums    = ws;                  // 24576
    float* counts  = ws + 24576;          // 8192
    float* sumabar = ws + 32768;          // 16
    float* mv      = ws + 32784;          // 18432
    float* abar    = ws + 51216;          // 8192   (zeroed too - atomic target)
    float* style   = ws + 59408;          // 4096
    float* colr    = ws + 63504;          // 24576
    float* wpad    = ws + 88080;          // 36864
    float* xin     = ws + 124944;         // 1179648 -> ends 1304592
    float* x       = ws + 1304592;        // 2097152 -> ends 3401744
    unsigned short* xh    = (unsigned short*)(ws + 3401744);
    unsigned short* xl    = (unsigned short*)(ws + 4450320);
    unsigned short* h1t_h = (unsigned short*)(ws + 5498896);
    unsigned short* h1t_l = (unsigned short*)(ws + 6547472);
    unsigned short* Ah    = (unsigned short*)(ws + 7596048);
    unsigned short* Al    = (unsigned short*)(ws + 11790352);
    unsigned short* Wh    = (unsigned short*)(ws + 15984656);
    unsigned short* Wl    = (unsigned short*)(ws + 16246800);

    const float sc_in = (float)sqrt(2.0 / 131.0);
    const float sc_c  = (float)sqrt(2.0 / 256.0);
    const float sc_2c = (float)sqrt(2.0 / 512.0);

    hipMemsetAsync(sums, 0, 59408 * sizeof(float), stream);  // thru abar
    seg_pool_kernel<<<dim3(BATCH * 32), 256, 0, stream>>>(images, seg, sums, counts);
    conv_split_abar_kernel<<<dim3(256), 256, 0, stream>>>(A, Ah, Al, abar, sumabar);
    prep_xin_kernel<<<dim3((8192 * 144) / 256), 256, 0, stream>>>(sums, counts, z, xin);
    prep_wpad_kernel<<<dim3((256 * 144) / 256), 256, 0, stream>>>(proj_w, wpad);
    conv_split_kernel<<<dim3(512), 256, 0, stream>>>(blk_w, Wh, Wl, sc_c, 131072u);

    gemm_nt_kernel<<<dim3(128, 4), 256, 0, stream>>>(xin, wpad, x, 144, sc_in, proj_b,
                                                     abar, mv, xh, xl);

    for (int i = 0; i < 8; ++i) {
        mlp2_kernel<<<dim3(8), 512, 0, stream>>>(
            mv + i * 2048, sumabar,
            blk_w + (size_t)i * CDIM * CDIM, blk_b + i * CDIM,
            ada_w1 + (size_t)i * 512 * 256, ada_b1 + i * 512,
            ada_w2 + (size_t)i * 512 * 512, ada_b2 + i * 512, style, sc_c, sc_2c);
        gemm_nt_mfma_kernel<<<dim3(64, 4), 256, 0, stream>>>(
            xh, xl, Wh + (size_t)i * 65536, Wl + (size_t)i * 65536,
            blk_b + i * CDIM, h1t_h, h1t_l);
        const bool last = (i == 7);
        gemm_nn_mfma_kernel<<<dim3(8, 4, 8), 256, 0, stream>>>(
            Ah, Al, h1t_h, h1t_l, style, abar,
            last ? x : nullptr,
            last ? nullptr : xh, last ? nullptr : xl,
            last ? nullptr : (mv + (i + 1) * 2048));
    }

    color_kernel<<<dim3(2048), 256, 0, stream>>>(x, rgb_w, rgb_b, colr, sc_c);
    gather_kernel<<<dim3(8192), 256, 0, stream>>>(seg, colr, out);
}

// Round 5
// 849.632 us; speedup vs baseline: 2.6425x; 1.0651x over previous
//
#include <hip/hip_runtime.h>
#include <math.h>

#define N_PIX (512*512)
#define S_SEG 1024
#define CDIM  256
#define BATCH 8

typedef __attribute__((ext_vector_type(4))) float f32x4;
typedef __attribute__((ext_vector_type(8))) short bf16x8;

__device__ __forceinline__ float lrelu(float v) { return v > 0.f ? v : 0.2f * v; }

__device__ __forceinline__ unsigned short bf16_hi(float x) {
    union { float f; unsigned int u; } v; v.f = x;
    unsigned int r = v.u + 0x7FFFu + ((v.u >> 16) & 1u);
    return (unsigned short)(r >> 16);
}
__device__ __forceinline__ float bf16_tof(unsigned short h) {
    union { float f; unsigned int u; } v; v.u = ((unsigned int)h) << 16;
    return v.f;
}

// ---------------------------------------------------------------------------
// Segment pooling (unchanged)
// ---------------------------------------------------------------------------
__global__ __launch_bounds__(256) void seg_pool_kernel(
    const float* __restrict__ images, const int* __restrict__ seg,
    float* __restrict__ sums, float* __restrict__ counts)
{
    __shared__ float bins[S_SEG * 4];
    const int b = blockIdx.x >> 5;
    const int chunk = blockIdx.x & 31;
    for (int i = threadIdx.x; i < S_SEG * 4; i += 256) bins[i] = 0.f;
    __syncthreads();

    const int pix_per_block = N_PIX / 32;  // 8192
    const int base = chunk * pix_per_block;
    const float* im = images + (size_t)b * 3 * N_PIX;
    const int* sg = seg + (size_t)b * N_PIX;

    for (int it = 0; it < pix_per_block / 256; ++it) {
        int p = base + it * 256 + threadIdx.x;
        int s = sg[p];
        float r = im[p];
        float g = im[N_PIX + p];
        float bl = im[2 * N_PIX + p];
        atomicAdd(&bins[s * 4 + 0], r);
        atomicAdd(&bins[s * 4 + 1], g);
        atomicAdd(&bins[s * 4 + 2], bl);
        atomicAdd(&bins[s * 4 + 3], 1.f);
    }
    __syncthreads();
    for (int s = threadIdx.x; s < S_SEG; s += 256) {
        float4 v = *(const float4*)&bins[s * 4];
        atomicAdd(&sums[((size_t)b * S_SEG + s) * 3 + 0], v.x);
        atomicAdd(&sums[((size_t)b * S_SEG + s) * 3 + 1], v.y);
        atomicAdd(&sums[((size_t)b * S_SEG + s) * 3 + 2], v.z);
        atomicAdd(&counts[(size_t)b * S_SEG + s], v.w);
    }
}

// ---------------------------------------------------------------------------
// FUSED: A -> (Ah, Al) bf16 split + abar (column means) + sumabar.
// ---------------------------------------------------------------------------
__global__ __launch_bounds__(256) void conv_split_abar_kernel(
    const float* __restrict__ A, unsigned short* __restrict__ Ah,
    unsigned short* __restrict__ Al, float* __restrict__ abar,
    float* __restrict__ sumabar)
{
    const int b = blockIdx.x >> 5;
    const int chunk = blockIdx.x & 31;
    const int t = threadIdx.x;
    const size_t base4 = ((size_t)b * 1024 * 1024 + (size_t)chunk * 32 * 1024) >> 2;
    const float4* Af = ((const float4*)A) + base4;
    ushort4* Ahf = ((ushort4*)Ah) + base4;
    ushort4* Alf = ((ushort4*)Al) + base4;
    float a0 = 0.f, a1 = 0.f, a2 = 0.f, a3 = 0.f;
#pragma unroll 4
    for (int r = 0; r < 32; ++r) {
        float4 v = Af[r * 256 + t];
        ushort4 h, l;
        h.x = bf16_hi(v.x); l.x = bf16_hi(v.x - bf16_tof(h.x));
        h.y = bf16_hi(v.y); l.y = bf16_hi(v.y - bf16_tof(h.y));
        h.z = bf16_hi(v.z); l.z = bf16_hi(v.z - bf16_tof(h.z));
        h.w = bf16_hi(v.w); l.w = bf16_hi(v.w - bf16_tof(h.w));
        Ahf[r * 256 + t] = h;
        Alf[r * 256 + t] = l;
        a0 += v.x; a1 += v.y; a2 += v.z; a3 += v.w;
    }
    const float inv = 1.f / 1024.f;
    atomicAdd(&abar[b * 1024 + t * 4 + 0], a0 * inv);
    atomicAdd(&abar[b * 1024 + t * 4 + 1], a1 * inv);
    atomicAdd(&abar[b * 1024 + t * 4 + 2], a2 * inv);
    atomicAdd(&abar[b * 1024 + t * 4 + 3], a3 * inv);
    __shared__ float red[256];
    red[t] = (a0 + a1 + a2 + a3) * inv;
    __syncthreads();
    for (int off = 128; off > 0; off >>= 1) {
        if (t < off) red[t] += red[t + off];
        __syncthreads();
    }
    if (t == 0) atomicAdd(&sumabar[b], red[0]);
}

__global__ __launch_bounds__(256) void prep_xin_kernel(
    const float* __restrict__ sums, const float* __restrict__ counts,
    const float* __restrict__ z, float* __restrict__ xin)
{
    int idx = blockIdx.x * 256 + threadIdx.x;
    int r = idx / 144, c = idx % 144;
    int b = r >> 10;
    float v;
    if (c < 3)        v = sums[r * 3 + c] / (counts[r] + 1e-6f);
    else if (c < 131) v = z[b * 128 + (c - 3)];
    else              v = 0.f;
    xin[idx] = v;
}

__global__ __launch_bounds__(256) void prep_wpad_kernel(
    const float* __restrict__ proj_w, float* __restrict__ wpad)
{
    int idx = blockIdx.x * 256 + threadIdx.x;
    int n = idx / 144, k = idx % 144;
    wpad[idx] = (k < 131) ? proj_w[n * 131 + k] : 0.f;
}

// ---------------------------------------------------------------------------
// fp32 -> (bf16 hi, bf16 lo) split with scale (weights only)
// ---------------------------------------------------------------------------
__global__ __launch_bounds__(256) void conv_split_kernel(
    const float* __restrict__ in, unsigned short* __restrict__ hi,
    unsigned short* __restrict__ lo, float scale, unsigned int n4)
{
    unsigned int idx = blockIdx.x * 256 + threadIdx.x;
    if (idx >= n4) return;
    float4 v = ((const float4*)in)[idx];
    ushort4 h, l;
    float a;
    a = v.x * scale; h.x = bf16_hi(a); l.x = bf16_hi(a - bf16_tof(h.x));
    a = v.y * scale; h.y = bf16_hi(a); l.y = bf16_hi(a - bf16_tof(h.y));
    a = v.z * scale; h.z = bf16_hi(a); l.z = bf16_hi(a - bf16_tof(h.z));
    a = v.w * scale; h.w = bf16_hi(a); l.w = bf16_hi(a - bf16_tof(h.w));
    ((ushort4*)hi)[idx] = h;
    ((ushort4*)lo)[idx] = l;
}

// ---------------------------------------------------------------------------
// staging helpers (rule #21 both-sides swizzle)
// ---------------------------------------------------------------------------
__device__ __forceinline__ void stage_tile(
    const unsigned short* __restrict__ g, int grow,
    unsigned short* lds, int tid, int nissue)
{
    for (int i = 0; i < nissue; ++i) {
        int c = i * 256 + tid;
        int row = c >> 3, cin = c & 7;
        int cs = cin ^ (row & 7);
        const unsigned short* src = g + (size_t)row * grow + cs * 8;
        unsigned short* dst = lds + (size_t)(i * 256 + (tid & ~63)) * 8;
        __builtin_amdgcn_global_load_lds(
            (const __attribute__((address_space(1))) unsigned int*)src,
            (__attribute__((address_space(3))) unsigned int*)dst, 16, 0, 0);
    }
}

__device__ __forceinline__ int frag_idx(int row, int ks, int l)
{
    int chunk = (ks * 4 + (l >> 4)) ^ (row & 7);
    return row * 64 + chunk * 8;
}

// ---------------------------------------------------------------------------
// MFMA split-3 GEMM: x_out = lrelu(gamma*(A @ h1) + beta) + optional outputs
// ---------------------------------------------------------------------------
__global__ __launch_bounds__(256) void gemm_nn_mfma_kernel(
    const unsigned short* __restrict__ Ah_g, const unsigned short* __restrict__ Al_g,
    const unsigned short* __restrict__ Hh_g, const unsigned short* __restrict__ Hl_g,
    const float* __restrict__ style, const float* __restrict__ abar,
    float* __restrict__ x, unsigned short* __restrict__ xh,
    unsigned short* __restrict__ xl, float* __restrict__ mv)
{
    __shared__ __align__(16) unsigned short Ah_s[128 * 64];
    __shared__ __align__(16) unsigned short Al_s[128 * 64];
    __shared__ __align__(16) unsigned short Bh_s[64 * 64];
    __shared__ __align__(16) unsigned short Bl_s[64 * 64];
    __shared__ float mvred[64];
    const int tid = threadIdx.x;
    const int b = blockIdx.z, bm = blockIdx.x, bn = blockIdx.y;
    const int l = tid & 63, wave = tid >> 6;
    const int wr = wave >> 1, wc = wave & 1;
    if (mv && tid < 64) mvred[tid] = 0.f;

    const unsigned short* Ag_h = Ah_g + ((size_t)(b * 1024 + bm * 128)) * 1024;
    const unsigned short* Ag_l = Al_g + ((size_t)(b * 1024 + bm * 128)) * 1024;
    const unsigned short* Hg_h = Hh_g + ((size_t)(b * 256 + bn * 64)) * 1024;
    const unsigned short* Hg_l = Hl_g + ((size_t)(b * 256 + bn * 64)) * 1024;

    f32x4 acc[4][2];
#pragma unroll
    for (int i = 0; i < 4; ++i)
#pragma unroll
        for (int j = 0; j < 2; ++j) acc[i][j] = (f32x4){0.f, 0.f, 0.f, 0.f};

    for (int kt = 0; kt < 16; ++kt) {
        stage_tile(Ag_h + kt * 64, 1024, Ah_s, tid, 4);
        stage_tile(Ag_l + kt * 64, 1024, Al_s, tid, 4);
        stage_tile(Hg_h + kt * 64, 1024, Bh_s, tid, 2);
        stage_tile(Hg_l + kt * 64, 1024, Bl_s, tid, 2);
        __syncthreads();
#pragma unroll
        for (int ks = 0; ks < 2; ++ks) {
            bf16x8 ah[4], al[4], bh[2], bl[2];
#pragma unroll
            for (int fm = 0; fm < 4; ++fm) {
                int row = wr * 64 + fm * 16 + (l & 15);
                int idx = frag_idx(row, ks, l);
                ah[fm] = *(const bf16x8*)&Ah_s[idx];
                al[fm] = *(const bf16x8*)&Al_s[idx];
            }
#pragma unroll
            for (int fn = 0; fn < 2; ++fn) {
                int row = wc * 32 + fn * 16 + (l & 15);
                int idx = frag_idx(row, ks, l);
                bh[fn] = *(const bf16x8*)&Bh_s[idx];
                bl[fn] = *(const bf16x8*)&Bl_s[idx];
            }
#pragma unroll
            for (int fm = 0; fm < 4; ++fm)
#pragma unroll
                for (int fn = 0; fn < 2; ++fn) {
                    acc[fm][fn] = __builtin_amdgcn_mfma_f32_16x16x32_bf16(ah[fm], bh[fn], acc[fm][fn], 0, 0, 0);
                    acc[fm][fn] = __builtin_amdgcn_mfma_f32_16x16x32_bf16(ah[fm], bl[fn], acc[fm][fn], 0, 0, 0);
                    acc[fm][fn] = __builtin_amdgcn_mfma_f32_16x16x32_bf16(al[fm], bh[fn], acc[fm][fn], 0, 0, 0);
                }
        }
        __syncthreads();
    }

    const float* st = style + b * 2 * CDIM;
#pragma unroll
    for (int fn = 0; fn < 2; ++fn) {
        int col = bn * 64 + wc * 32 + fn * 16 + (l & 15);
        float ga = st[col], be = st[CDIM + col];
        float pmv = 0.f;
#pragma unroll
        for (int fm = 0; fm < 4; ++fm) {
            int m0 = bm * 128 + wr * 64 + fm * 16 + (l >> 4) * 4;
#pragma unroll
            for (int r = 0; r < 4; ++r) {
                float v = lrelu(ga * acc[fm][fn][r] + be);
                size_t off = ((size_t)(b * 1024 + m0 + r)) * 256 + col;
                if (x) x[off] = v;
                if (xh) {
                    unsigned short h = bf16_hi(v);
                    xh[off] = h;
                    xl[off] = bf16_hi(v - bf16_tof(h));
                }
                pmv += abar[b * 1024 + m0 + r] * v;
            }
        }
        if (mv) atomicAdd(&mvred[wc * 32 + fn * 16 + (l & 15)], pmv);
    }
    if (mv) {
        __syncthreads();
        if (tid < 64) atomicAdd(&mv[b * 256 + bn * 64 + tid], mvred[tid]);
    }
}

// ---------------------------------------------------------------------------
// MFMA split-3 GEMM (h1 = x @ W'^T + b, transposed bf16 output) PLUS the
// per-batch style MLP folded in as 8 extra blocks (blockIdx.y == 4).
// The MLP blocks run concurrently with the 256 GEMM blocks, so their
// latency-bound weight streaming hides under the GEMM. grid (64, 5).
// ---------------------------------------------------------------------------
__global__ __launch_bounds__(256) void gemm_nt_mfma_kernel(
    const unsigned short* __restrict__ xh_g, const unsigned short* __restrict__ xl_g,
    const unsigned short* __restrict__ Wh, const unsigned short* __restrict__ Wl,
    const float* __restrict__ bias,
    unsigned short* __restrict__ h1t_h, unsigned short* __restrict__ h1t_l,
    const float* __restrict__ mv, const float* __restrict__ sumabar,
    const float* __restrict__ Wblk_f,
    const float* __restrict__ W1, const float* __restrict__ b1,
    const float* __restrict__ W2, const float* __restrict__ b2,
    float* __restrict__ style, float sc_c, float sc_2c)
{
    __shared__ __align__(16) unsigned short Ah_s[128 * 64];
    __shared__ __align__(16) unsigned short Al_s[128 * 64];
    __shared__ __align__(16) unsigned short Bh_s[64 * 64];
    __shared__ __align__(16) unsigned short Bl_s[64 * 64];
    __shared__ float mvs[256];
    __shared__ float m_s[256];
    __shared__ float s1_s[512];
    const int tid = threadIdx.x;
    const int bm = blockIdx.x, bn = blockIdx.y;

    if (bn == 4) {
        // ---- style MLP for batch bm (bm < 8) ----
        if (bm >= BATCH) return;
        const int bb = bm;
        const int t = tid;
        mvs[t] = mv[bb * 256 + t];
        __syncthreads();
        {   // layer A: m = sc_c * Wblk @ mv + sumabar*bias
            const float* wr = Wblk_f + (size_t)t * 256;
            float acc = 0.f;
#pragma unroll 8
            for (int k = 0; k < 64; ++k) {
                float4 w = *(const float4*)(wr + k * 4);
                float4 v = *(const float4*)(mvs + k * 4);
                acc += w.x * v.x + w.y * v.y + w.z * v.z + w.w * v.w;
            }
            m_s[t] = sc_c * acc + sumabar[bb] * bias[t];
        }
        __syncthreads();
        {   // layer B: s1 = lrelu(sc_c * W1 @ m + b1), 512 outputs, 2/thread
            const float* wa = W1 + (size_t)t * 256;
            const float* wb = W1 + (size_t)(t + 256) * 256;
            float acc1 = 0.f, acc2 = 0.f;
#pragma unroll 8
            for (int k = 0; k < 64; ++k) {
                float4 v = *(const float4*)(m_s + k * 4);
                float4 w1v = *(const float4*)(wa + k * 4);
                float4 w2v = *(const float4*)(wb + k * 4);
                acc1 += w1v.x * v.x + w1v.y * v.y + w1v.z * v.z + w1v.w * v.w;
                acc2 += w2v.x * v.x + w2v.y * v.y + w2v.z * v.z + w2v.w * v.w;
            }
            s1_s[t] = lrelu(sc_c * acc1 + b1[t]);
            s1_s[t + 256] = lrelu(sc_c * acc2 + b1[t + 256]);
        }
        __syncthreads();
        {   // layer C: style = sc_2c * W2 @ s1 + b2, 512 outputs, 2/thread
            const float* wa = W2 + (size_t)t * 512;
            const float* wb = W2 + (size_t)(t + 256) * 512;
            float acc1 = 0.f, acc2 = 0.f;
#pragma unroll 8
            for (int k = 0; k < 128; ++k) {
                float4 v = *(const float4*)(s1_s + k * 4);
                float4 w1v = *(const float4*)(wa + k * 4);
                float4 w2v = *(const float4*)(wb + k * 4);
                acc1 += w1v.x * v.x + w1v.y * v.y + w1v.z * v.z + w1v.w * v.w;
                acc2 += w2v.x * v.x + w2v.y * v.y + w2v.z * v.z + w2v.w * v.w;
            }
            style[bb * 512 + t] = sc_2c * acc1 + b2[t];
            style[bb * 512 + t + 256] = sc_2c * acc2 + b2[t + 256];
        }
        return;
    }

    // ---- GEMM path ----
    const int l = tid & 63, wave = tid >> 6;
    const int wr = wave >> 1, wc = wave & 1;
    const int row0 = bm * 128;
    const int b = row0 >> 10;

    const unsigned short* Ag_h = xh_g + (size_t)row0 * 256;
    const unsigned short* Ag_l = xl_g + (size_t)row0 * 256;
    const unsigned short* Bg_h = Wh + (size_t)(bn * 64) * 256;
    const unsigned short* Bg_l = Wl + (size_t)(bn * 64) * 256;

    f32x4 acc[4][2];
#pragma unroll
    for (int i = 0; i < 4; ++i)
#pragma unroll
        for (int j = 0; j < 2; ++j) acc[i][j] = (f32x4){0.f, 0.f, 0.f, 0.f};

    for (int kt = 0; kt < 4; ++kt) {
        stage_tile(Ag_h + kt * 64, 256, Ah_s, tid, 4);
        stage_tile(Ag_l + kt * 64, 256, Al_s, tid, 4);
        stage_tile(Bg_h + kt * 64, 256, Bh_s, tid, 2);
        stage_tile(Bg_l + kt * 64, 256, Bl_s, tid, 2);
        __syncthreads();
#pragma unroll
        for (int ks = 0; ks < 2; ++ks) {
            bf16x8 ah[4], al[4], bh[2], bl[2];
#pragma unroll
            for (int fm = 0; fm < 4; ++fm) {
                int row = wr * 64 + fm * 16 + (l & 15);
                int idx = frag_idx(row, ks, l);
                ah[fm] = *(const bf16x8*)&Ah_s[idx];
                al[fm] = *(const bf16x8*)&Al_s[idx];
            }
#pragma unroll
            for (int fn = 0; fn < 2; ++fn) {
                int row = wc * 32 + fn * 16 + (l & 15);
                int idx = frag_idx(row, ks, l);
                bh[fn] = *(const bf16x8*)&Bh_s[idx];
                bl[fn] = *(const bf16x8*)&Bl_s[idx];
            }
#pragma unroll
            for (int fm = 0; fm < 4; ++fm)
#pragma unroll
                for (int fn = 0; fn < 2; ++fn) {
                    acc[fm][fn] = __builtin_amdgcn_mfma_f32_16x16x32_bf16(ah[fm], bh[fn], acc[fm][fn], 0, 0, 0);
                    acc[fm][fn] = __builtin_amdgcn_mfma_f32_16x16x32_bf16(ah[fm], bl[fn], acc[fm][fn], 0, 0, 0);
                    acc[fm][fn] = __builtin_amdgcn_mfma_f32_16x16x32_bf16(al[fm], bh[fn], acc[fm][fn], 0, 0, 0);
                }
        }
        __syncthreads();
    }

#pragma unroll
    for (int fn = 0; fn < 2; ++fn) {
        int col = bn * 64 + wc * 32 + fn * 16 + (l & 15);
        float bi = bias[col];
#pragma unroll
        for (int fm = 0; fm < 4; ++fm) {
            int s0 = (row0 & 1023) + wr * 64 + fm * 16 + (l >> 4) * 4;
            float v0 = acc[fm][fn][0] + bi;
            float v1 = acc[fm][fn][1] + bi;
            float v2 = acc[fm][fn][2] + bi;
            float v3 = acc[fm][fn][3] + bi;
            ushort4 hv, lv;
            hv.x = bf16_hi(v0); lv.x = bf16_hi(v0 - bf16_tof(hv.x));
            hv.y = bf16_hi(v1); lv.y = bf16_hi(v1 - bf16_tof(hv.y));
            hv.z = bf16_hi(v2); lv.z = bf16_hi(v2 - bf16_tof(hv.z));
            hv.w = bf16_hi(v3); lv.w = bf16_hi(v3 - bf16_tof(hv.w));
            size_t off = ((size_t)(b * 256 + col)) * 1024 + s0;
            *(ushort4*)&h1t_h[off] = hv;
            *(ushort4*)&h1t_l[off] = lv;
        }
    }
}

// ---------------------------------------------------------------------------
// fp32 VALU gemm_nt (proj only) + mv + bf16 emit
// ---------------------------------------------------------------------------
#define BM 64
#define BN 64
#define BK 16
__global__ __launch_bounds__(256) void gemm_nt_kernel(
    const float* __restrict__ A, const float* __restrict__ B,
    float* __restrict__ C, int K, float alpha, const float* __restrict__ bias,
    const float* __restrict__ abar, float* __restrict__ mv,
    unsigned short* __restrict__ xh, unsigned short* __restrict__ xl)
{
    __shared__ float As[BK][BM + 4];
    __shared__ float Bs[BK][BN + 4];
    __shared__ float red[16][BN];
    const int tid = threadIdx.x;
    const int bm = blockIdx.x, bn = blockIdx.y;
    const int tx = tid & 15, ty = tid >> 4;
    const int lrow = tid >> 2;
    const int lk = (tid & 3) << 2;
    const float* Ag = A + (size_t)(bm * BM + lrow) * K + lk;
    const float* Bg = B + (size_t)(bn * BN + lrow) * K + lk;
    float acc[4][4] = {};

    for (int k0 = 0; k0 < K; k0 += BK) {
        float4 av = *(const float4*)(Ag + k0);
        float4 bv = *(const float4*)(Bg + k0);
        __syncthreads();
        As[lk + 0][lrow] = av.x; As[lk + 1][lrow] = av.y;
        As[lk + 2][lrow] = av.z; As[lk + 3][lrow] = av.w;
        Bs[lk + 0][lrow] = bv.x; Bs[lk + 1][lrow] = bv.y;
        Bs[lk + 2][lrow] = bv.z; Bs[lk + 3][lrow] = bv.w;
        __syncthreads();
#pragma unroll
        for (int kk = 0; kk < BK; ++kk) {
            const float4 a = *(const float4*)&As[kk][ty << 2];
            const float4 b = *(const float4*)&Bs[kk][tx << 2];
            float ar[4] = {a.x, a.y, a.z, a.w};
            float br[4] = {b.x, b.y, b.z, b.w};
#pragma unroll
            for (int i = 0; i < 4; ++i)
#pragma unroll
                for (int j = 0; j < 4; ++j)
                    acc[i][j] += ar[i] * br[j];
        }
    }
    const int row = bm * BM + (ty << 2);
    const int col = bn * BN + (tx << 2);
    const int b = row >> 10;
    float bi[4] = {bias[col], bias[col + 1], bias[col + 2], bias[col + 3]};
    float o[4][4];
#pragma unroll
    for (int i = 0; i < 4; ++i) {
        float4 ov;
        ov.x = o[i][0] = alpha * acc[i][0] + bi[0];
        ov.y = o[i][1] = alpha * acc[i][1] + bi[1];
        ov.z = o[i][2] = alpha * acc[i][2] + bi[2];
        ov.w = o[i][3] = alpha * acc[i][3] + bi[3];
        *(float4*)(C + (size_t)(row + i) * CDIM + col) = ov;
#pragma unroll
        for (int j = 0; j < 4; ++j) {
            size_t off = (size_t)(row + i) * CDIM + col + j;
            unsigned short h = bf16_hi(o[i][j]);
            xh[off] = h;
            xl[off] = bf16_hi(o[i][j] - bf16_tof(h));
        }
    }
    {
        float p[4];
#pragma unroll
        for (int j = 0; j < 4; ++j) {
            p[j] = 0.f;
#pragma unroll
            for (int i = 0; i < 4; ++i)
                p[j] += abar[((row + i) & 1023) + (b << 10)] * o[i][j];
            red[ty][(tx << 2) + j] = p[j];
        }
        __syncthreads();
        if (tid < BN) {
            float s = 0.f;
#pragma unroll
            for (int t = 0; t < 16; ++t) s += red[t][tid];
            atomicAdd(&mv[b * CDIM + bn * BN + tid], s);
        }
    }
}

// ---------------------------------------------------------------------------
// color + gather (unchanged)
// ---------------------------------------------------------------------------
__global__ __launch_bounds__(256) void color_kernel(
    const float* __restrict__ x, const float* __restrict__ rgb_w,
    const float* __restrict__ rgb_b, float* __restrict__ color, float sc_c)
{
    const int wave = threadIdx.x >> 6;
    const int lane = threadIdx.x & 63;
    const int r = blockIdx.x * 4 + wave;
    const float4 xv = *(const float4*)(x + (size_t)r * CDIM + lane * 4);
    float p[3];
#pragma unroll
    for (int cc = 0; cc < 3; ++cc) {
        const float4 wv = *(const float4*)(rgb_w + cc * CDIM + lane * 4);
        p[cc] = xv.x * wv.x + xv.y * wv.y + xv.z * wv.z + xv.w * wv.w;
    }
#pragma unroll
    for (int off = 32; off > 0; off >>= 1) {
#pragma unroll
        for (int cc = 0; cc < 3; ++cc) p[cc] += __shfl_down(p[cc], off);
    }
    if (lane == 0) {
#pragma unroll
        for (int cc = 0; cc < 3; ++cc)
            color[(size_t)r * 3 + cc] = sc_c * p[cc] + rgb_b[cc];
    }
}

__global__ __launch_bounds__(256) void gather_kernel(
    const int* __restrict__ seg, const float* __restrict__ color,
    float* __restrict__ out)
{
    int idx = blockIdx.x * 256 + threadIdx.x;
    int b = idx >> 18;
    int p = idx & (N_PIX - 1);
    int s = seg[idx];
    const float* cp = color + ((size_t)b * S_SEG + s) * 3;
    out[((size_t)b * 3 + 0) * N_PIX + p] = tanhf(cp[0]);
    out[((size_t)b * 3 + 1) * N_PIX + p] = tanhf(cp[1]);
    out[((size_t)b * 3 + 2) * N_PIX + p] = tanhf(cp[2]);
}

// ---------------------------------------------------------------------------
extern "C" void kernel_launch(void* const* d_in, const int* in_sizes, int n_in,
                              void* d_out, int out_size, void* d_ws, size_t ws_size,
                              hipStream_t stream)
{
    (void)in_sizes; (void)n_in; (void)out_size; (void)ws_size;
    const float* z      = (const float*)d_in[0];
    const float* images = (const float*)d_in[1];
    const int*   seg    = (const int*)d_in[2];
    const float* A      = (const float*)d_in[3];
    const float* proj_w = (const float*)d_in[4];
    const float* proj_b = (const float*)d_in[5];
    const float* blk_w  = (const float*)d_in[6];
    const float* blk_b  = (const float*)d_in[7];
    const float* ada_w1 = (const float*)d_in[8];
    const float* ada_b1 = (const float*)d_in[9];
    const float* ada_w2 = (const float*)d_in[10];
    const float* ada_b2 = (const float*)d_in[11];
    const float* rgb_w  = (const float*)d_in[12];
    const float* rgb_b  = (const float*)d_in[13];
    float* out = (float*)d_out;

    float* ws = (float*)d_ws;
    float* sums    = ws;                  // 24576
    float* counts  = ws + 24576;          // 8192
    float* sumabar = ws + 32768;          // 16
    float* mv      = ws + 32784;          // 18432
    float* abar    = ws + 51216;          // 8192
    float* style   = ws + 59408;          // 4096
    float* colr    = ws + 63504;          // 24576
    float* wpad    = ws + 88080;          // 36864
    float* xin     = ws + 124944;         // 1179648 -> ends 1304592
    float* x       = ws + 1304592;        // 2097152 -> ends 3401744
    unsigned short* xh    = (unsigned short*)(ws + 3401744);
    unsigned short* xl    = (unsigned short*)(ws + 4450320);
    unsigned short* h1t_h = (unsigned short*)(ws + 5498896);
    unsigned short* h1t_l = (unsigned short*)(ws + 6547472);
    unsigned short* Ah    = (unsigned short*)(ws + 7596048);
    unsigned short* Al    = (unsigned short*)(ws + 11790352);
    unsigned short* Wh    = (unsigned short*)(ws + 15984656);
    unsigned short* Wl    = (unsigned short*)(ws + 16246800);

    const float sc_in = (float)sqrt(2.0 / 131.0);
    const float sc_c  = (float)sqrt(2.0 / 256.0);
    const float sc_2c = (float)sqrt(2.0 / 512.0);

    hipMemsetAsync(sums, 0, 59408 * sizeof(float), stream);  // thru abar
    seg_pool_kernel<<<dim3(BATCH * 32), 256, 0, stream>>>(images, seg, sums, counts);
    conv_split_abar_kernel<<<dim3(256), 256, 0, stream>>>(A, Ah, Al, abar, sumabar);
    prep_xin_kernel<<<dim3((8192 * 144) / 256), 256, 0, stream>>>(sums, counts, z, xin);
    prep_wpad_kernel<<<dim3((256 * 144) / 256), 256, 0, stream>>>(proj_w, wpad);
    conv_split_kernel<<<dim3(512), 256, 0, stream>>>(blk_w, Wh, Wl, sc_c, 131072u);

    gemm_nt_kernel<<<dim3(128, 4), 256, 0, stream>>>(xin, wpad, x, 144, sc_in, proj_b,
                                                     abar, mv, xh, xl);

    for (int i = 0; i < 8; ++i) {
        // GEMM (h1t) + folded style-MLP (8 extra blocks at bn==4)
        gemm_nt_mfma_kernel<<<dim3(64, 5), 256, 0, stream>>>(
            xh, xl, Wh + (size_t)i * 65536, Wl + (size_t)i * 65536,
            blk_b + i * CDIM, h1t_h, h1t_l,
            mv + i * 2048, sumabar, blk_w + (size_t)i * CDIM * CDIM,
            ada_w1 + (size_t)i * 512 * 256, ada_b1 + i * 512,
            ada_w2 + (size_t)i * 512 * 512, ada_b2 + i * 512,
            style, sc_c, sc_2c);
        const bool last = (i == 7);
        gemm_nn_mfma_kernel<<<dim3(8, 4, 8), 256, 0, stream>>>(
            Ah, Al, h1t_h, h1t_l, style, abar,
            last ? x : nullptr,
            last ? nullptr : xh, last ? nullptr : xl,
            last ? nullptr : (mv + (i + 1) * 2048));
    }

    color_kernel<<<dim3(2048), 256, 0, stream>>>(x, rgb_w, rgb_b, colr, sc_c);
    gather_kernel<<<dim3(8192), 256, 0, stream>>>(seg, colr, out);
}

// Round 6
// 672.392 us; speedup vs baseline: 3.3391x; 1.2636x over previous
//
#include <hip/hip_runtime.h>
#include <math.h>

#define N_PIX (512*512)
#define S_SEG 1024
#define CDIM  256
#define BATCH 8

typedef __attribute__((ext_vector_type(4))) float f32x4;
typedef __attribute__((ext_vector_type(8))) short bf16x8;

__device__ __forceinline__ float lrelu(float v) { return v > 0.f ? v : 0.2f * v; }

__device__ __forceinline__ unsigned short bf16_hi(float x) {
    union { float f; unsigned int u; } v; v.f = x;
    unsigned int r = v.u + 0x7FFFu + ((v.u >> 16) & 1u);
    return (unsigned short)(r >> 16);
}
__device__ __forceinline__ float bf16_tof(unsigned short h) {
    union { float f; unsigned int u; } v; v.u = ((unsigned int)h) << 16;
    return v.f;
}
__device__ __forceinline__ float dot4(float4 a, float4 b) {
    return a.x * b.x + a.y * b.y + a.z * b.z + a.w * b.w;
}

// ---------------------------------------------------------------------------
// Segment pooling (unchanged)
// ---------------------------------------------------------------------------
__global__ __launch_bounds__(256) void seg_pool_kernel(
    const float* __restrict__ images, const int* __restrict__ seg,
    float* __restrict__ sums, float* __restrict__ counts)
{
    __shared__ float bins[S_SEG * 4];
    const int b = blockIdx.x >> 5;
    const int chunk = blockIdx.x & 31;
    for (int i = threadIdx.x; i < S_SEG * 4; i += 256) bins[i] = 0.f;
    __syncthreads();

    const int pix_per_block = N_PIX / 32;  // 8192
    const int base = chunk * pix_per_block;
    const float* im = images + (size_t)b * 3 * N_PIX;
    const int* sg = seg + (size_t)b * N_PIX;

    for (int it = 0; it < pix_per_block / 256; ++it) {
        int p = base + it * 256 + threadIdx.x;
        int s = sg[p];
        float r = im[p];
        float g = im[N_PIX + p];
        float bl = im[2 * N_PIX + p];
        atomicAdd(&bins[s * 4 + 0], r);
        atomicAdd(&bins[s * 4 + 1], g);
        atomicAdd(&bins[s * 4 + 2], bl);
        atomicAdd(&bins[s * 4 + 3], 1.f);
    }
    __syncthreads();
    for (int s = threadIdx.x; s < S_SEG; s += 256) {
        float4 v = *(const float4*)&bins[s * 4];
        atomicAdd(&sums[((size_t)b * S_SEG + s) * 3 + 0], v.x);
        atomicAdd(&sums[((size_t)b * S_SEG + s) * 3 + 1], v.y);
        atomicAdd(&sums[((size_t)b * S_SEG + s) * 3 + 2], v.z);
        atomicAdd(&counts[(size_t)b * S_SEG + s], v.w);
    }
}

// ---------------------------------------------------------------------------
// FUSED: A -> (Ah, Al) bf16 split + abar (column means) + sumabar.
// ---------------------------------------------------------------------------
__global__ __launch_bounds__(256) void conv_split_abar_kernel(
    const float* __restrict__ A, unsigned short* __restrict__ Ah,
    unsigned short* __restrict__ Al, float* __restrict__ abar,
    float* __restrict__ sumabar)
{
    const int b = blockIdx.x >> 5;
    const int chunk = blockIdx.x & 31;
    const int t = threadIdx.x;
    const size_t base4 = ((size_t)b * 1024 * 1024 + (size_t)chunk * 32 * 1024) >> 2;
    const float4* Af = ((const float4*)A) + base4;
    ushort4* Ahf = ((ushort4*)Ah) + base4;
    ushort4* Alf = ((ushort4*)Al) + base4;
    float a0 = 0.f, a1 = 0.f, a2 = 0.f, a3 = 0.f;
#pragma unroll 4
    for (int r = 0; r < 32; ++r) {
        float4 v = Af[r * 256 + t];
        ushort4 h, l;
        h.x = bf16_hi(v.x); l.x = bf16_hi(v.x - bf16_tof(h.x));
        h.y = bf16_hi(v.y); l.y = bf16_hi(v.y - bf16_tof(h.y));
        h.z = bf16_hi(v.z); l.z = bf16_hi(v.z - bf16_tof(h.z));
        h.w = bf16_hi(v.w); l.w = bf16_hi(v.w - bf16_tof(h.w));
        Ahf[r * 256 + t] = h;
        Alf[r * 256 + t] = l;
        a0 += v.x; a1 += v.y; a2 += v.z; a3 += v.w;
    }
    const float inv = 1.f / 1024.f;
    atomicAdd(&abar[b * 1024 + t * 4 + 0], a0 * inv);
    atomicAdd(&abar[b * 1024 + t * 4 + 1], a1 * inv);
    atomicAdd(&abar[b * 1024 + t * 4 + 2], a2 * inv);
    atomicAdd(&abar[b * 1024 + t * 4 + 3], a3 * inv);
    __shared__ float red[256];
    red[t] = (a0 + a1 + a2 + a3) * inv;
    __syncthreads();
    for (int off = 128; off > 0; off >>= 1) {
        if (t < off) red[t] += red[t + off];
        __syncthreads();
    }
    if (t == 0) atomicAdd(&sumabar[b], red[0]);
}

__global__ __launch_bounds__(256) void prep_xin_kernel(
    const float* __restrict__ sums, const float* __restrict__ counts,
    const float* __restrict__ z, float* __restrict__ xin)
{
    int idx = blockIdx.x * 256 + threadIdx.x;
    int r = idx / 144, c = idx % 144;
    int b = r >> 10;
    float v;
    if (c < 3)        v = sums[r * 3 + c] / (counts[r] + 1e-6f);
    else if (c < 131) v = z[b * 128 + (c - 3)];
    else              v = 0.f;
    xin[idx] = v;
}

__global__ __launch_bounds__(256) void prep_wpad_kernel(
    const float* __restrict__ proj_w, float* __restrict__ wpad)
{
    int idx = blockIdx.x * 256 + threadIdx.x;
    int n = idx / 144, k = idx % 144;
    wpad[idx] = (k < 131) ? proj_w[n * 131 + k] : 0.f;
}

// ---------------------------------------------------------------------------
// fp32 -> (bf16 hi, bf16 lo) split with scale (weights only)
// ---------------------------------------------------------------------------
__global__ __launch_bounds__(256) void conv_split_kernel(
    const float* __restrict__ in, unsigned short* __restrict__ hi,
    unsigned short* __restrict__ lo, float scale, unsigned int n4)
{
    unsigned int idx = blockIdx.x * 256 + threadIdx.x;
    if (idx >= n4) return;
    float4 v = ((const float4*)in)[idx];
    ushort4 h, l;
    float a;
    a = v.x * scale; h.x = bf16_hi(a); l.x = bf16_hi(a - bf16_tof(h.x));
    a = v.y * scale; h.y = bf16_hi(a); l.y = bf16_hi(a - bf16_tof(h.y));
    a = v.z * scale; h.z = bf16_hi(a); l.z = bf16_hi(a - bf16_tof(h.z));
    a = v.w * scale; h.w = bf16_hi(a); l.w = bf16_hi(a - bf16_tof(h.w));
    ((ushort4*)hi)[idx] = h;
    ((ushort4*)lo)[idx] = l;
}

// ---------------------------------------------------------------------------
// staging helpers (rule #21 both-sides swizzle)
// ---------------------------------------------------------------------------
__device__ __forceinline__ void stage_tile(
    const unsigned short* __restrict__ g, int grow,
    unsigned short* lds, int tid, int nissue)
{
    for (int i = 0; i < nissue; ++i) {
        int c = i * 256 + tid;
        int row = c >> 3, cin = c & 7;
        int cs = cin ^ (row & 7);
        const unsigned short* src = g + (size_t)row * grow + cs * 8;
        unsigned short* dst = lds + (size_t)(i * 256 + (tid & ~63)) * 8;
        __builtin_amdgcn_global_load_lds(
            (const __attribute__((address_space(1))) unsigned int*)src,
            (__attribute__((address_space(3))) unsigned int*)dst, 16, 0, 0);
    }
}

__device__ __forceinline__ int frag_idx(int row, int ks, int l)
{
    int chunk = (ks * 4 + (l >> 4)) ^ (row & 7);
    return row * 64 + chunk * 8;
}

// ---------------------------------------------------------------------------
// MFMA split-3 GEMM: x_out = lrelu(gamma*(A @ h1) + beta) + optional outputs
// ---------------------------------------------------------------------------
__global__ __launch_bounds__(256) void gemm_nn_mfma_kernel(
    const unsigned short* __restrict__ Ah_g, const unsigned short* __restrict__ Al_g,
    const unsigned short* __restrict__ Hh_g, const unsigned short* __restrict__ Hl_g,
    const float* __restrict__ style, const float* __restrict__ abar,
    float* __restrict__ x, unsigned short* __restrict__ xh,
    unsigned short* __restrict__ xl, float* __restrict__ mv)
{
    __shared__ __align__(16) unsigned short Ah_s[128 * 64];
    __shared__ __align__(16) unsigned short Al_s[128 * 64];
    __shared__ __align__(16) unsigned short Bh_s[64 * 64];
    __shared__ __align__(16) unsigned short Bl_s[64 * 64];
    __shared__ float mvred[64];
    const int tid = threadIdx.x;
    const int b = blockIdx.z, bm = blockIdx.x, bn = blockIdx.y;
    const int l = tid & 63, wave = tid >> 6;
    const int wr = wave >> 1, wc = wave & 1;
    if (mv && tid < 64) mvred[tid] = 0.f;

    const unsigned short* Ag_h = Ah_g + ((size_t)(b * 1024 + bm * 128)) * 1024;
    const unsigned short* Ag_l = Al_g + ((size_t)(b * 1024 + bm * 128)) * 1024;
    const unsigned short* Hg_h = Hh_g + ((size_t)(b * 256 + bn * 64)) * 1024;
    const unsigned short* Hg_l = Hl_g + ((size_t)(b * 256 + bn * 64)) * 1024;

    f32x4 acc[4][2];
#pragma unroll
    for (int i = 0; i < 4; ++i)
#pragma unroll
        for (int j = 0; j < 2; ++j) acc[i][j] = (f32x4){0.f, 0.f, 0.f, 0.f};

    for (int kt = 0; kt < 16; ++kt) {
        stage_tile(Ag_h + kt * 64, 1024, Ah_s, tid, 4);
        stage_tile(Ag_l + kt * 64, 1024, Al_s, tid, 4);
        stage_tile(Hg_h + kt * 64, 1024, Bh_s, tid, 2);
        stage_tile(Hg_l + kt * 64, 1024, Bl_s, tid, 2);
        __syncthreads();
#pragma unroll
        for (int ks = 0; ks < 2; ++ks) {
            bf16x8 ah[4], al[4], bh[2], bl[2];
#pragma unroll
            for (int fm = 0; fm < 4; ++fm) {
                int row = wr * 64 + fm * 16 + (l & 15);
                int idx = frag_idx(row, ks, l);
                ah[fm] = *(const bf16x8*)&Ah_s[idx];
                al[fm] = *(const bf16x8*)&Al_s[idx];
            }
#pragma unroll
            for (int fn = 0; fn < 2; ++fn) {
                int row = wc * 32 + fn * 16 + (l & 15);
                int idx = frag_idx(row, ks, l);
                bh[fn] = *(const bf16x8*)&Bh_s[idx];
                bl[fn] = *(const bf16x8*)&Bl_s[idx];
            }
#pragma unroll
            for (int fm = 0; fm < 4; ++fm)
#pragma unroll
                for (int fn = 0; fn < 2; ++fn) {
                    acc[fm][fn] = __builtin_amdgcn_mfma_f32_16x16x32_bf16(ah[fm], bh[fn], acc[fm][fn], 0, 0, 0);
                    acc[fm][fn] = __builtin_amdgcn_mfma_f32_16x16x32_bf16(ah[fm], bl[fn], acc[fm][fn], 0, 0, 0);
                    acc[fm][fn] = __builtin_amdgcn_mfma_f32_16x16x32_bf16(al[fm], bh[fn], acc[fm][fn], 0, 0, 0);
                }
        }
        __syncthreads();
    }

    const float* st = style + b * 2 * CDIM;
#pragma unroll
    for (int fn = 0; fn < 2; ++fn) {
        int col = bn * 64 + wc * 32 + fn * 16 + (l & 15);
        float ga = st[col], be = st[CDIM + col];
        float pmv = 0.f;
#pragma unroll
        for (int fm = 0; fm < 4; ++fm) {
            int m0 = bm * 128 + wr * 64 + fm * 16 + (l >> 4) * 4;
#pragma unroll
            for (int r = 0; r < 4; ++r) {
                float v = lrelu(ga * acc[fm][fn][r] + be);
                size_t off = ((size_t)(b * 1024 + m0 + r)) * 256 + col;
                if (x) x[off] = v;
                if (xh) {
                    unsigned short h = bf16_hi(v);
                    xh[off] = h;
                    xl[off] = bf16_hi(v - bf16_tof(h));
                }
                pmv += abar[b * 1024 + m0 + r] * v;
            }
        }
        if (mv) atomicAdd(&mvred[wc * 32 + fn * 16 + (l & 15)], pmv);
    }
    if (mv) {
        __syncthreads();
        if (tid < 64) atomicAdd(&mv[b * 256 + bn * 64 + tid], mvred[tid]);
    }
}

// ---------------------------------------------------------------------------
// MFMA split-3 GEMM (h1 = x @ W'^T + b, transposed bf16 output) PLUS the
// per-batch style MLP folded in at blockIdx.y == 4 (32 blocks, 4 per batch).
// MLP path is wave-per-output GEMV: one float4 per lane per weight row,
// groups of 8 outputs in flight, shuffle-butterfly reduce. Layers A,B are
// computed redundantly in all 4 blocks of a batch (weights L2-shared);
// layer C (1 MB) is split 4-ways. grid (64, 5).
// ---------------------------------------------------------------------------
__global__ __launch_bounds__(256) void gemm_nt_mfma_kernel(
    const unsigned short* __restrict__ xh_g, const unsigned short* __restrict__ xl_g,
    const unsigned short* __restrict__ Wh, const unsigned short* __restrict__ Wl,
    const float* __restrict__ bias,
    unsigned short* __restrict__ h1t_h, unsigned short* __restrict__ h1t_l,
    const float* __restrict__ mv, const float* __restrict__ sumabar,
    const float* __restrict__ Wblk_f,
    const float* __restrict__ W1, const float* __restrict__ b1,
    const float* __restrict__ W2, const float* __restrict__ b2,
    float* __restrict__ style, float sc_c, float sc_2c)
{
    __shared__ __align__(16) unsigned short Ah_s[128 * 64];
    __shared__ __align__(16) unsigned short Al_s[128 * 64];
    __shared__ __align__(16) unsigned short Bh_s[64 * 64];
    __shared__ __align__(16) unsigned short Bl_s[64 * 64];
    const int tid = threadIdx.x;
    const int bm = blockIdx.x, bn = blockIdx.y;

    if (bn == 4) {
        // ---- style MLP: block bm = batch*4 + quarter ----
        if (bm >= BATCH * 4) return;
        const int bb = bm >> 2;
        const int q = bm & 3;
        const int w = tid >> 6, lane = tid & 63;
        float* m_s = (float*)Ah_s;          // 256 floats (alias GEMM LDS)
        float* s1_s = (float*)Bh_s;         // 512 floats

        const float4 mvreg = *(const float4*)&mv[bb * 256 + lane * 4];
        const float sab = sumabar[bb];

        // Layer A: 256 outputs; wave owns 64; 8 groups of 8
        for (int g = 0; g < 8; ++g) {
            const int o0 = w * 64 + g * 8;
            float p[8];
#pragma unroll
            for (int j = 0; j < 8; ++j) {
                const float4 wv = *(const float4*)&Wblk_f[(size_t)(o0 + j) * 256 + lane * 4];
                p[j] = dot4(wv, mvreg);
            }
#pragma unroll
            for (int off = 32; off > 0; off >>= 1)
#pragma unroll
                for (int j = 0; j < 8; ++j) p[j] += __shfl_xor(p[j], off);
            if (lane == 0)
#pragma unroll
                for (int j = 0; j < 8; ++j)
                    m_s[o0 + j] = sc_c * p[j] + sab * bias[o0 + j];
        }
        __syncthreads();
        const float4 mreg = *(const float4*)&m_s[lane * 4];

        // Layer B: 512 outputs; wave owns 128; 16 groups of 8
        for (int g = 0; g < 16; ++g) {
            const int o0 = w * 128 + g * 8;
            float p[8];
#pragma unroll
            for (int j = 0; j < 8; ++j) {
                const float4 wv = *(const float4*)&W1[(size_t)(o0 + j) * 256 + lane * 4];
                p[j] = dot4(wv, mreg);
            }
#pragma unroll
            for (int off = 32; off > 0; off >>= 1)
#pragma unroll
                for (int j = 0; j < 8; ++j) p[j] += __shfl_xor(p[j], off);
            if (lane == 0)
#pragma unroll
                for (int j = 0; j < 8; ++j)
                    s1_s[o0 + j] = lrelu(sc_c * p[j] + b1[o0 + j]);
        }
        __syncthreads();
        const float4 sa = *(const float4*)&s1_s[lane * 4];
        const float4 sb = *(const float4*)&s1_s[256 + lane * 4];

        // Layer C: this block's quarter (128 outputs); wave owns 32; 4 groups
        for (int g = 0; g < 4; ++g) {
            const int o0 = q * 128 + w * 32 + g * 8;
            float p[8];
#pragma unroll
            for (int j = 0; j < 8; ++j) {
                const float4 wa = *(const float4*)&W2[(size_t)(o0 + j) * 512 + lane * 4];
                const float4 wb = *(const float4*)&W2[(size_t)(o0 + j) * 512 + 256 + lane * 4];
                p[j] = dot4(wa, sa) + dot4(wb, sb);
            }
#pragma unroll
            for (int off = 32; off > 0; off >>= 1)
#pragma unroll
                for (int j = 0; j < 8; ++j) p[j] += __shfl_xor(p[j], off);
            if (lane == 0)
#pragma unroll
                for (int j = 0; j < 8; ++j)
                    style[bb * 512 + o0 + j] = sc_2c * p[j] + b2[o0 + j];
        }
        return;
    }

    // ---- GEMM path ----
    const int l = tid & 63, wave = tid >> 6;
    const int wr = wave >> 1, wc = wave & 1;
    const int row0 = bm * 128;
    const int b = row0 >> 10;

    const unsigned short* Ag_h = xh_g + (size_t)row0 * 256;
    const unsigned short* Ag_l = xl_g + (size_t)row0 * 256;
    const unsigned short* Bg_h = Wh + (size_t)(bn * 64) * 256;
    const unsigned short* Bg_l = Wl + (size_t)(bn * 64) * 256;

    f32x4 acc[4][2];
#pragma unroll
    for (int i = 0; i < 4; ++i)
#pragma unroll
        for (int j = 0; j < 2; ++j) acc[i][j] = (f32x4){0.f, 0.f, 0.f, 0.f};

    for (int kt = 0; kt < 4; ++kt) {
        stage_tile(Ag_h + kt * 64, 256, Ah_s, tid, 4);
        stage_tile(Ag_l + kt * 64, 256, Al_s, tid, 4);
        stage_tile(Bg_h + kt * 64, 256, Bh_s, tid, 2);
        stage_tile(Bg_l + kt * 64, 256, Bl_s, tid, 2);
        __syncthreads();
#pragma unroll
        for (int ks = 0; ks < 2; ++ks) {
            bf16x8 ah[4], al[4], bh[2], bl[2];
#pragma unroll
            for (int fm = 0; fm < 4; ++fm) {
                int row = wr * 64 + fm * 16 + (l & 15);
                int idx = frag_idx(row, ks, l);
                ah[fm] = *(const bf16x8*)&Ah_s[idx];
                al[fm] = *(const bf16x8*)&Al_s[idx];
            }
#pragma unroll
            for (int fn = 0; fn < 2; ++fn) {
                int row = wc * 32 + fn * 16 + (l & 15);
                int idx = frag_idx(row, ks, l);
                bh[fn] = *(const bf16x8*)&Bh_s[idx];
                bl[fn] = *(const bf16x8*)&Bl_s[idx];
            }
#pragma unroll
            for (int fm = 0; fm < 4; ++fm)
#pragma unroll
                for (int fn = 0; fn < 2; ++fn) {
                    acc[fm][fn] = __builtin_amdgcn_mfma_f32_16x16x32_bf16(ah[fm], bh[fn], acc[fm][fn], 0, 0, 0);
                    acc[fm][fn] = __builtin_amdgcn_mfma_f32_16x16x32_bf16(ah[fm], bl[fn], acc[fm][fn], 0, 0, 0);
                    acc[fm][fn] = __builtin_amdgcn_mfma_f32_16x16x32_bf16(al[fm], bh[fn], acc[fm][fn], 0, 0, 0);
                }
        }
        __syncthreads();
    }

#pragma unroll
    for (int fn = 0; fn < 2; ++fn) {
        int col = bn * 64 + wc * 32 + fn * 16 + (l & 15);
        float bi = bias[col];
#pragma unroll
        for (int fm = 0; fm < 4; ++fm) {
            int s0 = (row0 & 1023) + wr * 64 + fm * 16 + (l >> 4) * 4;
            float v0 = acc[fm][fn][0] + bi;
            float v1 = acc[fm][fn][1] + bi;
            float v2 = acc[fm][fn][2] + bi;
            float v3 = acc[fm][fn][3] + bi;
            ushort4 hv, lv;
            hv.x = bf16_hi(v0); lv.x = bf16_hi(v0 - bf16_tof(hv.x));
            hv.y = bf16_hi(v1); lv.y = bf16_hi(v1 - bf16_tof(hv.y));
            hv.z = bf16_hi(v2); lv.z = bf16_hi(v2 - bf16_tof(hv.z));
            hv.w = bf16_hi(v3); lv.w = bf16_hi(v3 - bf16_tof(hv.w));
            size_t off = ((size_t)(b * 256 + col)) * 1024 + s0;
            *(ushort4*)&h1t_h[off] = hv;
            *(ushort4*)&h1t_l[off] = lv;
        }
    }
}

// ---------------------------------------------------------------------------
// fp32 VALU gemm_nt (proj only) + mv + bf16 emit
// ---------------------------------------------------------------------------
#define BM 64
#define BN 64
#define BK 16
__global__ __launch_bounds__(256) void gemm_nt_kernel(
    const float* __restrict__ A, const float* __restrict__ B,
    float* __restrict__ C, int K, float alpha, const float* __restrict__ bias,
    const float* __restrict__ abar, float* __restrict__ mv,
    unsigned short* __restrict__ xh, unsigned short* __restrict__ xl)
{
    __shared__ float As[BK][BM + 4];
    __shared__ float Bs[BK][BN + 4];
    __shared__ float red[16][BN];
    const int tid = threadIdx.x;
    const int bm = blockIdx.x, bn = blockIdx.y;
    const int tx = tid & 15, ty = tid >> 4;
    const int lrow = tid >> 2;
    const int lk = (tid & 3) << 2;
    const float* Ag = A + (size_t)(bm * BM + lrow) * K + lk;
    const float* Bg = B + (size_t)(bn * BN + lrow) * K + lk;
    float acc[4][4] = {};

    for (int k0 = 0; k0 < K; k0 += BK) {
        float4 av = *(const float4*)(Ag + k0);
        float4 bv = *(const float4*)(Bg + k0);
        __syncthreads();
        As[lk + 0][lrow] = av.x; As[lk + 1][lrow] = av.y;
        As[lk + 2][lrow] = av.z; As[lk + 3][lrow] = av.w;
        Bs[lk + 0][lrow] = bv.x; Bs[lk + 1][lrow] = bv.y;
        Bs[lk + 2][lrow] = bv.z; Bs[lk + 3][lrow] = bv.w;
        __syncthreads();
#pragma unroll
        for (int kk = 0; kk < BK; ++kk) {
            const float4 a = *(const float4*)&As[kk][ty << 2];
            const float4 b = *(const float4*)&Bs[kk][tx << 2];
            float ar[4] = {a.x, a.y, a.z, a.w};
            float br[4] = {b.x, b.y, b.z, b.w};
#pragma unroll
            for (int i = 0; i < 4; ++i)
#pragma unroll
                for (int j = 0; j < 4; ++j)
                    acc[i][j] += ar[i] * br[j];
        }
    }
    const int row = bm * BM + (ty << 2);
    const int col = bn * BN + (tx << 2);
    const int b = row >> 10;
    float bi[4] = {bias[col], bias[col + 1], bias[col + 2], bias[col + 3]};
    float o[4][4];
#pragma unroll
    for (int i = 0; i < 4; ++i) {
        float4 ov;
        ov.x = o[i][0] = alpha * acc[i][0] + bi[0];
        ov.y = o[i][1] = alpha * acc[i][1] + bi[1];
        ov.z = o[i][2] = alpha * acc[i][2] + bi[2];
        ov.w = o[i][3] = alpha * acc[i][3] + bi[3];
        *(float4*)(C + (size_t)(row + i) * CDIM + col) = ov;
#pragma unroll
        for (int j = 0; j < 4; ++j) {
            size_t off = (size_t)(row + i) * CDIM + col + j;
            unsigned short h = bf16_hi(o[i][j]);
            xh[off] = h;
            xl[off] = bf16_hi(o[i][j] - bf16_tof(h));
        }
    }
    {
        float p[4];
#pragma unroll
        for (int j = 0; j < 4; ++j) {
            p[j] = 0.f;
#pragma unroll
            for (int i = 0; i < 4; ++i)
                p[j] += abar[((row + i) & 1023) + (b << 10)] * o[i][j];
            red[ty][(tx << 2) + j] = p[j];
        }
        __syncthreads();
        if (tid < BN) {
            float s = 0.f;
#pragma unroll
            for (int t = 0; t < 16; ++t) s += red[t][tid];
            atomicAdd(&mv[b * CDIM + bn * BN + tid], s);
        }
    }
}

// ---------------------------------------------------------------------------
// color + gather (unchanged)
// ---------------------------------------------------------------------------
__global__ __launch_bounds__(256) void color_kernel(
    const float* __restrict__ x, const float* __restrict__ rgb_w,
    const float* __restrict__ rgb_b, float* __restrict__ color, float sc_c)
{
    const int wave = threadIdx.x >> 6;
    const int lane = threadIdx.x & 63;
    const int r = blockIdx.x * 4 + wave;
    const float4 xv = *(const float4*)(x + (size_t)r * CDIM + lane * 4);
    float p[3];
#pragma unroll
    for (int cc = 0; cc < 3; ++cc) {
        const float4 wv = *(const float4*)(rgb_w + cc * CDIM + lane * 4);
        p[cc] = xv.x * wv.x + xv.y * wv.y + xv.z * wv.z + xv.w * wv.w;
    }
#pragma unroll
    for (int off = 32; off > 0; off >>= 1) {
#pragma unroll
        for (int cc = 0; cc < 3; ++cc) p[cc] += __shfl_down(p[cc], off);
    }
    if (lane == 0) {
#pragma unroll
        for (int cc = 0; cc < 3; ++cc)
            color[(size_t)r * 3 + cc] = sc_c * p[cc] + rgb_b[cc];
    }
}

__global__ __launch_bounds__(256) void gather_kernel(
    const int* __restrict__ seg, const float* __restrict__ color,
    float* __restrict__ out)
{
    int idx = blockIdx.x * 256 + threadIdx.x;
    int b = idx >> 18;
    int p = idx & (N_PIX - 1);
    int s = seg[idx];
    const float* cp = color + ((size_t)b * S_SEG + s) * 3;
    out[((size_t)b * 3 + 0) * N_PIX + p] = tanhf(cp[0]);
    out[((size_t)b * 3 + 1) * N_PIX + p] = tanhf(cp[1]);
    out[((size_t)b * 3 + 2) * N_PIX + p] = tanhf(cp[2]);
}

// ---------------------------------------------------------------------------
extern "C" void kernel_launch(void* const* d_in, const int* in_sizes, int n_in,
                              void* d_out, int out_size, void* d_ws, size_t ws_size,
                              hipStream_t stream)
{
    (void)in_sizes; (void)n_in; (void)out_size; (void)ws_size;
    const float* z      = (const float*)d_in[0];
    const float* images = (const float*)d_in[1];
    const int*   seg    = (const int*)d_in[2];
    const float* A      = (const float*)d_in[3];
    const float* proj_w = (const float*)d_in[4];
    const float* proj_b = (const float*)d_in[5];
    const float* blk_w  = (const float*)d_in[6];
    const float* blk_b  = (const float*)d_in[7];
    const float* ada_w1 = (const float*)d_in[8];
    const float* ada_b1 = (const float*)d_in[9];
    const float* ada_w2 = (const float*)d_in[10];
    const float* ada_b2 = (const float*)d_in[11];
    const float* rgb_w  = (const float*)d_in[12];
    const float* rgb_b  = (const float*)d_in[13];
    float* out = (float*)d_out;

    float* ws = (float*)d_ws;
    float* sums    = ws;                  // 24576
    float* counts  = ws + 24576;          // 8192
    float* sumabar = ws + 32768;          // 16
    float* mv      = ws + 32784;          // 18432
    float* abar    = ws + 51216;          // 8192
    float* style   = ws + 59408;          // 4096
    float* colr    = ws + 63504;          // 24576
    float* wpad    = ws + 88080;          // 36864
    float* xin     = ws + 124944;         // 1179648 -> ends 1304592
    float* x       = ws + 1304592;        // 2097152 -> ends 3401744
    unsigned short* xh    = (unsigned short*)(ws + 3401744);
    unsigned short* xl    = (unsigned short*)(ws + 4450320);
    unsigned short* h1t_h = (unsigned short*)(ws + 5498896);
    unsigned short* h1t_l = (unsigned short*)(ws + 6547472);
    unsigned short* Ah    = (unsigned short*)(ws + 7596048);
    unsigned short* Al    = (unsigned short*)(ws + 11790352);
    unsigned short* Wh    = (unsigned short*)(ws + 15984656);
    unsigned short* Wl    = (unsigned short*)(ws + 16246800);

    const float sc_in = (float)sqrt(2.0 / 131.0);
    const float sc_c  = (float)sqrt(2.0 / 256.0);
    const float sc_2c = (float)sqrt(2.0 / 512.0);

    hipMemsetAsync(sums, 0, 59408 * sizeof(float), stream);  // thru abar
    seg_pool_kernel<<<dim3(BATCH * 32), 256, 0, stream>>>(images, seg, sums, counts);
    conv_split_abar_kernel<<<dim3(256), 256, 0, stream>>>(A, Ah, Al, abar, sumabar);
    prep_xin_kernel<<<dim3((8192 * 144) / 256), 256, 0, stream>>>(sums, counts, z, xin);
    prep_wpad_kernel<<<dim3((256 * 144) / 256), 256, 0, stream>>>(proj_w, wpad);
    conv_split_kernel<<<dim3(512), 256, 0, stream>>>(blk_w, Wh, Wl, sc_c, 131072u);

    gemm_nt_kernel<<<dim3(128, 4), 256, 0, stream>>>(xin, wpad, x, 144, sc_in, proj_b,
                                                     abar, mv, xh, xl);

    for (int i = 0; i < 8; ++i) {
        // GEMM (h1t) + folded style-MLP (32 blocks at bn==4, wave-per-output)
        gemm_nt_mfma_kernel<<<dim3(64, 5), 256, 0, stream>>>(
            xh, xl, Wh + (size_t)i * 65536, Wl + (size_t)i * 65536,
            blk_b + i * CDIM, h1t_h, h1t_l,
            mv + i * 2048, sumabar, blk_w + (size_t)i * CDIM * CDIM,
            ada_w1 + (size_t)i * 512 * 256, ada_b1 + i * 512,
            ada_w2 + (size_t)i * 512 * 512, ada_b2 + i * 512,
            style, sc_c, sc_2c);
        const bool last = (i == 7);
        gemm_nn_mfma_kernel<<<dim3(8, 4, 8), 256, 0, stream>>>(
            Ah, Al, h1t_h, h1t_l, style, abar,
            last ? x : nullptr,
            last ? nullptr : xh, last ? nullptr : xl,
            last ? nullptr : (mv + (i + 1) * 2048));
    }

    color_kernel<<<dim3(2048), 256, 0, stream>>>(x, rgb_w, rgb_b, colr, sc_c);
    gather_kernel<<<dim3(8192), 256, 0, stream>>>(seg, colr, out);
}

// Round 7
// 669.594 us; speedup vs baseline: 3.3530x; 1.0042x over previous
//
#include <hip/hip_runtime.h>
#include <math.h>

#define N_PIX (512*512)
#define S_SEG 1024
#define CDIM  256
#define BATCH 8

typedef __attribute__((ext_vector_type(4))) float f32x4;
typedef __attribute__((ext_vector_type(8))) short bf16x8;

__device__ __forceinline__ float lrelu(float v) { return v > 0.f ? v : 0.2f * v; }

__device__ __forceinline__ unsigned short bf16_hi(float x) {
    union { float f; unsigned int u; } v; v.f = x;
    unsigned int r = v.u + 0x7FFFu + ((v.u >> 16) & 1u);
    return (unsigned short)(r >> 16);
}
__device__ __forceinline__ float bf16_tof(unsigned short h) {
    union { float f; unsigned int u; } v; v.u = ((unsigned int)h) << 16;
    return v.f;
}
__device__ __forceinline__ float dot4(float4 a, float4 b) {
    return a.x * b.x + a.y * b.y + a.z * b.z + a.w * b.w;
}

// ---------------------------------------------------------------------------
// Segment pooling: 256 blocks x 1024 threads (16 waves/CU for latency hiding),
// float4-vectorized pixel loads, LDS bins + atomic flush.
// ---------------------------------------------------------------------------
__global__ __launch_bounds__(1024) void seg_pool_kernel(
    const float* __restrict__ images, const int* __restrict__ seg,
    float* __restrict__ sums, float* __restrict__ counts)
{
    __shared__ float bins[S_SEG * 4];
    const int b = blockIdx.x >> 5;
    const int chunk = blockIdx.x & 31;
    const int t = threadIdx.x;
    for (int i = t; i < S_SEG * 4; i += 1024) bins[i] = 0.f;
    __syncthreads();

    const float4* imr = (const float4*)(images + (size_t)b * 3 * N_PIX);
    const float4* img = imr + N_PIX / 4;
    const float4* imb = img + N_PIX / 4;
    const int4* sg4 = (const int4*)(seg + (size_t)b * N_PIX);
    const int base4 = chunk * (N_PIX / 32 / 4);  // 2048 float4 per chunk

#pragma unroll
    for (int it = 0; it < 2; ++it) {
        int p4 = base4 + it * 1024 + t;
        int4 s = sg4[p4];
        float4 r = imr[p4];
        float4 g = img[p4];
        float4 bl = imb[p4];
        atomicAdd(&bins[s.x * 4 + 0], r.x);
        atomicAdd(&bins[s.x * 4 + 1], g.x);
        atomicAdd(&bins[s.x * 4 + 2], bl.x);
        atomicAdd(&bins[s.x * 4 + 3], 1.f);
        atomicAdd(&bins[s.y * 4 + 0], r.y);
        atomicAdd(&bins[s.y * 4 + 1], g.y);
        atomicAdd(&bins[s.y * 4 + 2], bl.y);
        atomicAdd(&bins[s.y * 4 + 3], 1.f);
        atomicAdd(&bins[s.z * 4 + 0], r.z);
        atomicAdd(&bins[s.z * 4 + 1], g.z);
        atomicAdd(&bins[s.z * 4 + 2], bl.z);
        atomicAdd(&bins[s.z * 4 + 3], 1.f);
        atomicAdd(&bins[s.w * 4 + 0], r.w);
        atomicAdd(&bins[s.w * 4 + 1], g.w);
        atomicAdd(&bins[s.w * 4 + 2], bl.w);
        atomicAdd(&bins[s.w * 4 + 3], 1.f);
    }
    __syncthreads();
    if (t < S_SEG) {
        float4 v = *(const float4*)&bins[t * 4];
        if (v.w != 0.f) {
            atomicAdd(&sums[((size_t)b * S_SEG + t) * 3 + 0], v.x);
            atomicAdd(&sums[((size_t)b * S_SEG + t) * 3 + 1], v.y);
            atomicAdd(&sums[((size_t)b * S_SEG + t) * 3 + 2], v.z);
            atomicAdd(&counts[(size_t)b * S_SEG + t], v.w);
        }
    }
}

// ---------------------------------------------------------------------------
// FUSED: A -> (Ah, Al) bf16 split + abar (column means) + sumabar.
// ---------------------------------------------------------------------------
__global__ __launch_bounds__(256) void conv_split_abar_kernel(
    const float* __restrict__ A, unsigned short* __restrict__ Ah,
    unsigned short* __restrict__ Al, float* __restrict__ abar,
    float* __restrict__ sumabar)
{
    const int b = blockIdx.x >> 5;
    const int chunk = blockIdx.x & 31;
    const int t = threadIdx.x;
    const size_t base4 = ((size_t)b * 1024 * 1024 + (size_t)chunk * 32 * 1024) >> 2;
    const float4* Af = ((const float4*)A) + base4;
    ushort4* Ahf = ((ushort4*)Ah) + base4;
    ushort4* Alf = ((ushort4*)Al) + base4;
    float a0 = 0.f, a1 = 0.f, a2 = 0.f, a3 = 0.f;
#pragma unroll 4
    for (int r = 0; r < 32; ++r) {
        float4 v = Af[r * 256 + t];
        ushort4 h, l;
        h.x = bf16_hi(v.x); l.x = bf16_hi(v.x - bf16_tof(h.x));
        h.y = bf16_hi(v.y); l.y = bf16_hi(v.y - bf16_tof(h.y));
        h.z = bf16_hi(v.z); l.z = bf16_hi(v.z - bf16_tof(h.z));
        h.w = bf16_hi(v.w); l.w = bf16_hi(v.w - bf16_tof(h.w));
        Ahf[r * 256 + t] = h;
        Alf[r * 256 + t] = l;
        a0 += v.x; a1 += v.y; a2 += v.z; a3 += v.w;
    }
    const float inv = 1.f / 1024.f;
    atomicAdd(&abar[b * 1024 + t * 4 + 0], a0 * inv);
    atomicAdd(&abar[b * 1024 + t * 4 + 1], a1 * inv);
    atomicAdd(&abar[b * 1024 + t * 4 + 2], a2 * inv);
    atomicAdd(&abar[b * 1024 + t * 4 + 3], a3 * inv);
    __shared__ float red[256];
    red[t] = (a0 + a1 + a2 + a3) * inv;
    __syncthreads();
    for (int off = 128; off > 0; off >>= 1) {
        if (t < off) red[t] += red[t + off];
        __syncthreads();
    }
    if (t == 0) atomicAdd(&sumabar[b], red[0]);
}

__global__ __launch_bounds__(256) void prep_xin_kernel(
    const float* __restrict__ sums, const float* __restrict__ counts,
    const float* __restrict__ z, float* __restrict__ xin)
{
    int idx = blockIdx.x * 256 + threadIdx.x;
    int r = idx / 144, c = idx % 144;
    int b = r >> 10;
    float v;
    if (c < 3)        v = sums[r * 3 + c] / (counts[r] + 1e-6f);
    else if (c < 131) v = z[b * 128 + (c - 3)];
    else              v = 0.f;
    xin[idx] = v;
}

__global__ __launch_bounds__(256) void prep_wpad_kernel(
    const float* __restrict__ proj_w, float* __restrict__ wpad)
{
    int idx = blockIdx.x * 256 + threadIdx.x;
    int n = idx / 144, k = idx % 144;
    wpad[idx] = (k < 131) ? proj_w[n * 131 + k] : 0.f;
}

// ---------------------------------------------------------------------------
// fp32 -> (bf16 hi, bf16 lo) split with scale (weights only)
// ---------------------------------------------------------------------------
__global__ __launch_bounds__(256) void conv_split_kernel(
    const float* __restrict__ in, unsigned short* __restrict__ hi,
    unsigned short* __restrict__ lo, float scale, unsigned int n4)
{
    unsigned int idx = blockIdx.x * 256 + threadIdx.x;
    if (idx >= n4) return;
    float4 v = ((const float4*)in)[idx];
    ushort4 h, l;
    float a;
    a = v.x * scale; h.x = bf16_hi(a); l.x = bf16_hi(a - bf16_tof(h.x));
    a = v.y * scale; h.y = bf16_hi(a); l.y = bf16_hi(a - bf16_tof(h.y));
    a = v.z * scale; h.z = bf16_hi(a); l.z = bf16_hi(a - bf16_tof(h.z));
    a = v.w * scale; h.w = bf16_hi(a); l.w = bf16_hi(a - bf16_tof(h.w));
    ((ushort4*)hi)[idx] = h;
    ((ushort4*)lo)[idx] = l;
}

// ---------------------------------------------------------------------------
// staging helpers (rule #21 both-sides swizzle)
// ---------------------------------------------------------------------------
__device__ __forceinline__ void stage_tile(
    const unsigned short* __restrict__ g, int grow,
    unsigned short* lds, int tid, int nissue)
{
    for (int i = 0; i < nissue; ++i) {
        int c = i * 256 + tid;
        int row = c >> 3, cin = c & 7;
        int cs = cin ^ (row & 7);
        const unsigned short* src = g + (size_t)row * grow + cs * 8;
        unsigned short* dst = lds + (size_t)(i * 256 + (tid & ~63)) * 8;
        __builtin_amdgcn_global_load_lds(
            (const __attribute__((address_space(1))) unsigned int*)src,
            (__attribute__((address_space(3))) unsigned int*)dst, 16, 0, 0);
    }
}

__device__ __forceinline__ int frag_idx(int row, int ks, int l)
{
    int chunk = (ks * 4 + (l >> 4)) ^ (row & 7);
    return row * 64 + chunk * 8;
}

// ---------------------------------------------------------------------------
// MFMA split-3 GEMM: x_out = lrelu(gamma*(A @ h1) + beta) + optional outputs
// ---------------------------------------------------------------------------
__global__ __launch_bounds__(256) void gemm_nn_mfma_kernel(
    const unsigned short* __restrict__ Ah_g, const unsigned short* __restrict__ Al_g,
    const unsigned short* __restrict__ Hh_g, const unsigned short* __restrict__ Hl_g,
    const float* __restrict__ style, const float* __restrict__ abar,
    float* __restrict__ x, unsigned short* __restrict__ xh,
    unsigned short* __restrict__ xl, float* __restrict__ mv)
{
    __shared__ __align__(16) unsigned short Ah_s[128 * 64];
    __shared__ __align__(16) unsigned short Al_s[128 * 64];
    __shared__ __align__(16) unsigned short Bh_s[64 * 64];
    __shared__ __align__(16) unsigned short Bl_s[64 * 64];
    __shared__ float mvred[64];
    const int tid = threadIdx.x;
    const int b = blockIdx.z, bm = blockIdx.x, bn = blockIdx.y;
    const int l = tid & 63, wave = tid >> 6;
    const int wr = wave >> 1, wc = wave & 1;
    if (mv && tid < 64) mvred[tid] = 0.f;

    const unsigned short* Ag_h = Ah_g + ((size_t)(b * 1024 + bm * 128)) * 1024;
    const unsigned short* Ag_l = Al_g + ((size_t)(b * 1024 + bm * 128)) * 1024;
    const unsigned short* Hg_h = Hh_g + ((size_t)(b * 256 + bn * 64)) * 1024;
    const unsigned short* Hg_l = Hl_g + ((size_t)(b * 256 + bn * 64)) * 1024;

    f32x4 acc[4][2];
#pragma unroll
    for (int i = 0; i < 4; ++i)
#pragma unroll
        for (int j = 0; j < 2; ++j) acc[i][j] = (f32x4){0.f, 0.f, 0.f, 0.f};

    for (int kt = 0; kt < 16; ++kt) {
        stage_tile(Ag_h + kt * 64, 1024, Ah_s, tid, 4);
        stage_tile(Ag_l + kt * 64, 1024, Al_s, tid, 4);
        stage_tile(Hg_h + kt * 64, 1024, Bh_s, tid, 2);
        stage_tile(Hg_l + kt * 64, 1024, Bl_s, tid, 2);
        __syncthreads();
#pragma unroll
        for (int ks = 0; ks < 2; ++ks) {
            bf16x8 ah[4], al[4], bh[2], bl[2];
#pragma unroll
            for (int fm = 0; fm < 4; ++fm) {
                int row = wr * 64 + fm * 16 + (l & 15);
                int idx = frag_idx(row, ks, l);
                ah[fm] = *(const bf16x8*)&Ah_s[idx];
                al[fm] = *(const bf16x8*)&Al_s[idx];
            }
#pragma unroll
            for (int fn = 0; fn < 2; ++fn) {
                int row = wc * 32 + fn * 16 + (l & 15);
                int idx = frag_idx(row, ks, l);
                bh[fn] = *(const bf16x8*)&Bh_s[idx];
                bl[fn] = *(const bf16x8*)&Bl_s[idx];
            }
#pragma unroll
            for (int fm = 0; fm < 4; ++fm)
#pragma unroll
                for (int fn = 0; fn < 2; ++fn) {
                    acc[fm][fn] = __builtin_amdgcn_mfma_f32_16x16x32_bf16(ah[fm], bh[fn], acc[fm][fn], 0, 0, 0);
                    acc[fm][fn] = __builtin_amdgcn_mfma_f32_16x16x32_bf16(ah[fm], bl[fn], acc[fm][fn], 0, 0, 0);
                    acc[fm][fn] = __builtin_amdgcn_mfma_f32_16x16x32_bf16(al[fm], bh[fn], acc[fm][fn], 0, 0, 0);
                }
        }
        __syncthreads();
    }

    const float* st = style + b * 2 * CDIM;
#pragma unroll
    for (int fn = 0; fn < 2; ++fn) {
        int col = bn * 64 + wc * 32 + fn * 16 + (l & 15);
        float ga = st[col], be = st[CDIM + col];
        float pmv = 0.f;
#pragma unroll
        for (int fm = 0; fm < 4; ++fm) {
            int m0 = bm * 128 + wr * 64 + fm * 16 + (l >> 4) * 4;
#pragma unroll
            for (int r = 0; r < 4; ++r) {
                float v = lrelu(ga * acc[fm][fn][r] + be);
                size_t off = ((size_t)(b * 1024 + m0 + r)) * 256 + col;
                if (x) x[off] = v;
                if (xh) {
                    unsigned short h = bf16_hi(v);
                    xh[off] = h;
                    xl[off] = bf16_hi(v - bf16_tof(h));
                }
                pmv += abar[b * 1024 + m0 + r] * v;
            }
        }
        if (mv) atomicAdd(&mvred[wc * 32 + fn * 16 + (l & 15)], pmv);
    }
    if (mv) {
        __syncthreads();
        if (tid < 64) atomicAdd(&mv[b * 256 + bn * 64 + tid], mvred[tid]);
    }
}

// ---------------------------------------------------------------------------
// MFMA split-3 GEMM (h1 = x @ W'^T + b, transposed bf16 output) PLUS the
// per-batch style MLP folded in at blockIdx.y == 4 (wave-per-output GEMV).
// ---------------------------------------------------------------------------
__global__ __launch_bounds__(256) void gemm_nt_mfma_kernel(
    const unsigned short* __restrict__ xh_g, const unsigned short* __restrict__ xl_g,
    const unsigned short* __restrict__ Wh, const unsigned short* __restrict__ Wl,
    const float* __restrict__ bias,
    unsigned short* __restrict__ h1t_h, unsigned short* __restrict__ h1t_l,
    const float* __restrict__ mv, const float* __restrict__ sumabar,
    const float* __restrict__ Wblk_f,
    const float* __restrict__ W1, const float* __restrict__ b1,
    const float* __restrict__ W2, const float* __restrict__ b2,
    float* __restrict__ style, float sc_c, float sc_2c)
{
    __shared__ __align__(16) unsigned short Ah_s[128 * 64];
    __shared__ __align__(16) unsigned short Al_s[128 * 64];
    __shared__ __align__(16) unsigned short Bh_s[64 * 64];
    __shared__ __align__(16) unsigned short Bl_s[64 * 64];
    const int tid = threadIdx.x;
    const int bm = blockIdx.x, bn = blockIdx.y;

    if (bn == 4) {
        // ---- style MLP: block bm = batch*4 + quarter ----
        if (bm >= BATCH * 4) return;
        const int bb = bm >> 2;
        const int q = bm & 3;
        const int w = tid >> 6, lane = tid & 63;
        float* m_s = (float*)Ah_s;          // 256 floats (alias GEMM LDS)
        float* s1_s = (float*)Bh_s;         // 512 floats

        const float4 mvreg = *(const float4*)&mv[bb * 256 + lane * 4];
        const float sab = sumabar[bb];

        // Layer A: 256 outputs; wave owns 64; 8 groups of 8
        for (int g = 0; g < 8; ++g) {
            const int o0 = w * 64 + g * 8;
            float p[8];
#pragma unroll
            for (int j = 0; j < 8; ++j) {
                const float4 wv = *(const float4*)&Wblk_f[(size_t)(o0 + j) * 256 + lane * 4];
                p[j] = dot4(wv, mvreg);
            }
#pragma unroll
            for (int off = 32; off > 0; off >>= 1)
#pragma unroll
                for (int j = 0; j < 8; ++j) p[j] += __shfl_xor(p[j], off);
            if (lane == 0)
#pragma unroll
                for (int j = 0; j < 8; ++j)
                    m_s[o0 + j] = sc_c * p[j] + sab * bias[o0 + j];
        }
        __syncthreads();
        const float4 mreg = *(const float4*)&m_s[lane * 4];

        // Layer B: 512 outputs; wave owns 128; 16 groups of 8
        for (int g = 0; g < 16; ++g) {
            const int o0 = w * 128 + g * 8;
            float p[8];
#pragma unroll
            for (int j = 0; j < 8; ++j) {
                const float4 wv = *(const float4*)&W1[(size_t)(o0 + j) * 256 + lane * 4];
                p[j] = dot4(wv, mreg);
            }
#pragma unroll
            for (int off = 32; off > 0; off >>= 1)
#pragma unroll
                for (int j = 0; j < 8; ++j) p[j] += __shfl_xor(p[j], off);
            if (lane == 0)
#pragma unroll
                for (int j = 0; j < 8; ++j)
                    s1_s[o0 + j] = lrelu(sc_c * p[j] + b1[o0 + j]);
        }
        __syncthreads();
        const float4 sa = *(const float4*)&s1_s[lane * 4];
        const float4 sb = *(const float4*)&s1_s[256 + lane * 4];

        // Layer C: this block's quarter (128 outputs); wave owns 32; 4 groups
        for (int g = 0; g < 4; ++g) {
            const int o0 = q * 128 + w * 32 + g * 8;
            float p[8];
#pragma unroll
            for (int j = 0; j < 8; ++j) {
                const float4 wa = *(const float4*)&W2[(size_t)(o0 + j) * 512 + lane * 4];
                const float4 wb = *(const float4*)&W2[(size_t)(o0 + j) * 512 + 256 + lane * 4];
                p[j] = dot4(wa, sa) + dot4(wb, sb);
            }
#pragma unroll
            for (int off = 32; off > 0; off >>= 1)
#pragma unroll
                for (int j = 0; j < 8; ++j) p[j] += __shfl_xor(p[j], off);
            if (lane == 0)
#pragma unroll
                for (int j = 0; j < 8; ++j)
                    style[bb * 512 + o0 + j] = sc_2c * p[j] + b2[o0 + j];
        }
        return;
    }

    // ---- GEMM path ----
    const int l = tid & 63, wave = tid >> 6;
    const int wr = wave >> 1, wc = wave & 1;
    const int row0 = bm * 128;
    const int b = row0 >> 10;

    const unsigned short* Ag_h = xh_g + (size_t)row0 * 256;
    const unsigned short* Ag_l = xl_g + (size_t)row0 * 256;
    const unsigned short* Bg_h = Wh + (size_t)(bn * 64) * 256;
    const unsigned short* Bg_l = Wl + (size_t)(bn * 64) * 256;

    f32x4 acc[4][2];
#pragma unroll
    for (int i = 0; i < 4; ++i)
#pragma unroll
        for (int j = 0; j < 2; ++j) acc[i][j] = (f32x4){0.f, 0.f, 0.f, 0.f};

    for (int kt = 0; kt < 4; ++kt) {
        stage_tile(Ag_h + kt * 64, 256, Ah_s, tid, 4);
        stage_tile(Ag_l + kt * 64, 256, Al_s, tid, 4);
        stage_tile(Bg_h + kt * 64, 256, Bh_s, tid, 2);
        stage_tile(Bg_l + kt * 64, 256, Bl_s, tid, 2);
        __syncthreads();
#pragma unroll
        for (int ks = 0; ks < 2; ++ks) {
            bf16x8 ah[4], al[4], bh[2], bl[2];
#pragma unroll
            for (int fm = 0; fm < 4; ++fm) {
                int row = wr * 64 + fm * 16 + (l & 15);
                int idx = frag_idx(row, ks, l);
                ah[fm] = *(const bf16x8*)&Ah_s[idx];
                al[fm] = *(const bf16x8*)&Al_s[idx];
            }
#pragma unroll
            for (int fn = 0; fn < 2; ++fn) {
                int row = wc * 32 + fn * 16 + (l & 15);
                int idx = frag_idx(row, ks, l);
                bh[fn] = *(const bf16x8*)&Bh_s[idx];
                bl[fn] = *(const bf16x8*)&Bl_s[idx];
            }
#pragma unroll
            for (int fm = 0; fm < 4; ++fm)
#pragma unroll
                for (int fn = 0; fn < 2; ++fn) {
                    acc[fm][fn] = __builtin_amdgcn_mfma_f32_16x16x32_bf16(ah[fm], bh[fn], acc[fm][fn], 0, 0, 0);
                    acc[fm][fn] = __builtin_amdgcn_mfma_f32_16x16x32_bf16(ah[fm], bl[fn], acc[fm][fn], 0, 0, 0);
                    acc[fm][fn] = __builtin_amdgcn_mfma_f32_16x16x32_bf16(al[fm], bh[fn], acc[fm][fn], 0, 0, 0);
                }
        }
        __syncthreads();
    }

#pragma unroll
    for (int fn = 0; fn < 2; ++fn) {
        int col = bn * 64 + wc * 32 + fn * 16 + (l & 15);
        float bi = bias[col];
#pragma unroll
        for (int fm = 0; fm < 4; ++fm) {
            int s0 = (row0 & 1023) + wr * 64 + fm * 16 + (l >> 4) * 4;
            float v0 = acc[fm][fn][0] + bi;
            float v1 = acc[fm][fn][1] + bi;
            float v2 = acc[fm][fn][2] + bi;
            float v3 = acc[fm][fn][3] + bi;
            ushort4 hv, lv;
            hv.x = bf16_hi(v0); lv.x = bf16_hi(v0 - bf16_tof(hv.x));
            hv.y = bf16_hi(v1); lv.y = bf16_hi(v1 - bf16_tof(hv.y));
            hv.z = bf16_hi(v2); lv.z = bf16_hi(v2 - bf16_tof(hv.z));
            hv.w = bf16_hi(v3); lv.w = bf16_hi(v3 - bf16_tof(hv.w));
            size_t off = ((size_t)(b * 256 + col)) * 1024 + s0;
            *(ushort4*)&h1t_h[off] = hv;
            *(ushort4*)&h1t_l[off] = lv;
        }
    }
}

// ---------------------------------------------------------------------------
// fp32 VALU gemm_nt (proj only) + mv + bf16 emit
// ---------------------------------------------------------------------------
#define BM 64
#define BN 64
#define BK 16
__global__ __launch_bounds__(256) void gemm_nt_kernel(
    const float* __restrict__ A, const float* __restrict__ B,
    float* __restrict__ C, int K, float alpha, const float* __restrict__ bias,
    const float* __restrict__ abar, float* __restrict__ mv,
    unsigned short* __restrict__ xh, unsigned short* __restrict__ xl)
{
    __shared__ float As[BK][BM + 4];
    __shared__ float Bs[BK][BN + 4];
    __shared__ float red[16][BN];
    const int tid = threadIdx.x;
    const int bm = blockIdx.x, bn = blockIdx.y;
    const int tx = tid & 15, ty = tid >> 4;
    const int lrow = tid >> 2;
    const int lk = (tid & 3) << 2;
    const float* Ag = A + (size_t)(bm * BM + lrow) * K + lk;
    const float* Bg = B + (size_t)(bn * BN + lrow) * K + lk;
    float acc[4][4] = {};

    for (int k0 = 0; k0 < K; k0 += BK) {
        float4 av = *(const float4*)(Ag + k0);
        float4 bv = *(const float4*)(Bg + k0);
        __syncthreads();
        As[lk + 0][lrow] = av.x; As[lk + 1][lrow] = av.y;
        As[lk + 2][lrow] = av.z; As[lk + 3][lrow] = av.w;
        Bs[lk + 0][lrow] = bv.x; Bs[lk + 1][lrow] = bv.y;
        Bs[lk + 2][lrow] = bv.z; Bs[lk + 3][lrow] = bv.w;
        __syncthreads();
#pragma unroll
        for (int kk = 0; kk < BK; ++kk) {
            const float4 a = *(const float4*)&As[kk][ty << 2];
            const float4 b = *(const float4*)&Bs[kk][tx << 2];
            float ar[4] = {a.x, a.y, a.z, a.w};
            float br[4] = {b.x, b.y, b.z, b.w};
#pragma unroll
            for (int i = 0; i < 4; ++i)
#pragma unroll
                for (int j = 0; j < 4; ++j)
                    acc[i][j] += ar[i] * br[j];
        }
    }
    const int row = bm * BM + (ty << 2);
    const int col = bn * BN + (tx << 2);
    const int b = row >> 10;
    float bi[4] = {bias[col], bias[col + 1], bias[col + 2], bias[col + 3]};
    float o[4][4];
#pragma unroll
    for (int i = 0; i < 4; ++i) {
        float4 ov;
        ov.x = o[i][0] = alpha * acc[i][0] + bi[0];
        ov.y = o[i][1] = alpha * acc[i][1] + bi[1];
        ov.z = o[i][2] = alpha * acc[i][2] + bi[2];
        ov.w = o[i][3] = alpha * acc[i][3] + bi[3];
        *(float4*)(C + (size_t)(row + i) * CDIM + col) = ov;
#pragma unroll
        for (int j = 0; j < 4; ++j) {
            size_t off = (size_t)(row + i) * CDIM + col + j;
            unsigned short h = bf16_hi(o[i][j]);
            xh[off] = h;
            xl[off] = bf16_hi(o[i][j] - bf16_tof(h));
        }
    }
    {
        float p[4];
#pragma unroll
        for (int j = 0; j < 4; ++j) {
            p[j] = 0.f;
#pragma unroll
            for (int i = 0; i < 4; ++i)
                p[j] += abar[((row + i) & 1023) + (b << 10)] * o[i][j];
            red[ty][(tx << 2) + j] = p[j];
        }
        __syncthreads();
        if (tid < BN) {
            float s = 0.f;
#pragma unroll
            for (int t = 0; t < 16; ++t) s += red[t][tid];
            atomicAdd(&mv[b * CDIM + bn * BN + tid], s);
        }
    }
}

// ---------------------------------------------------------------------------
// color: writes tanh'd color table (tanh hoisted out of the pixel gather)
// ---------------------------------------------------------------------------
__global__ __launch_bounds__(256) void color_kernel(
    const float* __restrict__ x, const float* __restrict__ rgb_w,
    const float* __restrict__ rgb_b, float* __restrict__ color, float sc_c)
{
    const int wave = threadIdx.x >> 6;
    const int lane = threadIdx.x & 63;
    const int r = blockIdx.x * 4 + wave;
    const float4 xv = *(const float4*)(x + (size_t)r * CDIM + lane * 4);
    float p[3];
#pragma unroll
    for (int cc = 0; cc < 3; ++cc) {
        const float4 wv = *(const float4*)(rgb_w + cc * CDIM + lane * 4);
        p[cc] = xv.x * wv.x + xv.y * wv.y + xv.z * wv.z + xv.w * wv.w;
    }
#pragma unroll
    for (int off = 32; off > 0; off >>= 1) {
#pragma unroll
        for (int cc = 0; cc < 3; ++cc) p[cc] += __shfl_down(p[cc], off);
    }
    if (lane == 0) {
#pragma unroll
        for (int cc = 0; cc < 3; ++cc)
            color[(size_t)r * 3 + cc] = tanhf(sc_c * p[cc] + rgb_b[cc]);
    }
}

// ---------------------------------------------------------------------------
// gather: 4 pixels/thread, float4 stores per plane; color already tanh'd
// grid: B*N_PIX/4/256 = 2048 blocks
// ---------------------------------------------------------------------------
__global__ __launch_bounds__(256) void gather_kernel(
    const int* __restrict__ seg, const float* __restrict__ color,
    float* __restrict__ out)
{
    int idx = blockIdx.x * 256 + threadIdx.x;   // over B * N_PIX/4
    int b = idx >> 16;                          // N_PIX/4 = 65536
    int p4 = idx & 65535;
    int4 s = ((const int4*)(seg + (size_t)b * N_PIX))[p4];
    const float* cb = color + (size_t)b * S_SEG * 3;
    float4 o0, o1, o2;
    o0.x = cb[s.x * 3 + 0]; o1.x = cb[s.x * 3 + 1]; o2.x = cb[s.x * 3 + 2];
    o0.y = cb[s.y * 3 + 0]; o1.y = cb[s.y * 3 + 1]; o2.y = cb[s.y * 3 + 2];
    o0.z = cb[s.z * 3 + 0]; o1.z = cb[s.z * 3 + 1]; o2.z = cb[s.z * 3 + 2];
    o0.w = cb[s.w * 3 + 0]; o1.w = cb[s.w * 3 + 1]; o2.w = cb[s.w * 3 + 2];
    ((float4*)(out + ((size_t)b * 3 + 0) * N_PIX))[p4] = o0;
    ((float4*)(out + ((size_t)b * 3 + 1) * N_PIX))[p4] = o1;
    ((float4*)(out + ((size_t)b * 3 + 2) * N_PIX))[p4] = o2;
}

// ---------------------------------------------------------------------------
extern "C" void kernel_launch(void* const* d_in, const int* in_sizes, int n_in,
                              void* d_out, int out_size, void* d_ws, size_t ws_size,
                              hipStream_t stream)
{
    (void)in_sizes; (void)n_in; (void)out_size; (void)ws_size;
    const float* z      = (const float*)d_in[0];
    const float* images = (const float*)d_in[1];
    const int*   seg    = (const int*)d_in[2];
    const float* A      = (const float*)d_in[3];
    const float* proj_w = (const float*)d_in[4];
    const float* proj_b = (const float*)d_in[5];
    const float* blk_w  = (const float*)d_in[6];
    const float* blk_b  = (const float*)d_in[7];
    const float* ada_w1 = (const float*)d_in[8];
    const float* ada_b1 = (const float*)d_in[9];
    const float* ada_w2 = (const float*)d_in[10];
    const float* ada_b2 = (const float*)d_in[11];
    const float* rgb_w  = (const float*)d_in[12];
    const float* rgb_b  = (const float*)d_in[13];
    float* out = (float*)d_out;

    float* ws = (float*)d_ws;
    float* sums    = ws;                  // 24576
    float* counts  = ws + 24576;          // 8192
    float* sumabar = ws + 32768;          // 16
    float* mv      = ws + 32784;          // 18432
    float* abar    = ws + 51216;          // 8192
    float* style   = ws + 59408;          // 4096
    float* colr    = ws + 63504;          // 24576
    float* wpad    = ws + 88080;          // 36864
    float* xin     = ws + 124944;         // 1179648 -> ends 1304592
    float* x       = ws + 1304592;        // 2097152 -> ends 3401744
    unsigned short* xh    = (unsigned short*)(ws + 3401744);
    unsigned short* xl    = (unsigned short*)(ws + 4450320);
    unsigned short* h1t_h = (unsigned short*)(ws + 5498896);
    unsigned short* h1t_l = (unsigned short*)(ws + 6547472);
    unsigned short* Ah    = (unsigned short*)(ws + 7596048);
    unsigned short* Al    = (unsigned short*)(ws + 11790352);
    unsigned short* Wh    = (unsigned short*)(ws + 15984656);
    unsigned short* Wl    = (unsigned short*)(ws + 16246800);

    const float sc_in = (float)sqrt(2.0 / 131.0);
    const float sc_c  = (float)sqrt(2.0 / 256.0);
    const float sc_2c = (float)sqrt(2.0 / 512.0);

    hipMemsetAsync(sums, 0, 59408 * sizeof(float), stream);  // thru abar
    seg_pool_kernel<<<dim3(BATCH * 32), 1024, 0, stream>>>(images, seg, sums, counts);
    conv_split_abar_kernel<<<dim3(256), 256, 0, stream>>>(A, Ah, Al, abar, sumabar);
    prep_xin_kernel<<<dim3((8192 * 144) / 256), 256, 0, stream>>>(sums, counts, z, xin);
    prep_wpad_kernel<<<dim3((256 * 144) / 256), 256, 0, stream>>>(proj_w, wpad);
    conv_split_kernel<<<dim3(512), 256, 0, stream>>>(blk_w, Wh, Wl, sc_c, 131072u);

    gemm_nt_kernel<<<dim3(128, 4), 256, 0, stream>>>(xin, wpad, x, 144, sc_in, proj_b,
                                                     abar, mv, xh, xl);

    for (int i = 0; i < 8; ++i) {
        gemm_nt_mfma_kernel<<<dim3(64, 5), 256, 0, stream>>>(
            xh, xl, Wh + (size_t)i * 65536, Wl + (size_t)i * 65536,
            blk_b + i * CDIM, h1t_h, h1t_l,
            mv + i * 2048, sumabar, blk_w + (size_t)i * CDIM * CDIM,
            ada_w1 + (size_t)i * 512 * 256, ada_b1 + i * 512,
            ada_w2 + (size_t)i * 512 * 512, ada_b2 + i * 512,
            style, sc_c, sc_2c);
        const bool last = (i == 7);
        gemm_nn_mfma_kernel<<<dim3(8, 4, 8), 256, 0, stream>>>(
            Ah, Al, h1t_h, h1t_l, style, abar,
            last ? x : nullptr,
            last ? nullptr : xh, last ? nullptr : xl,
            last ? nullptr : (mv + (i + 1) * 2048));
    }

    color_kernel<<<dim3(2048), 256, 0, stream>>>(x, rgb_w, rgb_b, colr, sc_c);
    gather_kernel<<<dim3(2048), 256, 0, stream>>>(seg, colr, out);
}

// Round 9
// 557.313 us; speedup vs baseline: 4.0285x; 1.2015x over previous
//
#include <hip/hip_runtime.h>
#include <math.h>

#define N_PIX (512*512)
#define S_SEG 1024
#define CDIM  256
#define BATCH 8

typedef __attribute__((ext_vector_type(4))) float f32x4;
typedef __attribute__((ext_vector_type(8))) short bf16x8;
typedef __fp16 half2v __attribute__((ext_vector_type(2)));
typedef __attribute__((address_space(3))) unsigned int lds_uint;

__device__ __forceinline__ float lrelu(float v) { return v > 0.f ? v : 0.2f * v; }

__device__ __forceinline__ unsigned short bf16_hi(float x) {
    union { float f; unsigned int u; } v; v.f = x;
    unsigned int r = v.u + 0x7FFFu + ((v.u >> 16) & 1u);
    return (unsigned short)(r >> 16);
}
__device__ __forceinline__ float bf16_tof(unsigned short h) {
    union { float f; unsigned int u; } v; v.u = ((unsigned int)h) << 16;
    return v.f;
}
__device__ __forceinline__ float dot4(float4 a, float4 b) {
    return a.x * b.x + a.y * b.y + a.z * b.z + a.w * b.w;
}
__device__ __forceinline__ unsigned pack_h2(float lo, float hi) {
    union { half2v h; unsigned u; } c;
    c.h = __builtin_amdgcn_cvt_pkrtz(lo, hi);
    return c.u;
}
__device__ __forceinline__ void ds_pk_add(lds_uint* p, unsigned val) {
    asm volatile("ds_pk_add_f16 %0, %1"
                 :: "v"((unsigned)(unsigned long)p), "v"(val) : "memory");
}

// ---------------------------------------------------------------------------
// Segment pooling: LDS packed-fp16 atomics (2 per pixel instead of 4).
// bins2[s*2+0] += (r,g) as half2; bins2[s*2+1] += (b,1.0) as half2.
// LDS atomics retire ~1 lane/cycle/CU -> op count is the wall; this halves it.
// ---------------------------------------------------------------------------
__global__ __launch_bounds__(1024) void seg_pool_kernel(
    const float* __restrict__ images, const int* __restrict__ seg,
    float* __restrict__ sums, float* __restrict__ counts)
{
    __shared__ unsigned int bins2[S_SEG * 2];
    const int b = blockIdx.x >> 5;
    const int chunk = blockIdx.x & 31;
    const int t = threadIdx.x;
    for (int i = t; i < S_SEG * 2; i += 1024) bins2[i] = 0u;
    __syncthreads();

    lds_uint* bl2 = (lds_uint*)bins2;
    const float4* imr = (const float4*)(images + (size_t)b * 3 * N_PIX);
    const float4* img = imr + N_PIX / 4;
    const float4* imb = img + N_PIX / 4;
    const int4* sg4 = (const int4*)(seg + (size_t)b * N_PIX);
    const int base4 = chunk * (N_PIX / 32 / 4);  // 2048 float4 per chunk

#pragma unroll
    for (int it = 0; it < 2; ++it) {
        int p4 = base4 + it * 1024 + t;
        int4 s = sg4[p4];
        float4 r = imr[p4];
        float4 g = img[p4];
        float4 bb = imb[p4];
        ds_pk_add(bl2 + s.x * 2 + 0, pack_h2(r.x, g.x));
        ds_pk_add(bl2 + s.x * 2 + 1, pack_h2(bb.x, 1.f));
        ds_pk_add(bl2 + s.y * 2 + 0, pack_h2(r.y, g.y));
        ds_pk_add(bl2 + s.y * 2 + 1, pack_h2(bb.y, 1.f));
        ds_pk_add(bl2 + s.z * 2 + 0, pack_h2(r.z, g.z));
        ds_pk_add(bl2 + s.z * 2 + 1, pack_h2(bb.z, 1.f));
        ds_pk_add(bl2 + s.w * 2 + 0, pack_h2(r.w, g.w));
        ds_pk_add(bl2 + s.w * 2 + 1, pack_h2(bb.w, 1.f));
    }
    __syncthreads();
    if (t < S_SEG) {
        union { unsigned u; __fp16 h[2]; } p0, p1;
        p0.u = bins2[t * 2 + 0];
        p1.u = bins2[t * 2 + 1];
        float cnt = (float)p1.h[1];
        if (cnt != 0.f) {
            atomicAdd(&sums[((size_t)b * S_SEG + t) * 3 + 0], (float)p0.h[0]);
            atomicAdd(&sums[((size_t)b * S_SEG + t) * 3 + 1], (float)p0.h[1]);
            atomicAdd(&sums[((size_t)b * S_SEG + t) * 3 + 2], (float)p1.h[0]);
            atomicAdd(&counts[(size_t)b * S_SEG + t], cnt);
        }
    }
}

// ---------------------------------------------------------------------------
// FUSED: A -> (Ah, Al) bf16 split + abar (column means) + sumabar.
// ---------------------------------------------------------------------------
__global__ __launch_bounds__(256) void conv_split_abar_kernel(
    const float* __restrict__ A, unsigned short* __restrict__ Ah,
    unsigned short* __restrict__ Al, float* __restrict__ abar,
    float* __restrict__ sumabar)
{
    const int b = blockIdx.x >> 5;
    const int chunk = blockIdx.x & 31;
    const int t = threadIdx.x;
    const size_t base4 = ((size_t)b * 1024 * 1024 + (size_t)chunk * 32 * 1024) >> 2;
    const float4* Af = ((const float4*)A) + base4;
    ushort4* Ahf = ((ushort4*)Ah) + base4;
    ushort4* Alf = ((ushort4*)Al) + base4;
    float a0 = 0.f, a1 = 0.f, a2 = 0.f, a3 = 0.f;
#pragma unroll 4
    for (int r = 0; r < 32; ++r) {
        float4 v = Af[r * 256 + t];
        ushort4 h, l;
        h.x = bf16_hi(v.x); l.x = bf16_hi(v.x - bf16_tof(h.x));
        h.y = bf16_hi(v.y); l.y = bf16_hi(v.y - bf16_tof(h.y));
        h.z = bf16_hi(v.z); l.z = bf16_hi(v.z - bf16_tof(h.z));
        h.w = bf16_hi(v.w); l.w = bf16_hi(v.w - bf16_tof(h.w));
        Ahf[r * 256 + t] = h;
        Alf[r * 256 + t] = l;
        a0 += v.x; a1 += v.y; a2 += v.z; a3 += v.w;
    }
    const float inv = 1.f / 1024.f;
    atomicAdd(&abar[b * 1024 + t * 4 + 0], a0 * inv);
    atomicAdd(&abar[b * 1024 + t * 4 + 1], a1 * inv);
    atomicAdd(&abar[b * 1024 + t * 4 + 2], a2 * inv);
    atomicAdd(&abar[b * 1024 + t * 4 + 3], a3 * inv);
    __shared__ float red[256];
    red[t] = (a0 + a1 + a2 + a3) * inv;
    __syncthreads();
    for (int off = 128; off > 0; off >>= 1) {
        if (t < off) red[t] += red[t + off];
        __syncthreads();
    }
    if (t == 0) atomicAdd(&sumabar[b], red[0]);
}

__global__ __launch_bounds__(256) void prep_xin_kernel(
    const float* __restrict__ sums, const float* __restrict__ counts,
    const float* __restrict__ z, float* __restrict__ xin)
{
    int idx = blockIdx.x * 256 + threadIdx.x;
    int r = idx / 144, c = idx % 144;
    int b = r >> 10;
    float v;
    if (c < 3)        v = sums[r * 3 + c] / (counts[r] + 1e-6f);
    else if (c < 131) v = z[b * 128 + (c - 3)];
    else              v = 0.f;
    xin[idx] = v;
}

__global__ __launch_bounds__(256) void prep_wpad_kernel(
    const float* __restrict__ proj_w, float* __restrict__ wpad)
{
    int idx = blockIdx.x * 256 + threadIdx.x;
    int n = idx / 144, k = idx % 144;
    wpad[idx] = (k < 131) ? proj_w[n * 131 + k] : 0.f;
}

// ---------------------------------------------------------------------------
// fp32 -> (bf16 hi, bf16 lo) split with scale (weights only)
// ---------------------------------------------------------------------------
__global__ __launch_bounds__(256) void conv_split_kernel(
    const float* __restrict__ in, unsigned short* __restrict__ hi,
    unsigned short* __restrict__ lo, float scale, unsigned int n4)
{
    unsigned int idx = blockIdx.x * 256 + threadIdx.x;
    if (idx >= n4) return;
    float4 v = ((const float4*)in)[idx];
    ushort4 h, l;
    float a;
    a = v.x * scale; h.x = bf16_hi(a); l.x = bf16_hi(a - bf16_tof(h.x));
    a = v.y * scale; h.y = bf16_hi(a); l.y = bf16_hi(a - bf16_tof(h.y));
    a = v.z * scale; h.z = bf16_hi(a); l.z = bf16_hi(a - bf16_tof(h.z));
    a = v.w * scale; h.w = bf16_hi(a); l.w = bf16_hi(a - bf16_tof(h.w));
    ((ushort4*)hi)[idx] = h;
    ((ushort4*)lo)[idx] = l;
}

// ---------------------------------------------------------------------------
// staging helpers (rule #21 both-sides swizzle); T = block thread count
// ---------------------------------------------------------------------------
__device__ __forceinline__ void stage_tile(
    const unsigned short* __restrict__ g, int grow,
    unsigned short* lds, int tid, int nissue, int T)
{
    for (int i = 0; i < nissue; ++i) {
        int c = i * T + tid;
        int row = c >> 3, cin = c & 7;
        int cs = cin ^ (row & 7);
        const unsigned short* src = g + (size_t)row * grow + cs * 8;
        unsigned short* dst = lds + (size_t)(i * T + (tid & ~63)) * 8;
        __builtin_amdgcn_global_load_lds(
            (const __attribute__((address_space(1))) unsigned int*)src,
            (__attribute__((address_space(3))) unsigned int*)dst, 16, 0, 0);
    }
}

__device__ __forceinline__ int frag_idx(int row, int ks, int l)
{
    int chunk = (ks * 4 + (l >> 4)) ^ (row & 7);
    return row * 64 + chunk * 8;
}

// ---------------------------------------------------------------------------
// MFMA split-3 GEMM: x_out = lrelu(gamma*(A @ h1) + beta) + optional outputs.
// 512 threads / 8 waves (2 waves/SIMD for stall covering), wave-tile 64x16.
// ---------------------------------------------------------------------------
__global__ __launch_bounds__(512) void gemm_nn_mfma_kernel(
    const unsigned short* __restrict__ Ah_g, const unsigned short* __restrict__ Al_g,
    const unsigned short* __restrict__ Hh_g, const unsigned short* __restrict__ Hl_g,
    const float* __restrict__ style, const float* __restrict__ abar,
    float* __restrict__ x, unsigned short* __restrict__ xh,
    unsigned short* __restrict__ xl, float* __restrict__ mv)
{
    __shared__ __align__(16) unsigned short Ah_s[128 * 64];
    __shared__ __align__(16) unsigned short Al_s[128 * 64];
    __shared__ __align__(16) unsigned short Bh_s[64 * 64];
    __shared__ __align__(16) unsigned short Bl_s[64 * 64];
    __shared__ float mvred[64];
    const int tid = threadIdx.x;
    const int b = blockIdx.z, bm = blockIdx.x, bn = blockIdx.y;
    const int l = tid & 63, wave = tid >> 6;
    const int wr = wave >> 2, wc = wave & 3;   // 2 x 4 waves, tile 64x16
    if (mv && tid < 64) mvred[tid] = 0.f;

    const unsigned short* Ag_h = Ah_g + ((size_t)(b * 1024 + bm * 128)) * 1024;
    const unsigned short* Ag_l = Al_g + ((size_t)(b * 1024 + bm * 128)) * 1024;
    const unsigned short* Hg_h = Hh_g + ((size_t)(b * 256 + bn * 64)) * 1024;
    const unsigned short* Hg_l = Hl_g + ((size_t)(b * 256 + bn * 64)) * 1024;

    f32x4 acc[4];
#pragma unroll
    for (int i = 0; i < 4; ++i) acc[i] = (f32x4){0.f, 0.f, 0.f, 0.f};

    for (int kt = 0; kt < 16; ++kt) {
        stage_tile(Ag_h + kt * 64, 1024, Ah_s, tid, 2, 512);
        stage_tile(Ag_l + kt * 64, 1024, Al_s, tid, 2, 512);
        stage_tile(Hg_h + kt * 64, 1024, Bh_s, tid, 1, 512);
        stage_tile(Hg_l + kt * 64, 1024, Bl_s, tid, 1, 512);
        __syncthreads();
#pragma unroll
        for (int ks = 0; ks < 2; ++ks) {
            bf16x8 ah[4], al[4], bh, bl;
#pragma unroll
            for (int fm = 0; fm < 4; ++fm) {
                int row = wr * 64 + fm * 16 + (l & 15);
                int idx = frag_idx(row, ks, l);
                ah[fm] = *(const bf16x8*)&Ah_s[idx];
                al[fm] = *(const bf16x8*)&Al_s[idx];
            }
            {
                int row = wc * 16 + (l & 15);
                int idx = frag_idx(row, ks, l);
                bh = *(const bf16x8*)&Bh_s[idx];
                bl = *(const bf16x8*)&Bl_s[idx];
            }
#pragma unroll
            for (int fm = 0; fm < 4; ++fm) {
                acc[fm] = __builtin_amdgcn_mfma_f32_16x16x32_bf16(ah[fm], bh, acc[fm], 0, 0, 0);
                acc[fm] = __builtin_amdgcn_mfma_f32_16x16x32_bf16(ah[fm], bl, acc[fm], 0, 0, 0);
                acc[fm] = __builtin_amdgcn_mfma_f32_16x16x32_bf16(al[fm], bh, acc[fm], 0, 0, 0);
            }
        }
        __syncthreads();
    }

    const float* st = style + b * 2 * CDIM;
    {
        int col = bn * 64 + wc * 16 + (l & 15);
        float ga = st[col], be = st[CDIM + col];
        float pmv = 0.f;
#pragma unroll
        for (int fm = 0; fm < 4; ++fm) {
            int m0 = bm * 128 + wr * 64 + fm * 16 + (l >> 4) * 4;
#pragma unroll
            for (int r = 0; r < 4; ++r) {
                float v = lrelu(ga * acc[fm][r] + be);
                size_t off = ((size_t)(b * 1024 + m0 + r)) * 256 + col;
                if (x) x[off] = v;
                if (xh) {
                    unsigned short h = bf16_hi(v);
                    xh[off] = h;
                    xl[off] = bf16_hi(v - bf16_tof(h));
                }
                pmv += abar[b * 1024 + m0 + r] * v;
            }
        }
        if (mv) atomicAdd(&mvred[wc * 16 + (l & 15)], pmv);
    }
    if (mv) {
        __syncthreads();
        if (tid < 64) atomicAdd(&mv[b * 256 + bn * 64 + tid], mvred[tid]);
    }
}

// ---------------------------------------------------------------------------
// MFMA split-3 GEMM (h1 = x @ W'^T + b, transposed bf16 output), 512 thr /
// 8 waves, PLUS the per-batch style MLP at blockIdx.y == 4 (wave-per-output).
// ---------------------------------------------------------------------------
__global__ __launch_bounds__(512) void gemm_nt_mfma_kernel(
    const unsigned short* __restrict__ xh_g, const unsigned short* __restrict__ xl_g,
    const unsigned short* __restrict__ Wh, const unsigned short* __restrict__ Wl,
    const float* __restrict__ bias,
    unsigned short* __restrict__ h1t_h, unsigned short* __restrict__ h1t_l,
    const float* __restrict__ mv, const float* __restrict__ sumabar,
    const float* __restrict__ Wblk_f,
    const float* __restrict__ W1, const float* __restrict__ b1,
    const float* __restrict__ W2, const float* __restrict__ b2,
    float* __restrict__ style, float sc_c, float sc_2c)
{
    __shared__ __align__(16) unsigned short Ah_s[128 * 64];
    __shared__ __align__(16) unsigned short Al_s[128 * 64];
    __shared__ __align__(16) unsigned short Bh_s[64 * 64];
    __shared__ __align__(16) unsigned short Bl_s[64 * 64];
    const int tid = threadIdx.x;
    const int bm = blockIdx.x, bn = blockIdx.y;

    if (bn == 4) {
        // ---- style MLP: block bm = batch*4 + quarter (bm < 32) ----
        if (bm >= BATCH * 4) return;
        const int bb = bm >> 2;
        const int q = bm & 3;
        const int w = tid >> 6, lane = tid & 63;
        float* m_s = (float*)Ah_s;          // 256 floats (alias GEMM LDS)
        float* s1_s = (float*)Bh_s;         // 512 floats

        const float4 mvreg = *(const float4*)&mv[bb * 256 + lane * 4];
        const float sab = sumabar[bb];

        // Layer A: 256 outputs over 8 waves; 4 groups of 8
        for (int g = 0; g < 4; ++g) {
            const int o0 = w * 32 + g * 8;
            float p[8];
#pragma unroll
            for (int j = 0; j < 8; ++j) {
                const float4 wv = *(const float4*)&Wblk_f[(size_t)(o0 + j) * 256 + lane * 4];
                p[j] = dot4(wv, mvreg);
            }
#pragma unroll
            for (int off = 32; off > 0; off >>= 1)
#pragma unroll
                for (int j = 0; j < 8; ++j) p[j] += __shfl_xor(p[j], off);
            if (lane == 0)
#pragma unroll
                for (int j = 0; j < 8; ++j)
                    m_s[o0 + j] = sc_c * p[j] + sab * bias[o0 + j];
        }
        __syncthreads();
        const float4 mreg = *(const float4*)&m_s[lane * 4];

        // Layer B: 512 outputs over 8 waves; 8 groups of 8
        for (int g = 0; g < 8; ++g) {
            const int o0 = w * 64 + g * 8;
            float p[8];
#pragma unroll
            for (int j = 0; j < 8; ++j) {
                const float4 wv = *(const float4*)&W1[(size_t)(o0 + j) * 256 + lane * 4];
                p[j] = dot4(wv, mreg);
            }
#pragma unroll
            for (int off = 32; off > 0; off >>= 1)
#pragma unroll
                for (int j = 0; j < 8; ++j) p[j] += __shfl_xor(p[j], off);
            if (lane == 0)
#pragma unroll
                for (int j = 0; j < 8; ++j)
                    s1_s[o0 + j] = lrelu(sc_c * p[j] + b1[o0 + j]);
        }
        __syncthreads();
        const float4 sa = *(const float4*)&s1_s[lane * 4];
        const float4 sb = *(const float4*)&s1_s[256 + lane * 4];

        // Layer C: quarter (128 outputs) over 8 waves; 2 groups of 8
        for (int g = 0; g < 2; ++g) {
            const int o0 = q * 128 + w * 16 + g * 8;
            float p[8];
#pragma unroll
            for (int j = 0; j < 8; ++j) {
                const float4 wa = *(const float4*)&W2[(size_t)(o0 + j) * 512 + lane * 4];
                const float4 wb = *(const float4*)&W2[(size_t)(o0 + j) * 512 + 256 + lane * 4];
                p[j] = dot4(wa, sa) + dot4(wb, sb);
            }
#pragma unroll
            for (int off = 32; off > 0; off >>= 1)
#pragma unroll
                for (int j = 0; j < 8; ++j) p[j] += __shfl_xor(p[j], off);
            if (lane == 0)
#pragma unroll
                for (int j = 0; j < 8; ++j)
                    style[bb * 512 + o0 + j] = sc_2c * p[j] + b2[o0 + j];
        }
        return;
    }

    // ---- GEMM path (8 waves, wave-tile 64x16) ----
    const int l = tid & 63, wave = tid >> 6;
    const int wr = wave >> 2, wc = wave & 3;
    const int row0 = bm * 128;
    const int b = row0 >> 10;

    const unsigned short* Ag_h = xh_g + (size_t)row0 * 256;
    const unsigned short* Ag_l = xl_g + (size_t)row0 * 256;
    const unsigned short* Bg_h = Wh + (size_t)(bn * 64) * 256;
    const unsigned short* Bg_l = Wl + (size_t)(bn * 64) * 256;

    f32x4 acc[4];
#pragma unroll
    for (int i = 0; i < 4; ++i) acc[i] = (f32x4){0.f, 0.f, 0.f, 0.f};

    for (int kt = 0; kt < 4; ++kt) {
        stage_tile(Ag_h + kt * 64, 256, Ah_s, tid, 2, 512);
        stage_tile(Ag_l + kt * 64, 256, Al_s, tid, 2, 512);
        stage_tile(Bg_h + kt * 64, 256, Bh_s, tid, 1, 512);
        stage_tile(Bg_l + kt * 64, 256, Bl_s, tid, 1, 512);
        __syncthreads();
#pragma unroll
        for (int ks = 0; ks < 2; ++ks) {
            bf16x8 ah[4], al[4], bh, bl;
#pragma unroll
            for (int fm = 0; fm < 4; ++fm) {
                int row = wr * 64 + fm * 16 + (l & 15);
                int idx = frag_idx(row, ks, l);
                ah[fm] = *(const bf16x8*)&Ah_s[idx];
                al[fm] = *(const bf16x8*)&Al_s[idx];
            }
            {
                int row = wc * 16 + (l & 15);
                int idx = frag_idx(row, ks, l);
                bh = *(const bf16x8*)&Bh_s[idx];
                bl = *(const bf16x8*)&Bl_s[idx];
            }
#pragma unroll
            for (int fm = 0; fm < 4; ++fm) {
                acc[fm] = __builtin_amdgcn_mfma_f32_16x16x32_bf16(ah[fm], bh, acc[fm], 0, 0, 0);
                acc[fm] = __builtin_amdgcn_mfma_f32_16x16x32_bf16(ah[fm], bl, acc[fm], 0, 0, 0);
                acc[fm] = __builtin_amdgcn_mfma_f32_16x16x32_bf16(al[fm], bh, acc[fm], 0, 0, 0);
            }
        }
        __syncthreads();
    }

    {
        int col = bn * 64 + wc * 16 + (l & 15);
        float bi = bias[col];
#pragma unroll
        for (int fm = 0; fm < 4; ++fm) {
            int s0 = (row0 & 1023) + wr * 64 + fm * 16 + (l >> 4) * 4;
            float v0 = acc[fm][0] + bi;
            float v1 = acc[fm][1] + bi;
            float v2 = acc[fm][2] + bi;
            float v3 = acc[fm][3] + bi;
            ushort4 hv, lv;
            hv.x = bf16_hi(v0); lv.x = bf16_hi(v0 - bf16_tof(hv.x));
            hv.y = bf16_hi(v1); lv.y = bf16_hi(v1 - bf16_tof(hv.y));
            hv.z = bf16_hi(v2); lv.z = bf16_hi(v2 - bf16_tof(hv.z));
            hv.w = bf16_hi(v3); lv.w = bf16_hi(v3 - bf16_tof(hv.w));
            size_t off = ((size_t)(b * 256 + col)) * 1024 + s0;
            *(ushort4*)&h1t_h[off] = hv;
            *(ushort4*)&h1t_l[off] = lv;
        }
    }
}

// ---------------------------------------------------------------------------
// fp32 VALU gemm_nt (proj only) + mv + bf16 emit
// ---------------------------------------------------------------------------
#define BM 64
#define BN 64
#define BK 16
__global__ __launch_bounds__(256) void gemm_nt_kernel(
    const float* __restrict__ A, const float* __restrict__ B,
    float* __restrict__ C, int K, float alpha, const float* __restrict__ bias,
    const float* __restrict__ abar, float* __restrict__ mv,
    unsigned short* __restrict__ xh, unsigned short* __restrict__ xl)
{
    __shared__ float As[BK][BM + 4];
    __shared__ float Bs[BK][BN + 4];
    __shared__ float red[16][BN];
    const int tid = threadIdx.x;
    const int bm = blockIdx.x, bn = blockIdx.y;
    const int tx = tid & 15, ty = tid >> 4;
    const int lrow = tid >> 2;
    const int lk = (tid & 3) << 2;
    const float* Ag = A + (size_t)(bm * BM + lrow) * K + lk;
    const float* Bg = B + (size_t)(bn * BN + lrow) * K + lk;
    float acc[4][4] = {};

    for (int k0 = 0; k0 < K; k0 += BK) {
        float4 av = *(const float4*)(Ag + k0);
        float4 bv = *(const float4*)(Bg + k0);
        __syncthreads();
        As[lk + 0][lrow] = av.x; As[lk + 1][lrow] = av.y;
        As[lk + 2][lrow] = av.z; As[lk + 3][lrow] = av.w;
        Bs[lk + 0][lrow] = bv.x; Bs[lk + 1][lrow] = bv.y;
        Bs[lk + 2][lrow] = bv.z; Bs[lk + 3][lrow] = bv.w;
        __syncthreads();
#pragma unroll
        for (int kk = 0; kk < BK; ++kk) {
            const float4 a = *(const float4*)&As[kk][ty << 2];
            const float4 b = *(const float4*)&Bs[kk][tx << 2];
            float ar[4] = {a.x, a.y, a.z, a.w};
            float br[4] = {b.x, b.y, b.z, b.w};
#pragma unroll
            for (int i = 0; i < 4; ++i)
#pragma unroll
                for (int j = 0; j < 4; ++j)
                    acc[i][j] += ar[i] * br[j];
        }
    }
    const int row = bm * BM + (ty << 2);
    const int col = bn * BN + (tx << 2);
    const int b = row >> 10;
    float bi[4] = {bias[col], bias[col + 1], bias[col + 2], bias[col + 3]};
    float o[4][4];
#pragma unroll
    for (int i = 0; i < 4; ++i) {
        float4 ov;
        ov.x = o[i][0] = alpha * acc[i][0] + bi[0];
        ov.y = o[i][1] = alpha * acc[i][1] + bi[1];
        ov.z = o[i][2] = alpha * acc[i][2] + bi[2];
        ov.w = o[i][3] = alpha * acc[i][3] + bi[3];
        *(float4*)(C + (size_t)(row + i) * CDIM + col) = ov;
#pragma unroll
        for (int j = 0; j < 4; ++j) {
            size_t off = (size_t)(row + i) * CDIM + col + j;
            unsigned short h = bf16_hi(o[i][j]);
            xh[off] = h;
            xl[off] = bf16_hi(o[i][j] - bf16_tof(h));
        }
    }
    {
        float p[4];
#pragma unroll
        for (int j = 0; j < 4; ++j) {
            p[j] = 0.f;
#pragma unroll
            for (int i = 0; i < 4; ++i)
                p[j] += abar[((row + i) & 1023) + (b << 10)] * o[i][j];
            red[ty][(tx << 2) + j] = p[j];
        }
        __syncthreads();
        if (tid < BN) {
            float s = 0.f;
#pragma unroll
            for (int t = 0; t < 16; ++t) s += red[t][tid];
            atomicAdd(&mv[b * CDIM + bn * BN + tid], s);
        }
    }
}

// ---------------------------------------------------------------------------
// color: writes tanh'd color table (tanh hoisted out of the pixel gather)
// ---------------------------------------------------------------------------
__global__ __launch_bounds__(256) void color_kernel(
    const float* __restrict__ x, const float* __restrict__ rgb_w,
    const float* __restrict__ rgb_b, float* __restrict__ color, float sc_c)
{
    const int wave = threadIdx.x >> 6;
    const int lane = threadIdx.x & 63;
    const int r = blockIdx.x * 4 + wave;
    const float4 xv = *(const float4*)(x + (size_t)r * CDIM + lane * 4);
    float p[3];
#pragma unroll
    for (int cc = 0; cc < 3; ++cc) {
        const float4 wv = *(const float4*)(rgb_w + cc * CDIM + lane * 4);
        p[cc] = xv.x * wv.x + xv.y * wv.y + xv.z * wv.z + xv.w * wv.w;
    }
#pragma unroll
    for (int off = 32; off > 0; off >>= 1) {
#pragma unroll
        for (int cc = 0; cc < 3; ++cc) p[cc] += __shfl_down(p[cc], off);
    }
    if (lane == 0) {
#pragma unroll
        for (int cc = 0; cc < 3; ++cc)
            color[(size_t)r * 3 + cc] = tanhf(sc_c * p[cc] + rgb_b[cc]);
    }
}

// ---------------------------------------------------------------------------
// gather: 4 pixels/thread, float4 stores per plane; color already tanh'd
// ---------------------------------------------------------------------------
__global__ __launch_bounds__(256) void gather_kernel(
    const int* __restrict__ seg, const float* __restrict__ color,
    float* __restrict__ out)
{
    int idx = blockIdx.x * 256 + threadIdx.x;   // over B * N_PIX/4
    int b = idx >> 16;                          // N_PIX/4 = 65536
    int p4 = idx & 65535;
    int4 s = ((const int4*)(seg + (size_t)b * N_PIX))[p4];
    const float* cb = color + (size_t)b * S_SEG * 3;
    float4 o0, o1, o2;
    o0.x = cb[s.x * 3 + 0]; o1.x = cb[s.x * 3 + 1]; o2.x = cb[s.x * 3 + 2];
    o0.y = cb[s.y * 3 + 0]; o1.y = cb[s.y * 3 + 1]; o2.y = cb[s.y * 3 + 2];
    o0.z = cb[s.z * 3 + 0]; o1.z = cb[s.z * 3 + 1]; o2.z = cb[s.z * 3 + 2];
    o0.w = cb[s.w * 3 + 0]; o1.w = cb[s.w * 3 + 1]; o2.w = cb[s.w * 3 + 2];
    ((float4*)(out + ((size_t)b * 3 + 0) * N_PIX))[p4] = o0;
    ((float4*)(out + ((size_t)b * 3 + 1) * N_PIX))[p4] = o1;
    ((float4*)(out + ((size_t)b * 3 + 2) * N_PIX))[p4] = o2;
}

// ---------------------------------------------------------------------------
extern "C" void kernel_launch(void* const* d_in, const int* in_sizes, int n_in,
                              void* d_out, int out_size, void* d_ws, size_t ws_size,
                              hipStream_t stream)
{
    (void)in_sizes; (void)n_in; (void)out_size; (void)ws_size;
    const float* z      = (const float*)d_in[0];
    const float* images = (const float*)d_in[1];
    const int*   seg    = (const int*)d_in[2];
    const float* A      = (const float*)d_in[3];
    const float* proj_w = (const float*)d_in[4];
    const float* proj_b = (const float*)d_in[5];
    const float* blk_w  = (const float*)d_in[6];
    const float* blk_b  = (const float*)d_in[7];
    const float* ada_w1 = (const float*)d_in[8];
    const float* ada_b1 = (const float*)d_in[9];
    const float* ada_w2 = (const float*)d_in[10];
    const float* ada_b2 = (const float*)d_in[11];
    const float* rgb_w  = (const float*)d_in[12];
    const float* rgb_b  = (const float*)d_in[13];
    float* out = (float*)d_out;

    float* ws = (float*)d_ws;
    float* sums    = ws;                  // 24576
    float* counts  = ws + 24576;          // 8192
    float* sumabar = ws + 32768;          // 16
    float* mv      = ws + 32784;          // 18432
    float* abar    = ws + 51216;          // 8192
    float* style   = ws + 59408;          // 4096
    float* colr    = ws + 63504;          // 24576
    float* wpad    = ws + 88080;          // 36864
    float* xin     = ws + 124944;         // 1179648 -> ends 1304592
    float* x       = ws + 1304592;        // 2097152 -> ends 3401744
    unsigned short* xh    = (unsigned short*)(ws + 3401744);
    unsigned short* xl    = (unsigned short*)(ws + 4450320);
    unsigned short* h1t_h = (unsigned short*)(ws + 5498896);
    unsigned short* h1t_l = (unsigned short*)(ws + 6547472);
    unsigned short* Ah    = (unsigned short*)(ws + 7596048);
    unsigned short* Al    = (unsigned short*)(ws + 11790352);
    unsigned short* Wh    = (unsigned short*)(ws + 15984656);
    unsigned short* Wl    = (unsigned short*)(ws + 16246800);

    const float sc_in = (float)sqrt(2.0 / 131.0);
    const float sc_c  = (float)sqrt(2.0 / 256.0);
    const float sc_2c = (float)sqrt(2.0 / 512.0);

    (void)hipMemsetAsync(sums, 0, 59408 * sizeof(float), stream);  // thru abar
    seg_pool_kernel<<<dim3(BATCH * 32), 1024, 0, stream>>>(images, seg, sums, counts);
    conv_split_abar_kernel<<<dim3(256), 256, 0, stream>>>(A, Ah, Al, abar, sumabar);
    prep_xin_kernel<<<dim3((8192 * 144) / 256), 256, 0, stream>>>(sums, counts, z, xin);
    prep_wpad_kernel<<<dim3((256 * 144) / 256), 256, 0, stream>>>(proj_w, wpad);
    conv_split_kernel<<<dim3(512), 256, 0, stream>>>(blk_w, Wh, Wl, sc_c, 131072u);

    gemm_nt_kernel<<<dim3(128, 4), 256, 0, stream>>>(xin, wpad, x, 144, sc_in, proj_b,
                                                     abar, mv, xh, xl);

    for (int i = 0; i < 8; ++i) {
        gemm_nt_mfma_kernel<<<dim3(64, 5), 512, 0, stream>>>(
            xh, xl, Wh + (size_t)i * 65536, Wl + (size_t)i * 65536,
            blk_b + i * CDIM, h1t_h, h1t_l,
            mv + i * 2048, sumabar, blk_w + (size_t)i * CDIM * CDIM,
            ada_w1 + (size_t)i * 512 * 256, ada_b1 + i * 512,
            ada_w2 + (size_t)i * 512 * 512, ada_b2 + i * 512,
            style, sc_c, sc_2c);
        const bool last = (i == 7);
        gemm_nn_mfma_kernel<<<dim3(8, 4, 8), 512, 0, stream>>>(
            Ah, Al, h1t_h, h1t_l, style, abar,
            last ? x : nullptr,
            last ? nullptr : xh, last ? nullptr : xl,
            last ? nullptr : (mv + (i + 1) * 2048));
    }

    color_kernel<<<dim3(2048), 256, 0, stream>>>(x, rgb_w, rgb_b, colr, sc_c);
    gather_kernel<<<dim3(2048), 256, 0, stream>>>(seg, colr, out);
}

// Round 10
// 548.718 us; speedup vs baseline: 4.0917x; 1.0157x over previous
//
#include <hip/hip_runtime.h>
#include <math.h>

#define N_PIX (512*512)
#define S_SEG 1024
#define CDIM  256
#define BATCH 8

typedef __attribute__((ext_vector_type(4))) float f32x4;
typedef __attribute__((ext_vector_type(8))) short bf16x8;
typedef __fp16 half2v __attribute__((ext_vector_type(2)));
typedef __attribute__((address_space(3))) unsigned int lds_uint;

__device__ __forceinline__ float lrelu(float v) { return v > 0.f ? v : 0.2f * v; }

__device__ __forceinline__ unsigned short bf16_hi(float x) {
    union { float f; unsigned int u; } v; v.f = x;
    unsigned int r = v.u + 0x7FFFu + ((v.u >> 16) & 1u);
    return (unsigned short)(r >> 16);
}
__device__ __forceinline__ float bf16_tof(unsigned short h) {
    union { float f; unsigned int u; } v; v.u = ((unsigned int)h) << 16;
    return v.f;
}
__device__ __forceinline__ float dot4(float4 a, float4 b) {
    return a.x * b.x + a.y * b.y + a.z * b.z + a.w * b.w;
}
__device__ __forceinline__ unsigned pack_h2(float lo, float hi) {
    union { half2v h; unsigned u; } c;
    c.h = __builtin_amdgcn_cvt_pkrtz(lo, hi);
    return c.u;
}
__device__ __forceinline__ void ds_pk_add(lds_uint* p, unsigned val) {
    asm volatile("ds_pk_add_f16 %0, %1"
                 :: "v"((unsigned)(unsigned long)p), "v"(val) : "memory");
}

// ---------------------------------------------------------------------------
// MERGED prep: block-range partitioned, 1024 threads.
//   blocks [0,256)    : segment pooling (LDS packed-fp16 atomics)
//   blocks [256,512)  : A -> bf16 hi/lo split + abar column means + sumabar
//   blocks [512,640)  : blk_w -> Wh/Wl split (scaled by sc_c)
//   block  640        : proj_w -> wpad (zero-padded to K=144)
// Independent tasks; atomic-bound and BW-bound branches overlap on the GPU.
// ---------------------------------------------------------------------------
__global__ __launch_bounds__(1024) void prep_all_kernel(
    const float* __restrict__ images, const int* __restrict__ seg,
    float* __restrict__ sums, float* __restrict__ counts,
    const float* __restrict__ A, unsigned short* __restrict__ Ah,
    unsigned short* __restrict__ Al, float* __restrict__ abar,
    float* __restrict__ sumabar,
    const float* __restrict__ blk_w, unsigned short* __restrict__ Wh,
    unsigned short* __restrict__ Wl, float sc_c,
    const float* __restrict__ proj_w, float* __restrict__ wpad)
{
    __shared__ unsigned int sm[2048];    // seg: bins2 (8KB) | conv: red (4KB)
    const int blk = blockIdx.x;
    const int t = threadIdx.x;

    if (blk < 256) {
        // ---- segment pooling ----
        const int b = blk >> 5;
        const int chunk = blk & 31;
        for (int i = t; i < S_SEG * 2; i += 1024) sm[i] = 0u;
        __syncthreads();

        lds_uint* bl2 = (lds_uint*)sm;
        const float4* imr = (const float4*)(images + (size_t)b * 3 * N_PIX);
        const float4* img = imr + N_PIX / 4;
        const float4* imb = img + N_PIX / 4;
        const int4* sg4 = (const int4*)(seg + (size_t)b * N_PIX);
        const int base4 = chunk * (N_PIX / 32 / 4);

#pragma unroll
        for (int it = 0; it < 2; ++it) {
            int p4 = base4 + it * 1024 + t;
            int4 s = sg4[p4];
            float4 r = imr[p4];
            float4 g = img[p4];
            float4 bb = imb[p4];
            ds_pk_add(bl2 + s.x * 2 + 0, pack_h2(r.x, g.x));
            ds_pk_add(bl2 + s.x * 2 + 1, pack_h2(bb.x, 1.f));
            ds_pk_add(bl2 + s.y * 2 + 0, pack_h2(r.y, g.y));
            ds_pk_add(bl2 + s.y * 2 + 1, pack_h2(bb.y, 1.f));
            ds_pk_add(bl2 + s.z * 2 + 0, pack_h2(r.z, g.z));
            ds_pk_add(bl2 + s.z * 2 + 1, pack_h2(bb.z, 1.f));
            ds_pk_add(bl2 + s.w * 2 + 0, pack_h2(r.w, g.w));
            ds_pk_add(bl2 + s.w * 2 + 1, pack_h2(bb.w, 1.f));
        }
        __syncthreads();
        if (t < S_SEG) {
            union { unsigned u; __fp16 h[2]; } p0, p1;
            p0.u = sm[t * 2 + 0];
            p1.u = sm[t * 2 + 1];
            float cnt = (float)p1.h[1];
            if (cnt != 0.f) {
                atomicAdd(&sums[((size_t)b * S_SEG + t) * 3 + 0], (float)p0.h[0]);
                atomicAdd(&sums[((size_t)b * S_SEG + t) * 3 + 1], (float)p0.h[1]);
                atomicAdd(&sums[((size_t)b * S_SEG + t) * 3 + 2], (float)p1.h[0]);
                atomicAdd(&counts[(size_t)b * S_SEG + t], cnt);
            }
        }
        return;
    }

    if (blk < 512) {
        // ---- A split + abar (threads 0-255 active for the streaming work) ----
        const int b = (blk - 256) >> 5;
        const int chunk = (blk - 256) & 31;
        float a0 = 0.f, a1 = 0.f, a2 = 0.f, a3 = 0.f;
        if (t < 256) {
            const size_t base4 = ((size_t)b * 1024 * 1024 + (size_t)chunk * 32 * 1024) >> 2;
            const float4* Af = ((const float4*)A) + base4;
            ushort4* Ahf = ((ushort4*)Ah) + base4;
            ushort4* Alf = ((ushort4*)Al) + base4;
#pragma unroll 4
            for (int r = 0; r < 32; ++r) {
                float4 v = Af[r * 256 + t];
                ushort4 h, l;
                h.x = bf16_hi(v.x); l.x = bf16_hi(v.x - bf16_tof(h.x));
                h.y = bf16_hi(v.y); l.y = bf16_hi(v.y - bf16_tof(h.y));
                h.z = bf16_hi(v.z); l.z = bf16_hi(v.z - bf16_tof(h.z));
                h.w = bf16_hi(v.w); l.w = bf16_hi(v.w - bf16_tof(h.w));
                Ahf[r * 256 + t] = h;
                Alf[r * 256 + t] = l;
                a0 += v.x; a1 += v.y; a2 += v.z; a3 += v.w;
            }
            const float inv = 1.f / 1024.f;
            atomicAdd(&abar[b * 1024 + t * 4 + 0], a0 * inv);
            atomicAdd(&abar[b * 1024 + t * 4 + 1], a1 * inv);
            atomicAdd(&abar[b * 1024 + t * 4 + 2], a2 * inv);
            atomicAdd(&abar[b * 1024 + t * 4 + 3], a3 * inv);
        }
        float* red = (float*)sm;
        red[t] = (t < 256) ? (a0 + a1 + a2 + a3) * (1.f / 1024.f) : 0.f;
        __syncthreads();
        for (int off = 512; off > 0; off >>= 1) {
            if (t < off) red[t] += red[t + off];
            __syncthreads();
        }
        if (t == 0) atomicAdd(&sumabar[b], red[0]);
        return;
    }

    if (blk < 640) {
        // ---- blk_w split: 131072 float4 over 128 blocks ----
        unsigned int idx = (blk - 512) * 1024 + t;
        float4 v = ((const float4*)blk_w)[idx];
        ushort4 h, l;
        float a;
        a = v.x * sc_c; h.x = bf16_hi(a); l.x = bf16_hi(a - bf16_tof(h.x));
        a = v.y * sc_c; h.y = bf16_hi(a); l.y = bf16_hi(a - bf16_tof(h.y));
        a = v.z * sc_c; h.z = bf16_hi(a); l.z = bf16_hi(a - bf16_tof(h.z));
        a = v.w * sc_c; h.w = bf16_hi(a); l.w = bf16_hi(a - bf16_tof(h.w));
        ((ushort4*)Wh)[idx] = h;
        ((ushort4*)Wl)[idx] = l;
        return;
    }

    // ---- wpad: 256 x 144 ----
    for (int i = t; i < 256 * 144; i += 1024) {
        int n = i / 144, k = i % 144;
        wpad[i] = (k < 131) ? proj_w[n * 131 + k] : 0.f;
    }
}

__global__ __launch_bounds__(256) void prep_xin_kernel(
    const float* __restrict__ sums, const float* __restrict__ counts,
    const float* __restrict__ z, float* __restrict__ xin)
{
    int idx = blockIdx.x * 256 + threadIdx.x;
    int r = idx / 144, c = idx % 144;
    int b = r >> 10;
    float v;
    if (c < 3)        v = sums[r * 3 + c] / (counts[r] + 1e-6f);
    else if (c < 131) v = z[b * 128 + (c - 3)];
    else              v = 0.f;
    xin[idx] = v;
}

// ---------------------------------------------------------------------------
// staging helpers (rule #21 both-sides swizzle); T = block thread count
// ---------------------------------------------------------------------------
__device__ __forceinline__ void stage_tile(
    const unsigned short* __restrict__ g, int grow,
    unsigned short* lds, int tid, int nissue, int T)
{
    for (int i = 0; i < nissue; ++i) {
        int c = i * T + tid;
        int row = c >> 3, cin = c & 7;
        int cs = cin ^ (row & 7);
        const unsigned short* src = g + (size_t)row * grow + cs * 8;
        unsigned short* dst = lds + (size_t)(i * T + (tid & ~63)) * 8;
        __builtin_amdgcn_global_load_lds(
            (const __attribute__((address_space(1))) unsigned int*)src,
            (__attribute__((address_space(3))) unsigned int*)dst, 16, 0, 0);
    }
}

__device__ __forceinline__ int frag_idx(int row, int ks, int l)
{
    int chunk = (ks * 4 + (l >> 4)) ^ (row & 7);
    return row * 64 + chunk * 8;
}

// ---------------------------------------------------------------------------
// MFMA split-3 GEMM: x_out = lrelu(gamma*(A @ h1) + beta) + optional outputs.
// Tile 64x128 (grid 16x2x8): column-split 2 instead of 4 halves A re-read
// traffic. 512 threads / 8 waves (2x4), wave-tile 32x32.
// ---------------------------------------------------------------------------
__global__ __launch_bounds__(512) void gemm_nn_mfma_kernel(
    const unsigned short* __restrict__ Ah_g, const unsigned short* __restrict__ Al_g,
    const unsigned short* __restrict__ Hh_g, const unsigned short* __restrict__ Hl_g,
    const float* __restrict__ style, const float* __restrict__ abar,
    float* __restrict__ x, unsigned short* __restrict__ xh,
    unsigned short* __restrict__ xl, float* __restrict__ mv)
{
    __shared__ __align__(16) unsigned short Ah_s[64 * 64];
    __shared__ __align__(16) unsigned short Al_s[64 * 64];
    __shared__ __align__(16) unsigned short Bh_s[128 * 64];
    __shared__ __align__(16) unsigned short Bl_s[128 * 64];
    __shared__ float mvred[128];
    const int tid = threadIdx.x;
    const int b = blockIdx.z, bm = blockIdx.x, bn = blockIdx.y;
    const int l = tid & 63, wave = tid >> 6;
    const int wr = wave >> 2, wc = wave & 3;   // 2 x 4 waves, wave-tile 32x32
    if (mv && tid < 128) mvred[tid] = 0.f;

    const unsigned short* Ag_h = Ah_g + ((size_t)(b * 1024 + bm * 64)) * 1024;
    const unsigned short* Ag_l = Al_g + ((size_t)(b * 1024 + bm * 64)) * 1024;
    const unsigned short* Hg_h = Hh_g + ((size_t)(b * 256 + bn * 128)) * 1024;
    const unsigned short* Hg_l = Hl_g + ((size_t)(b * 256 + bn * 128)) * 1024;

    f32x4 acc[2][2];
#pragma unroll
    for (int i = 0; i < 2; ++i)
#pragma unroll
        for (int j = 0; j < 2; ++j) acc[i][j] = (f32x4){0.f, 0.f, 0.f, 0.f};

    for (int kt = 0; kt < 16; ++kt) {
        stage_tile(Ag_h + kt * 64, 1024, Ah_s, tid, 1, 512);
        stage_tile(Ag_l + kt * 64, 1024, Al_s, tid, 1, 512);
        stage_tile(Hg_h + kt * 64, 1024, Bh_s, tid, 2, 512);
        stage_tile(Hg_l + kt * 64, 1024, Bl_s, tid, 2, 512);
        __syncthreads();
#pragma unroll
        for (int ks = 0; ks < 2; ++ks) {
            bf16x8 ah[2], al[2], bh[2], bl[2];
#pragma unroll
            for (int fm = 0; fm < 2; ++fm) {
                int row = wr * 32 + fm * 16 + (l & 15);
                int idx = frag_idx(row, ks, l);
                ah[fm] = *(const bf16x8*)&Ah_s[idx];
                al[fm] = *(const bf16x8*)&Al_s[idx];
            }
#pragma unroll
            for (int fn = 0; fn < 2; ++fn) {
                int row = wc * 32 + fn * 16 + (l & 15);
                int idx = frag_idx(row, ks, l);
                bh[fn] = *(const bf16x8*)&Bh_s[idx];
                bl[fn] = *(const bf16x8*)&Bl_s[idx];
            }
#pragma unroll
            for (int fm = 0; fm < 2; ++fm)
#pragma unroll
                for (int fn = 0; fn < 2; ++fn) {
                    acc[fm][fn] = __builtin_amdgcn_mfma_f32_16x16x32_bf16(ah[fm], bh[fn], acc[fm][fn], 0, 0, 0);
                    acc[fm][fn] = __builtin_amdgcn_mfma_f32_16x16x32_bf16(ah[fm], bl[fn], acc[fm][fn], 0, 0, 0);
                    acc[fm][fn] = __builtin_amdgcn_mfma_f32_16x16x32_bf16(al[fm], bh[fn], acc[fm][fn], 0, 0, 0);
                }
        }
        __syncthreads();
    }

    const float* st = style + b * 2 * CDIM;
#pragma unroll
    for (int fn = 0; fn < 2; ++fn) {
        int col = bn * 128 + wc * 32 + fn * 16 + (l & 15);
        float ga = st[col], be = st[CDIM + col];
        float pmv = 0.f;
#pragma unroll
        for (int fm = 0; fm < 2; ++fm) {
            int m0 = bm * 64 + wr * 32 + fm * 16 + (l >> 4) * 4;
#pragma unroll
            for (int r = 0; r < 4; ++r) {
                float v = lrelu(ga * acc[fm][fn][r] + be);
                size_t off = ((size_t)(b * 1024 + m0 + r)) * 256 + col;
                if (x) x[off] = v;
                if (xh) {
                    unsigned short h = bf16_hi(v);
                    xh[off] = h;
                    xl[off] = bf16_hi(v - bf16_tof(h));
                }
                pmv += abar[b * 1024 + m0 + r] * v;
            }
        }
        if (mv) atomicAdd(&mvred[wc * 32 + fn * 16 + (l & 15)], pmv);
    }
    if (mv) {
        __syncthreads();
        if (tid < 128) atomicAdd(&mv[b * 256 + bn * 128 + tid], mvred[tid]);
    }
}

// ---------------------------------------------------------------------------
// MFMA split-3 GEMM (h1 = x @ W'^T + b, transposed bf16 output), 512 thr /
// 8 waves, PLUS the per-batch style MLP at blockIdx.y == 4 (wave-per-output).
// ---------------------------------------------------------------------------
__global__ __launch_bounds__(512) void gemm_nt_mfma_kernel(
    const unsigned short* __restrict__ xh_g, const unsigned short* __restrict__ xl_g,
    const unsigned short* __restrict__ Wh, const unsigned short* __restrict__ Wl,
    const float* __restrict__ bias,
    unsigned short* __restrict__ h1t_h, unsigned short* __restrict__ h1t_l,
    const float* __restrict__ mv, const float* __restrict__ sumabar,
    const float* __restrict__ Wblk_f,
    const float* __restrict__ W1, const float* __restrict__ b1,
    const float* __restrict__ W2, const float* __restrict__ b2,
    float* __restrict__ style, float sc_c, float sc_2c)
{
    __shared__ __align__(16) unsigned short Ah_s[128 * 64];
    __shared__ __align__(16) unsigned short Al_s[128 * 64];
    __shared__ __align__(16) unsigned short Bh_s[64 * 64];
    __shared__ __align__(16) unsigned short Bl_s[64 * 64];
    const int tid = threadIdx.x;
    const int bm = blockIdx.x, bn = blockIdx.y;

    if (bn == 4) {
        if (bm >= BATCH * 4) return;
        const int bb = bm >> 2;
        const int q = bm & 3;
        const int w = tid >> 6, lane = tid & 63;
        float* m_s = (float*)Ah_s;
        float* s1_s = (float*)Bh_s;

        const float4 mvreg = *(const float4*)&mv[bb * 256 + lane * 4];
        const float sab = sumabar[bb];

        for (int g = 0; g < 4; ++g) {
            const int o0 = w * 32 + g * 8;
            float p[8];
#pragma unroll
            for (int j = 0; j < 8; ++j) {
                const float4 wv = *(const float4*)&Wblk_f[(size_t)(o0 + j) * 256 + lane * 4];
                p[j] = dot4(wv, mvreg);
            }
#pragma unroll
            for (int off = 32; off > 0; off >>= 1)
#pragma unroll
                for (int j = 0; j < 8; ++j) p[j] += __shfl_xor(p[j], off);
            if (lane == 0)
#pragma unroll
                for (int j = 0; j < 8; ++j)
                    m_s[o0 + j] = sc_c * p[j] + sab * bias[o0 + j];
        }
        __syncthreads();
        const float4 mreg = *(const float4*)&m_s[lane * 4];

        for (int g = 0; g < 8; ++g) {
            const int o0 = w * 64 + g * 8;
            float p[8];
#pragma unroll
            for (int j = 0; j < 8; ++j) {
                const float4 wv = *(const float4*)&W1[(size_t)(o0 + j) * 256 + lane * 4];
                p[j] = dot4(wv, mreg);
            }
#pragma unroll
            for (int off = 32; off > 0; off >>= 1)
#pragma unroll
                for (int j = 0; j < 8; ++j) p[j] += __shfl_xor(p[j], off);
            if (lane == 0)
#pragma unroll
                for (int j = 0; j < 8; ++j)
                    s1_s[o0 + j] = lrelu(sc_c * p[j] + b1[o0 + j]);
        }
        __syncthreads();
        const float4 sa = *(const float4*)&s1_s[lane * 4];
        const float4 sb = *(const float4*)&s1_s[256 + lane * 4];

        for (int g = 0; g < 2; ++g) {
            const int o0 = q * 128 + w * 16 + g * 8;
            float p[8];
#pragma unroll
            for (int j = 0; j < 8; ++j) {
                const float4 wa = *(const float4*)&W2[(size_t)(o0 + j) * 512 + lane * 4];
                const float4 wb = *(const float4*)&W2[(size_t)(o0 + j) * 512 + 256 + lane * 4];
                p[j] = dot4(wa, sa) + dot4(wb, sb);
            }
#pragma unroll
            for (int off = 32; off > 0; off >>= 1)
#pragma unroll
                for (int j = 0; j < 8; ++j) p[j] += __shfl_xor(p[j], off);
            if (lane == 0)
#pragma unroll
                for (int j = 0; j < 8; ++j)
                    style[bb * 512 + o0 + j] = sc_2c * p[j] + b2[o0 + j];
        }
        return;
    }

    // ---- GEMM path (8 waves, wave-tile 64x16) ----
    const int l = tid & 63, wave = tid >> 6;
    const int wr = wave >> 2, wc = wave & 3;
    const int row0 = bm * 128;
    const int b = row0 >> 10;

    const unsigned short* Ag_h = xh_g + (size_t)row0 * 256;
    const unsigned short* Ag_l = xl_g + (size_t)row0 * 256;
    const unsigned short* Bg_h = Wh + (size_t)(bn * 64) * 256;
    const unsigned short* Bg_l = Wl + (size_t)(bn * 64) * 256;

    f32x4 acc[4];
#pragma unroll
    for (int i = 0; i < 4; ++i) acc[i] = (f32x4){0.f, 0.f, 0.f, 0.f};

    for (int kt = 0; kt < 4; ++kt) {
        stage_tile(Ag_h + kt * 64, 256, Ah_s, tid, 2, 512);
        stage_tile(Ag_l + kt * 64, 256, Al_s, tid, 2, 512);
        stage_tile(Bg_h + kt * 64, 256, Bh_s, tid, 1, 512);
        stage_tile(Bg_l + kt * 64, 256, Bl_s, tid, 1, 512);
        __syncthreads();
#pragma unroll
        for (int ks = 0; ks < 2; ++ks) {
            bf16x8 ah[4], al[4], bh, bl;
#pragma unroll
            for (int fm = 0; fm < 4; ++fm) {
                int row = wr * 64 + fm * 16 + (l & 15);
                int idx = frag_idx(row, ks, l);
                ah[fm] = *(const bf16x8*)&Ah_s[idx];
                al[fm] = *(const bf16x8*)&Al_s[idx];
            }
            {
                int row = wc * 16 + (l & 15);
                int idx = frag_idx(row, ks, l);
                bh = *(const bf16x8*)&Bh_s[idx];
                bl = *(const bf16x8*)&Bl_s[idx];
            }
#pragma unroll
            for (int fm = 0; fm < 4; ++fm) {
                acc[fm] = __builtin_amdgcn_mfma_f32_16x16x32_bf16(ah[fm], bh, acc[fm], 0, 0, 0);
                acc[fm] = __builtin_amdgcn_mfma_f32_16x16x32_bf16(ah[fm], bl, acc[fm], 0, 0, 0);
                acc[fm] = __builtin_amdgcn_mfma_f32_16x16x32_bf16(al[fm], bh, acc[fm], 0, 0, 0);
            }
        }
        __syncthreads();
    }

    {
        int col = bn * 64 + wc * 16 + (l & 15);
        float bi = bias[col];
#pragma unroll
        for (int fm = 0; fm < 4; ++fm) {
            int s0 = (row0 & 1023) + wr * 64 + fm * 16 + (l >> 4) * 4;
            float v0 = acc[fm][0] + bi;
            float v1 = acc[fm][1] + bi;
            float v2 = acc[fm][2] + bi;
            float v3 = acc[fm][3] + bi;
            ushort4 hv, lv;
            hv.x = bf16_hi(v0); lv.x = bf16_hi(v0 - bf16_tof(hv.x));
            hv.y = bf16_hi(v1); lv.y = bf16_hi(v1 - bf16_tof(hv.y));
            hv.z = bf16_hi(v2); lv.z = bf16_hi(v2 - bf16_tof(hv.z));
            hv.w = bf16_hi(v3); lv.w = bf16_hi(v3 - bf16_tof(hv.w));
            size_t off = ((size_t)(b * 256 + col)) * 1024 + s0;
            *(ushort4*)&h1t_h[off] = hv;
            *(ushort4*)&h1t_l[off] = lv;
        }
    }
}

// ---------------------------------------------------------------------------
// fp32 VALU gemm_nt (proj only) + mv + bf16 emit
// ---------------------------------------------------------------------------
#define BM 64
#define BN 64
#define BK 16
__global__ __launch_bounds__(256) void gemm_nt_kernel(
    const float* __restrict__ A, const float* __restrict__ B,
    float* __restrict__ C, int K, float alpha, const float* __restrict__ bias,
    const float* __restrict__ abar, float* __restrict__ mv,
    unsigned short* __restrict__ xh, unsigned short* __restrict__ xl)
{
    __shared__ float As[BK][BM + 4];
    __shared__ float Bs[BK][BN + 4];
    __shared__ float red[16][BN];
    const int tid = threadIdx.x;
    const int bm = blockIdx.x, bn = blockIdx.y;
    const int tx = tid & 15, ty = tid >> 4;
    const int lrow = tid >> 2;
    const int lk = (tid & 3) << 2;
    const float* Ag = A + (size_t)(bm * BM + lrow) * K + lk;
    const float* Bg = B + (size_t)(bn * BN + lrow) * K + lk;
    float acc[4][4] = {};

    for (int k0 = 0; k0 < K; k0 += BK) {
        float4 av = *(const float4*)(Ag + k0);
        float4 bv = *(const float4*)(Bg + k0);
        __syncthreads();
        As[lk + 0][lrow] = av.x; As[lk + 1][lrow] = av.y;
        As[lk + 2][lrow] = av.z; As[lk + 3][lrow] = av.w;
        Bs[lk + 0][lrow] = bv.x; Bs[lk + 1][lrow] = bv.y;
        Bs[lk + 2][lrow] = bv.z; Bs[lk + 3][lrow] = bv.w;
        __syncthreads();
#pragma unroll
        for (int kk = 0; kk < BK; ++kk) {
            const float4 a = *(const float4*)&As[kk][ty << 2];
            const float4 b = *(const float4*)&Bs[kk][tx << 2];
            float ar[4] = {a.x, a.y, a.z, a.w};
            float br[4] = {b.x, b.y, b.z, b.w};
#pragma unroll
            for (int i = 0; i < 4; ++i)
#pragma unroll
                for (int j = 0; j < 4; ++j)
                    acc[i][j] += ar[i] * br[j];
        }
    }
    const int row = bm * BM + (ty << 2);
    const int col = bn * BN + (tx << 2);
    const int b = row >> 10;
    float bi[4] = {bias[col], bias[col + 1], bias[col + 2], bias[col + 3]};
    float o[4][4];
#pragma unroll
    for (int i = 0; i < 4; ++i) {
        float4 ov;
        ov.x = o[i][0] = alpha * acc[i][0] + bi[0];
        ov.y = o[i][1] = alpha * acc[i][1] + bi[1];
        ov.z = o[i][2] = alpha * acc[i][2] + bi[2];
        ov.w = o[i][3] = alpha * acc[i][3] + bi[3];
        *(float4*)(C + (size_t)(row + i) * CDIM + col) = ov;
#pragma unroll
        for (int j = 0; j < 4; ++j) {
            size_t off = (size_t)(row + i) * CDIM + col + j;
            unsigned short h = bf16_hi(o[i][j]);
            xh[off] = h;
            xl[off] = bf16_hi(o[i][j] - bf16_tof(h));
        }
    }
    {
        float p[4];
#pragma unroll
        for (int j = 0; j < 4; ++j) {
            p[j] = 0.f;
#pragma unroll
            for (int i = 0; i < 4; ++i)
                p[j] += abar[((row + i) & 1023) + (b << 10)] * o[i][j];
            red[ty][(tx << 2) + j] = p[j];
        }
        __syncthreads();
        if (tid < BN) {
            float s = 0.f;
#pragma unroll
            for (int t = 0; t < 16; ++t) s += red[t][tid];
            atomicAdd(&mv[b * CDIM + bn * BN + tid], s);
        }
    }
}

// ---------------------------------------------------------------------------
// color: writes tanh'd color table
// ---------------------------------------------------------------------------
__global__ __launch_bounds__(256) void color_kernel(
    const float* __restrict__ x, const float* __restrict__ rgb_w,
    const float* __restrict__ rgb_b, float* __restrict__ color, float sc_c)
{
    const int wave = threadIdx.x >> 6;
    const int lane = threadIdx.x & 63;
    const int r = blockIdx.x * 4 + wave;
    const float4 xv = *(const float4*)(x + (size_t)r * CDIM + lane * 4);
    float p[3];
#pragma unroll
    for (int cc = 0; cc < 3; ++cc) {
        const float4 wv = *(const float4*)(rgb_w + cc * CDIM + lane * 4);
        p[cc] = xv.x * wv.x + xv.y * wv.y + xv.z * wv.z + xv.w * wv.w;
    }
#pragma unroll
    for (int off = 32; off > 0; off >>= 1) {
#pragma unroll
        for (int cc = 0; cc < 3; ++cc) p[cc] += __shfl_down(p[cc], off);
    }
    if (lane == 0) {
#pragma unroll
        for (int cc = 0; cc < 3; ++cc)
            color[(size_t)r * 3 + cc] = tanhf(sc_c * p[cc] + rgb_b[cc]);
    }
}

// ---------------------------------------------------------------------------
// gather: 4 pixels/thread, float4 stores per plane; color already tanh'd
// ---------------------------------------------------------------------------
__global__ __launch_bounds__(256) void gather_kernel(
    const int* __restrict__ seg, const float* __restrict__ color,
    float* __restrict__ out)
{
    int idx = blockIdx.x * 256 + threadIdx.x;
    int b = idx >> 16;
    int p4 = idx & 65535;
    int4 s = ((const int4*)(seg + (size_t)b * N_PIX))[p4];
    const float* cb = color + (size_t)b * S_SEG * 3;
    float4 o0, o1, o2;
    o0.x = cb[s.x * 3 + 0]; o1.x = cb[s.x * 3 + 1]; o2.x = cb[s.x * 3 + 2];
    o0.y = cb[s.y * 3 + 0]; o1.y = cb[s.y * 3 + 1]; o2.y = cb[s.y * 3 + 2];
    o0.z = cb[s.z * 3 + 0]; o1.z = cb[s.z * 3 + 1]; o2.z = cb[s.z * 3 + 2];
    o0.w = cb[s.w * 3 + 0]; o1.w = cb[s.w * 3 + 1]; o2.w = cb[s.w * 3 + 2];
    ((float4*)(out + ((size_t)b * 3 + 0) * N_PIX))[p4] = o0;
    ((float4*)(out + ((size_t)b * 3 + 1) * N_PIX))[p4] = o1;
    ((float4*)(out + ((size_t)b * 3 + 2) * N_PIX))[p4] = o2;
}

// ---------------------------------------------------------------------------
extern "C" void kernel_launch(void* const* d_in, const int* in_sizes, int n_in,
                              void* d_out, int out_size, void* d_ws, size_t ws_size,
                              hipStream_t stream)
{
    (void)in_sizes; (void)n_in; (void)out_size; (void)ws_size;
    const float* z      = (const float*)d_in[0];
    const float* images = (const float*)d_in[1];
    const int*   seg    = (const int*)d_in[2];
    const float* A      = (const float*)d_in[3];
    const float* proj_w = (const float*)d_in[4];
    const float* proj_b = (const float*)d_in[5];
    const float* blk_w  = (const float*)d_in[6];
    const float* blk_b  = (const float*)d_in[7];
    const float* ada_w1 = (const float*)d_in[8];
    const float* ada_b1 = (const float*)d_in[9];
    const float* ada_w2 = (const float*)d_in[10];
    const float* ada_b2 = (const float*)d_in[11];
    const float* rgb_w  = (const float*)d_in[12];
    const float* rgb_b  = (const float*)d_in[13];
    float* out = (float*)d_out;

    float* ws = (float*)d_ws;
    float* sums    = ws;                  // 24576
    float* counts  = ws + 24576;          // 8192
    float* sumabar = ws + 32768;          // 16
    float* mv      = ws + 32784;          // 18432
    float* abar    = ws + 51216;          // 8192
    float* style   = ws + 59408;          // 4096
    float* colr    = ws + 63504;          // 24576
    float* wpad    = ws + 88080;          // 36864
    float* xin     = ws + 124944;         // 1179648 -> ends 1304592
    float* x       = ws + 1304592;        // 2097152 -> ends 3401744
    unsigned short* xh    = (unsigned short*)(ws + 3401744);
    unsigned short* xl    = (unsigned short*)(ws + 4450320);
    unsigned short* h1t_h = (unsigned short*)(ws + 5498896);
    unsigned short* h1t_l = (unsigned short*)(ws + 6547472);
    unsigned short* Ah    = (unsigned short*)(ws + 7596048);
    unsigned short* Al    = (unsigned short*)(ws + 11790352);
    unsigned short* Wh    = (unsigned short*)(ws + 15984656);
    unsigned short* Wl    = (unsigned short*)(ws + 16246800);

    const float sc_in = (float)sqrt(2.0 / 131.0);
    const float sc_c  = (float)sqrt(2.0 / 256.0);
    const float sc_2c = (float)sqrt(2.0 / 512.0);

    (void)hipMemsetAsync(sums, 0, 59408 * sizeof(float), stream);  // thru abar
    prep_all_kernel<<<dim3(641), 1024, 0, stream>>>(
        images, seg, sums, counts, A, Ah, Al, abar, sumabar,
        blk_w, Wh, Wl, sc_c, proj_w, wpad);
    prep_xin_kernel<<<dim3((8192 * 144) / 256), 256, 0, stream>>>(sums, counts, z, xin);

    gemm_nt_kernel<<<dim3(128, 4), 256, 0, stream>>>(xin, wpad, x, 144, sc_in, proj_b,
                                                     abar, mv, xh, xl);

    for (int i = 0; i < 8; ++i) {
        gemm_nt_mfma_kernel<<<dim3(64, 5), 512, 0, stream>>>(
            xh, xl, Wh + (size_t)i * 65536, Wl + (size_t)i * 65536,
            blk_b + i * CDIM, h1t_h, h1t_l,
            mv + i * 2048, sumabar, blk_w + (size_t)i * CDIM * CDIM,
            ada_w1 + (size_t)i * 512 * 256, ada_b1 + i * 512,
            ada_w2 + (size_t)i * 512 * 512, ada_b2 + i * 512,
            style, sc_c, sc_2c);
        const bool last = (i == 7);
        gemm_nn_mfma_kernel<<<dim3(16, 2, 8), 512, 0, stream>>>(
            Ah, Al, h1t_h, h1t_l, style, abar,
            last ? x : nullptr,
            last ? nullptr : xh, last ? nullptr : xl,
            last ? nullptr : (mv + (i + 1) * 2048));
    }

    color_kernel<<<dim3(2048), 256, 0, stream>>>(x, rgb_w, rgb_b, colr, sc_c);
    gather_kernel<<<dim3(2048), 256, 0, stream>>>(seg, colr, out);
}